// Round 4
// baseline (487.130 us; speedup 1.0000x reference)
//
#include <hip/hip_runtime.h>
#include <hip/hip_bf16.h>

#define NBATCH 8
#define CDIM 256
#define HH 64
#define WW 64
#define HWSZ 4096
#define TT 32768        // NBATCH * HWSZ tokens
#define QKVD 768        // q(256) | k(256) | v(256)
#define TOPK 4
#define HID 1024
#define ATTN_SCALE 0.0625f   // 256^-0.5

typedef __hip_bfloat16 bf16;
typedef __attribute__((ext_vector_type(8))) short s8v;   // 8 bf16 = 4 VGPR
typedef __attribute__((ext_vector_type(4))) float f4v;   // MFMA acc

__device__ __forceinline__ float toF(bf16 v) { return __bfloat162float(v); }
__device__ __forceinline__ bf16  toB(float v) { return __float2bfloat16(v); }

// async 16B global -> LDS (wave-uniform LDS base + lane*16)
__device__ __forceinline__ void gload_lds16(const bf16* g, bf16* l) {
    __builtin_amdgcn_global_load_lds(
        (const __attribute__((address_space(1))) void*)g,
        (__attribute__((address_space(3))) void*)l, 16, 0, 0);
}

// ---------------------------------------------------------------------------
// Prep: fold gamma into weights, cast to bf16; concat qkv bias; and build
// wdwT: per-cg-contiguous dw3 weights+bias fp32: wdwT[cg*80 + c*9 + k],
// bias at wdwT[cg*80 + 72 + c]  (40 KB total).
__global__ void k_prep(const float* __restrict__ wq, const float* __restrict__ gq,
                       const float* __restrict__ wkv, const float* __restrict__ gkv,
                       const float* __restrict__ wfc1, const float* __restrict__ gfc1,
                       const float* __restrict__ wfc2, const float* __restrict__ gfc2,
                       const float* __restrict__ bq, const float* __restrict__ bkv,
                       const float* __restrict__ w_dw, const float* __restrict__ b_dw,
                       bf16* __restrict__ wbqkv, bf16* __restrict__ wbfc1,
                       bf16* __restrict__ wbfc2, float* __restrict__ bias768,
                       float* __restrict__ wdwT) {
    int i = blockIdx.x * 256 + threadIdx.x;
    if (i < 196608) {                       // wbqkv [768][256]
        int r = i >> 8;
        float g = (r < 256) ? gq[r] : gkv[r - 256];
        float w = (r < 256) ? wq[i] : wkv[i - 65536];
        wbqkv[i] = toB(w * g);
        if (i < 768) bias768[i] = (i < 256) ? bq[i] : bkv[i - 256];
    } else if (i < 458752) {                // wbfc1 [1024][256]
        int j = i - 196608;
        wbfc1[j] = toB(wfc1[j] * gfc1[j >> 8]);
    } else if (i < 720896) {                // wbfc2 [256][1024]
        int j = i - 458752;
        wbfc2[j] = toB(wfc2[j] * gfc2[j >> 10]);
    } else if (i < 731136) {                // wdwT [128][80]
        int j = i - 720896;
        int cg = j / 80, r = j - cg * 80;
        wdwT[j] = (r < 72) ? w_dw[(cg * 8 + r / 9) * 9 + (r % 9)]
                           : b_dw[cg * 8 + (r - 72)];
    }
}

// ---------------------------------------------------------------------------
// x NCHW fp32 -> token-major bf16 xt[m][c]
__global__ void k_xt(const float* __restrict__ x, bf16* __restrict__ xt) {
    __shared__ float tile[32][33];
    int s0 = blockIdx.x * 32, c0 = blockIdx.y * 32, n = blockIdx.z;
    int tx = threadIdx.x, ty = threadIdx.y;
#pragma unroll
    for (int r = 0; r < 4; r++)
        tile[ty + r * 8][tx] = x[(size_t)n * CDIM * HWSZ + (size_t)(c0 + ty + r * 8) * HWSZ + s0 + tx];
    __syncthreads();
#pragma unroll
    for (int r = 0; r < 4; r++)
        xt[((size_t)n * HWSZ + s0 + ty + r * 8) * CDIM + c0 + tx] = toB(tile[tx][ty + r * 8]);
}

// ---------------------------------------------------------------------------
// Window means of x (fp32-exact routing path). Block=(n,c), thread=window p.
__global__ void k_xwin(const float* __restrict__ x, float* __restrict__ xwin) {
    int b = blockIdx.x;
    int n = b >> 8, c = b & 255;
    int p = threadIdx.x, wy = p >> 4, wx = p & 15;
    const float* pl = x + ((size_t)n * CDIM + c) * HWSZ;
    float s = 0.f;
#pragma unroll
    for (int dy = 0; dy < 4; dy++)
#pragma unroll
        for (int dx = 0; dx < 4; dx++)
            s += pl[(wy * 4 + dy) * WW + wx * 4 + dx];
    xwin[((size_t)(n << 8) + p) * 256 + c] = s * 0.0625f;
}

// ---------------------------------------------------------------------------
// qkwin[m][0:512] = (xwin @ [wq|wk]^T)*g + b  (fp32 vector GEMM, M=2048 K=256)
__global__ void k_qkwin(const float* __restrict__ xwin,
                        const float* __restrict__ wq, const float* __restrict__ wkv,
                        const float* __restrict__ gq, const float* __restrict__ bq,
                        const float* __restrict__ gkv, const float* __restrict__ bkv,
                        float* __restrict__ qkwin) {
    __shared__ float As[16][68];
    __shared__ float Bs[16][68];
    int m0 = blockIdx.x * 64, n0 = blockIdx.y * 64;
    int tid = threadIdx.x;
    int tx = tid & 15, ty = tid >> 4;
    float acc[4][4] = {};
    for (int k0 = 0; k0 < 256; k0 += 16) {
#pragma unroll
        for (int r = 0; r < 4; r++) {
            int lin = tid + r * 256;
            int row = lin >> 4, kk = lin & 15;
            As[kk][row] = xwin[(size_t)(m0 + row) * 256 + k0 + kk];
            int n = n0 + row;
            const float* wr = (n < 256) ? (wq + (size_t)n * 256) : (wkv + (size_t)(n - 256) * 256);
            Bs[kk][row] = wr[k0 + kk];
        }
        __syncthreads();
#pragma unroll
        for (int kk = 0; kk < 16; kk++) {
            float a[4], bb[4];
#pragma unroll
            for (int i = 0; i < 4; i++) a[i] = As[kk][tx * 4 + i];
#pragma unroll
            for (int j = 0; j < 4; j++) bb[j] = Bs[kk][ty * 4 + j];
#pragma unroll
            for (int i = 0; i < 4; i++)
#pragma unroll
                for (int j = 0; j < 4; j++) acc[i][j] += a[i] * bb[j];
        }
        __syncthreads();
    }
#pragma unroll
    for (int j = 0; j < 4; j++) {
        int n = n0 + ty * 4 + j;
        float gg = (n < 256) ? gq[n] : gkv[n - 256];
        float bb = (n < 256) ? bq[n] : bkv[n - 256];
#pragma unroll
        for (int i = 0; i < 4; i++)
            qkwin[(size_t)(m0 + tx * 4 + i) * 512 + n] = acc[i][j] * gg + bb;
    }
}

// ---------------------------------------------------------------------------
// Routing logits: per image, L[pq][key] = sum_c qwin[pq][c] * kwin[key][c].
__global__ void k_logits(const float* __restrict__ qkwin, float* __restrict__ logits) {
    __shared__ float As[16][68];
    __shared__ float Bs[16][68];
    int m0 = blockIdx.x * 64, n0 = blockIdx.y * 64, img = blockIdx.z;
    const float* base = qkwin + (size_t)(img << 8) * 512;
    int tid = threadIdx.x;
    int tx = tid & 15, ty = tid >> 4;
    float acc[4][4] = {};
    for (int k0 = 0; k0 < 256; k0 += 16) {
#pragma unroll
        for (int r = 0; r < 4; r++) {
            int lin = tid + r * 256;
            int row = lin >> 4, kk = lin & 15;
            As[kk][row] = base[(size_t)(m0 + row) * 512 + k0 + kk];
            Bs[kk][row] = base[(size_t)(n0 + row) * 512 + 256 + k0 + kk];
        }
        __syncthreads();
#pragma unroll
        for (int kk = 0; kk < 16; kk++) {
            float a[4], bb[4];
#pragma unroll
            for (int i = 0; i < 4; i++) a[i] = As[kk][tx * 4 + i];
#pragma unroll
            for (int j = 0; j < 4; j++) bb[j] = Bs[kk][ty * 4 + j];
#pragma unroll
            for (int i = 0; i < 4; i++)
#pragma unroll
                for (int j = 0; j < 4; j++) acc[i][j] += a[i] * bb[j];
        }
        __syncthreads();
    }
    float* Lr = logits + (size_t)(img << 8) * 256;
#pragma unroll
    for (int j = 0; j < 4; j++)
#pragma unroll
        for (int i = 0; i < 4; i++)
            Lr[(size_t)(m0 + tx * 4 + i) * 256 + n0 + ty * 4 + j] = acc[i][j];
}

// ---------------------------------------------------------------------------
// Top-4 per row of 256 logits: one wave per row, float4 load, shuffle argmax,
// jax tie-break (lower index wins). No __syncthreads.
__global__ __launch_bounds__(256) void k_topk(const float* __restrict__ logits,
                                              int* __restrict__ topk) {
    int row = blockIdx.x * 4 + (threadIdx.x >> 6);
    int lane = threadIdx.x & 63;
    float4 v4 = *(const float4*)(logits + (size_t)row * 256 + lane * 4);
    float v[4] = {v4.x, v4.y, v4.z, v4.w};
#pragma unroll
    for (int sel = 0; sel < TOPK; sel++) {
        float mv = v[0]; int mi = lane * 4;
#pragma unroll
        for (int j = 1; j < 4; j++)
            if (v[j] > mv) { mv = v[j]; mi = lane * 4 + j; }
#pragma unroll
        for (int off = 1; off < 64; off <<= 1) {
            float ov = __shfl_xor(mv, off);
            int oi = __shfl_xor(mi, off);
            if (ov > mv || (ov == mv && oi < mi)) { mv = ov; mi = oi; }
        }
        if (lane == 0) topk[(size_t)row * TOPK + sel] = mi;
        if ((mi >> 2) == lane) v[mi & 3] = -INFINITY;
    }
}

// ---------------------------------------------------------------------------
// MFMA GEMM: C[m][n] = A[m][k] * Wb[n][k] + bias[n].  A token-major bf16,
// Wb bf16 (gamma folded), bias fp32, out token-major bf16.
// Staging via global_load_lds width=16 (T-ladder step 3): LDS byte layout is
// linear in tid (off = c*16), so wave base = (w*64+q*256)*16 + lane*16.
// XCD-aware block swizzle (T1): all grids have tot % 8 == 0.
template <int BM, int BN>
__global__ __launch_bounds__(256) void k_mfma(const bf16* __restrict__ A,
                                              const bf16* __restrict__ Wb,
                                              const float* __restrict__ bias,
                                              bf16* __restrict__ out,
                                              int M, int N, int K) {
    constexpr int WROWS = BM / 2, WCOLS = BN / 2;     // per-wave quadrant
    constexpr int WM = WROWS / 16, WN = WCOLS / 16;   // 16x16 tiles per wave
    constexpr int CA = (BM * 4) / 256;                // 16B chunks/thread for A
    constexpr int CB = (BN * 4) / 256;
    __shared__ bf16 As[BM * 32];
    __shared__ bf16 Bs[BN * 32];
    // bijective XCD swizzle over the linearized grid
    int gx = gridDim.x;
    int lin = blockIdx.x + blockIdx.y * gx;
    int tot = gx * gridDim.y;
    int cpx = tot >> 3;
    int swz = (lin & 7) * cpx + (lin >> 3);
    int m0 = (swz % gx) * BM, n0 = (swz / gx) * BN;
    int tid = threadIdx.x;
    int w = tid >> 6, lane = tid & 63;
    int wr = w >> 1, wc = w & 1;
    int lm = lane & 15, lq = lane >> 4;
    f4v acc[WM][WN];
#pragma unroll
    for (int i = 0; i < WM; i++)
#pragma unroll
        for (int j = 0; j < WN; j++) acc[i][j] = (f4v){0.f, 0.f, 0.f, 0.f};

    for (int k0 = 0; k0 < K; k0 += 32) {
#pragma unroll
        for (int q = 0; q < CA; q++) {
            int c = tid + q * 256, row = c >> 2, col = c & 3;
            gload_lds16(A + (size_t)(m0 + row) * K + k0 + col * 8,
                        As + (size_t)(w * 64 + q * 256) * 8);
        }
#pragma unroll
        for (int q = 0; q < CB; q++) {
            int c = tid + q * 256, row = c >> 2, col = c & 3;
            gload_lds16(Wb + (size_t)(n0 + row) * K + k0 + col * 8,
                        Bs + (size_t)(w * 64 + q * 256) * 8);
        }
        asm volatile("s_waitcnt vmcnt(0)" ::: "memory");
        __syncthreads();                      // staged tile visible
        s8v af[WM], bfr[WN];
#pragma unroll
        for (int i = 0; i < WM; i++)
            af[i] = *(const s8v*)&As[(wr * WROWS + i * 16 + lm) * 32 + lq * 8];
#pragma unroll
        for (int j = 0; j < WN; j++)
            bfr[j] = *(const s8v*)&Bs[(wc * WCOLS + j * 16 + lm) * 32 + lq * 8];
#pragma unroll
        for (int i = 0; i < WM; i++)
#pragma unroll
            for (int j = 0; j < WN; j++)
                acc[i][j] = __builtin_amdgcn_mfma_f32_16x16x32_bf16(af[i], bfr[j], acc[i][j], 0, 0, 0);
        __syncthreads();                      // LDS reads done; next iter may overwrite
    }
    // Epilogue. C/D layout: col(n) = lane&15, row(m) = (lane>>4)*4 + reg.
#pragma unroll
    for (int j = 0; j < WN; j++) {
        int n = n0 + wc * WCOLS + j * 16 + lm;
        float bb = bias[n];
#pragma unroll
        for (int i = 0; i < WM; i++) {
            int mb = m0 + wr * WROWS + i * 16 + lq * 4;
#pragma unroll
            for (int r = 0; r < 4; r++)
                out[(size_t)(mb + r) * N + n] = toB(acc[i][j][r] + bb);
        }
    }
}

// ---------------------------------------------------------------------------
// LEPE token-major: 5x5 depthwise conv on V read straight from qkv[s][512+c],
// output lepe[s][c] token-major. k_dw3_t-style: channels lane-fast (64 groups
// of 4), wave-uniform spatial position, fully coalesced 512B tap reads.
__global__ __launch_bounds__(256) void k_lepe_t(const bf16* __restrict__ qkv,
                                                const float* __restrict__ w_lepe,
                                                const float* __restrict__ b_lepe,
                                                bf16* __restrict__ lepe) {
    int tid = threadIdx.x;
    int cg = tid & 63;                  // 4-channel group, lane-fast
    int slot = tid >> 6;                // wave id 0..3 (wave-uniform)
    int bx = blockIdx.x;                // 0..127: y = bx>>1, x-half = bx&1
    int n = blockIdx.y;                 // image
    int y = bx >> 1;
    int x0 = (bx & 1) * 32 + slot * 8;  // 8 x-positions per thread
    float w[100], bias[4];
#pragma unroll
    for (int i = 0; i < 100; i++) w[i] = w_lepe[cg * 100 + i];
#pragma unroll
    for (int c = 0; c < 4; c++) bias[c] = b_lepe[cg * 4 + c];
    const bf16* vb = qkv + (size_t)n * HWSZ * QKVD + 512;
    bf16* dst = lepe + (size_t)n * HWSZ * CDIM;
#pragma unroll
    for (int xi = 0; xi < 8; xi++) {
        int x = x0 + xi;                // wave-uniform
        float o[4] = {bias[0], bias[1], bias[2], bias[3]};
#pragma unroll
        for (int dy = -2; dy <= 2; dy++) {
            int yy = y + dy;
            if (yy < 0 || yy >= HH) continue;       // wave-uniform
#pragma unroll
            for (int dx = -2; dx <= 2; dx++) {
                int xx = x + dx;
                if (xx < 0 || xx >= WW) continue;   // wave-uniform
                int k = (dy + 2) * 5 + (dx + 2);
                uint2 v = *(const uint2*)(vb + (size_t)(yy * WW + xx) * QKVD + cg * 4);
                const bf16* pv = (const bf16*)&v;
#pragma unroll
                for (int c = 0; c < 4; c++) o[c] += toF(pv[c]) * w[c * 25 + k];
            }
        }
        uint2 pk;
        bf16* pb = (bf16*)&pk;
#pragma unroll
        for (int c = 0; c < 4; c++) pb[c] = toB(o[c]);
        *(uint2*)(dst + (size_t)(y * WW + x) * CDIM + cg * 4) = pk;
    }
}

// ---------------------------------------------------------------------------
// MFMA attention: one block per (n, window). 256 thr = 4 waves, 2 heads/wave.
__global__ __launch_bounds__(256) void k_attn(const bf16* __restrict__ qkv,
                                              const int* __restrict__ topk,
                                              bf16* __restrict__ attnout) {
    __shared__ bf16 vst[256][72];      // V^T [dim][key], pad 72
    __shared__ bf16 plds[4][16][72];   // per-wave P [tok][key]
    __shared__ float lsm[4][16];       // per-wave softmax denominator per tok
    __shared__ int toks[64];           // routed key -> token index (within image)
    int b = blockIdx.x;
    int n = b >> 8, p = b & 255;
    int wy = p >> 4, wx = p & 15;
    int tid = threadIdx.x;
    if (tid < 64) {
        int rp = topk[((size_t)(n << 8) + p) * TOPK + (tid >> 4)] & 255;
        int st = tid & 15;
        toks[tid] = ((rp >> 4) * 4 + (st >> 2)) * WW + (rp & 15) * 4 + (st & 3);
    }
    __syncthreads();
    const bf16* qbase = qkv + (size_t)n * HWSZ * QKVD;
    {
        int kt = tid & 63, jj = tid >> 6;
#pragma unroll
        for (int pass = 0; pass < 8; pass++) {
            int d0 = pass * 32 + jj * 8;
            uint4 v = *(const uint4*)(qbase + (size_t)toks[kt] * QKVD + 512 + d0);
            const bf16* pv = (const bf16*)&v;
#pragma unroll
            for (int e = 0; e < 8; e++) vst[d0 + e][kt] = pv[e];
        }
    }
    __syncthreads();
    int w = tid >> 6, lane = tid & 63;
    int ln = lane & 15, lq = lane >> 4;
    int myS = (wy * 4 + (ln >> 2)) * WW + wx * 4 + (ln & 3);
    const f4v fz = {0.f, 0.f, 0.f, 0.f};
    for (int hh = 0; hh < 2; hh++) {
        int h = w * 2 + hh;
        s8v qf = *(const s8v*)(qbase + (size_t)myS * QKVD + h * 32 + lq * 8);
        f4v st4[4];
#pragma unroll
        for (int t = 0; t < 4; t++) {
            s8v kf = *(const s8v*)(qbase + (size_t)toks[t * 16 + ln] * QKVD + 256 + h * 32 + lq * 8);
            st4[t] = __builtin_amdgcn_mfma_f32_16x16x32_bf16(kf, qf, fz, 0, 0, 0);
        }
        float mx = -INFINITY;
#pragma unroll
        for (int t = 0; t < 4; t++)
#pragma unroll
            for (int r = 0; r < 4; r++) mx = fmaxf(mx, st4[t][r]);
        mx = fmaxf(mx, __shfl_xor(mx, 16));
        mx = fmaxf(mx, __shfl_xor(mx, 32));
        mx *= ATTN_SCALE;
        float sum = 0.f;
#pragma unroll
        for (int t = 0; t < 4; t++)
#pragma unroll
            for (int r = 0; r < 4; r++) {
                float pp = __expf(st4[t][r] * ATTN_SCALE - mx);
                sum += pp;
                plds[w][ln][t * 16 + lq * 4 + r] = toB(pp);
            }
        sum += __shfl_xor(sum, 16);
        sum += __shfl_xor(sum, 32);
        if (lq == 0) lsm[w][ln] = sum;
        __syncthreads();
        s8v ap0 = *(const s8v*)&plds[w][ln][lq * 8];
        s8v ap1 = *(const s8v*)&plds[w][ln][32 + lq * 8];
#pragma unroll
        for (int dt = 0; dt < 2; dt++) {
            int dim = h * 32 + dt * 16 + ln;
            s8v vv0 = *(const s8v*)&vst[dim][lq * 8];
            s8v vv1 = *(const s8v*)&vst[dim][32 + lq * 8];
            f4v o = __builtin_amdgcn_mfma_f32_16x16x32_bf16(ap0, vv0, fz, 0, 0, 0);
            o = __builtin_amdgcn_mfma_f32_16x16x32_bf16(ap1, vv1, o, 0, 0, 0);
#pragma unroll
            for (int r = 0; r < 4; r++) {
                int t = lq * 4 + r;
                float linv = 1.f / lsm[w][t];
                int s = (wy * 4 + (t >> 2)) * WW + wx * 4 + (t & 3);
                attnout[((size_t)n * HWSZ + s) * CDIM + dim] = toB(o[r] * linv);
            }
        }
        __syncthreads();
    }
}

// ---------------------------------------------------------------------------
// x1 = xt + attn + lepe  (ALL token-major now) — pure streaming elementwise.
__global__ __launch_bounds__(256) void k_x1(const bf16* __restrict__ xt,
                                            const bf16* __restrict__ lepe,
                                            const bf16* __restrict__ attnout,
                                            bf16* __restrict__ x1) {
    size_t i = ((size_t)blockIdx.x * 256 + threadIdx.x) * 8;
    uint4 a = *(const uint4*)(xt + i);
    uint4 b = *(const uint4*)(attnout + i);
    uint4 c = *(const uint4*)(lepe + i);
    const bf16* pa = (const bf16*)&a;
    const bf16* pb = (const bf16*)&b;
    const bf16* pc = (const bf16*)&c;
    uint4 r;
    bf16* pr = (bf16*)&r;
#pragma unroll
    for (int e = 0; e < 8; e++) pr[e] = toB(toF(pa[e]) + toF(pb[e]) + toF(pc[e]));
    *(uint4*)(x1 + i) = r;
}

// ---------------------------------------------------------------------------
// Depthwise 3x3 + bias + ReLU, token-major in/out, channels lane-fast.
__global__ __launch_bounds__(256) void k_dw3_t(const bf16* __restrict__ h1,
                                               const float* __restrict__ wdwT,
                                               bf16* __restrict__ h1p) {
    int tid = threadIdx.x;
    int cg = tid & 127;
    int slot = tid >> 7;
    int seg = blockIdx.x;
    int img = blockIdx.y;
    int y = seg >> 2;
    int x0 = ((seg & 3) << 4) + (slot << 3);
    const float* wp = wdwT + cg * 80;
    float w[72], bias[8];
#pragma unroll
    for (int i = 0; i < 72; i++) w[i] = wp[i];
#pragma unroll
    for (int c = 0; c < 8; c++) bias[c] = wp[72 + c];
    const uint4* src = (const uint4*)h1 + (size_t)img * HWSZ * 128;
    uint4* dst = (uint4*)h1p + (size_t)img * HWSZ * 128;
#pragma unroll
    for (int xi = 0; xi < 8; xi++) {
        int x = x0 + xi;
        float o[8];
#pragma unroll
        for (int c = 0; c < 8; c++) o[c] = bias[c];
#pragma unroll
        for (int dy = -1; dy <= 1; dy++) {
            int yy = y + dy;
            if (yy < 0 || yy >= HH) continue;
#pragma unroll
            for (int dx = -1; dx <= 1; dx++) {
                int xx = x + dx;
                if (xx < 0 || xx >= WW) continue;
                int k = (dy + 1) * 3 + (dx + 1);
                uint4 v = src[(size_t)(yy * WW + xx) * 128 + cg];
                const bf16* pv = (const bf16*)&v;
#pragma unroll
                for (int c = 0; c < 8; c++) o[c] += toF(pv[c]) * w[c * 9 + k];
            }
        }
        uint4 pk;
        bf16* pb = (bf16*)&pk;
#pragma unroll
        for (int c = 0; c < 8; c++) pb[c] = toB(fmaxf(o[c], 0.f));
        dst[(size_t)(y * WW + x) * 128 + cg] = pk;
    }
}

// ---------------------------------------------------------------------------
// out (NCHW fp32) = x1 + h2 (both token-major bf16)
__global__ void k_final(const bf16* __restrict__ x1, const bf16* __restrict__ h2,
                        float* __restrict__ out) {
    __shared__ float tile[32][33];
    int s0 = blockIdx.x * 32, c0 = blockIdx.y * 32, n = blockIdx.z;
    int tx = threadIdx.x, ty = threadIdx.y;
#pragma unroll
    for (int r = 0; r < 4; r++) {
        int s = s0 + ty + r * 8;
        size_t idx = ((size_t)n * HWSZ + s) * CDIM + c0 + tx;
        tile[tx][ty + r * 8] = toF(x1[idx]) + toF(h2[idx]);
    }
    __syncthreads();
#pragma unroll
    for (int r = 0; r < 4; r++) {
        int c = c0 + ty + r * 8;
        out[(size_t)n * CDIM * HWSZ + (size_t)c * HWSZ + s0 + tx] = tile[ty + r * 8][tx];
    }
}

// ---------------------------------------------------------------------------
extern "C" void kernel_launch(void* const* d_in, const int* in_sizes, int n_in,
                              void* d_out, int out_size, void* d_ws, size_t ws_size,
                              hipStream_t stream) {
    (void)in_sizes; (void)n_in; (void)out_size; (void)ws_size;
    const float* x      = (const float*)d_in[0];
    const float* wq     = (const float*)d_in[1];
    const float* gq     = (const float*)d_in[2];
    const float* bq     = (const float*)d_in[3];
    const float* wkv    = (const float*)d_in[4];
    const float* gkv    = (const float*)d_in[5];
    const float* bkv    = (const float*)d_in[6];
    const float* w_lepe = (const float*)d_in[7];
    const float* b_lepe = (const float*)d_in[8];
    const float* w_fc1  = (const float*)d_in[9];
    const float* g_fc1  = (const float*)d_in[10];
    const float* b_fc1  = (const float*)d_in[11];
    const float* w_dw   = (const float*)d_in[12];
    const float* b_dw   = (const float*)d_in[13];
    const float* w_fc2  = (const float*)d_in[14];
    const float* g_fc2  = (const float*)d_in[15];
    const float* b_fc2  = (const float*)d_in[16];

    char* ws = (char*)d_ws;
    bf16*  qkv    = (bf16*)(ws);
    bf16*  lepe   = (bf16*)(ws + 50331648);   // token-major now
    bf16*  attn   = (bf16*)(ws + 67108864);
    bf16*  xt     = (bf16*)(ws + 83886080);
    bf16*  x1     = (bf16*)(ws + 83886080);   // in-place over xt
    bf16*  h1     = (bf16*)(ws);              // phase B
    bf16*  h1p    = (bf16*)(ws + 33554432);
    bf16*  h2     = (bf16*)(ws + 67108864);
    float* xwin   = (float*)(ws + 100663296);
    float* qkwin  = (float*)(ws + 102760448);
    int*   tk     = (int*)(ws + 106954752);
    bf16*  wbqkv  = (bf16*)(ws + 106987520);
    bf16*  wbfc1  = (bf16*)(ws + 107380736);
    bf16*  wbfc2  = (bf16*)(ws + 107905024);
    float* bias768= (float*)(ws + 108429312);
    float* wdwT   = (float*)(ws + 108433408);  // 40 KB
    float* logits = (float*)(ws + 108478464);  // 2 MB

    k_prep<<<2856, 256, 0, stream>>>(wq, gq, wkv, gkv, w_fc1, g_fc1, w_fc2, g_fc2,
                                     bq, bkv, w_dw, b_dw,
                                     wbqkv, wbfc1, wbfc2, bias768, wdwT);
    k_xt<<<dim3(128, 8, 8), dim3(32, 8), 0, stream>>>(x, xt);
    k_xwin<<<2048, 256, 0, stream>>>(x, xwin);
    k_qkwin<<<dim3(32, 8), 256, 0, stream>>>(xwin, wq, wkv, gq, bq, gkv, bkv, qkwin);
    k_logits<<<dim3(4, 4, 8), 256, 0, stream>>>(qkwin, logits);
    k_topk<<<512, 256, 0, stream>>>(logits, tk);
    k_mfma<128, 128><<<dim3(256, 6), 256, 0, stream>>>(
        xt, wbqkv, bias768, qkv, TT, QKVD, CDIM);
    k_lepe_t<<<dim3(128, 8), 256, 0, stream>>>(qkv, w_lepe, b_lepe, lepe);
    k_attn<<<2048, 256, 0, stream>>>(qkv, tk, attn);
    k_x1<<<4096, 256, 0, stream>>>(xt, lepe, attn, x1);
    for (int c = 0; c < 2; c++) {
        bf16* x1c = x1 + (size_t)c * 16384 * CDIM;
        bf16* h2c = h2 + (size_t)c * 16384 * CDIM;
        k_mfma<128, 128><<<dim3(128, 8), 256, 0, stream>>>(
            x1c, wbfc1, b_fc1, h1, 16384, HID, CDIM);
        k_dw3_t<<<dim3(256, 4), 256, 0, stream>>>(h1, wdwT, h1p);
        k_mfma<64, 128><<<dim3(256, 2), 256, 0, stream>>>(
            h1p, wbfc2, b_fc2, h2c, 16384, CDIM, HID);
    }
    k_final<<<dim3(128, 8, 8), dim3(32, 8), 0, stream>>>(x1, h2, (float*)d_out);
}

// Round 5
// 444.115 us; speedup vs baseline: 1.0969x; 1.0969x over previous
//
#include <hip/hip_runtime.h>
#include <hip/hip_bf16.h>

#define NBATCH 8
#define CDIM 256
#define HH 64
#define WW 64
#define HWSZ 4096
#define TT 32768        // NBATCH * HWSZ tokens
#define QKVD 768        // q(256) | k(256) | v(256)
#define TOPK 4
#define HID 1024
#define ATTN_SCALE 0.0625f   // 256^-0.5

typedef __hip_bfloat16 bf16;
typedef __attribute__((ext_vector_type(8))) short s8v;   // 8 bf16 = 4 VGPR
typedef __attribute__((ext_vector_type(4))) float f4v;   // MFMA acc

__device__ __forceinline__ float toF(bf16 v) { return __bfloat162float(v); }
__device__ __forceinline__ bf16  toB(float v) { return __float2bfloat16(v); }

// async 16B global -> LDS (wave-uniform LDS base + lane*16)
__device__ __forceinline__ void gload_lds16(const bf16* g, bf16* l) {
    __builtin_amdgcn_global_load_lds(
        (const __attribute__((address_space(1))) void*)g,
        (__attribute__((address_space(3))) void*)l, 16, 0, 0);
}

// ---------------------------------------------------------------------------
// Prep: fold gamma into weights, cast to bf16; concat qkv bias; and build
// wdwT: per-cg-contiguous dw3 weights+bias fp32.
__global__ void k_prep(const float* __restrict__ wq, const float* __restrict__ gq,
                       const float* __restrict__ wkv, const float* __restrict__ gkv,
                       const float* __restrict__ wfc1, const float* __restrict__ gfc1,
                       const float* __restrict__ wfc2, const float* __restrict__ gfc2,
                       const float* __restrict__ bq, const float* __restrict__ bkv,
                       const float* __restrict__ w_dw, const float* __restrict__ b_dw,
                       bf16* __restrict__ wbqkv, bf16* __restrict__ wbfc1,
                       bf16* __restrict__ wbfc2, float* __restrict__ bias768,
                       float* __restrict__ wdwT) {
    int i = blockIdx.x * 256 + threadIdx.x;
    if (i < 196608) {                       // wbqkv [768][256]
        int r = i >> 8;
        float g = (r < 256) ? gq[r] : gkv[r - 256];
        float w = (r < 256) ? wq[i] : wkv[i - 65536];
        wbqkv[i] = toB(w * g);
        if (i < 768) bias768[i] = (i < 256) ? bq[i] : bkv[i - 256];
    } else if (i < 458752) {                // wbfc1 [1024][256]
        int j = i - 196608;
        wbfc1[j] = toB(wfc1[j] * gfc1[j >> 8]);
    } else if (i < 720896) {                // wbfc2 [256][1024]
        int j = i - 458752;
        wbfc2[j] = toB(wfc2[j] * gfc2[j >> 10]);
    } else if (i < 731136) {                // wdwT [128][80]
        int j = i - 720896;
        int cg = j / 80, r = j - cg * 80;
        wdwT[j] = (r < 72) ? w_dw[(cg * 8 + r / 9) * 9 + (r % 9)]
                           : b_dw[cg * 8 + (r - 72)];
    }
}

// ---------------------------------------------------------------------------
// x NCHW fp32 -> token-major bf16 xt[m][c]
__global__ void k_xt(const float* __restrict__ x, bf16* __restrict__ xt) {
    __shared__ float tile[32][33];
    int s0 = blockIdx.x * 32, c0 = blockIdx.y * 32, n = blockIdx.z;
    int tx = threadIdx.x, ty = threadIdx.y;
#pragma unroll
    for (int r = 0; r < 4; r++)
        tile[ty + r * 8][tx] = x[(size_t)n * CDIM * HWSZ + (size_t)(c0 + ty + r * 8) * HWSZ + s0 + tx];
    __syncthreads();
#pragma unroll
    for (int r = 0; r < 4; r++)
        xt[((size_t)n * HWSZ + s0 + ty + r * 8) * CDIM + c0 + tx] = toB(tile[tx][ty + r * 8]);
}

// ---------------------------------------------------------------------------
// Window means of x (fp32-exact routing path). Block=(n,c), thread=window p.
__global__ void k_xwin(const float* __restrict__ x, float* __restrict__ xwin) {
    int b = blockIdx.x;
    int n = b >> 8, c = b & 255;
    int p = threadIdx.x, wy = p >> 4, wx = p & 15;
    const float* pl = x + ((size_t)n * CDIM + c) * HWSZ;
    float s = 0.f;
#pragma unroll
    for (int dy = 0; dy < 4; dy++)
#pragma unroll
        for (int dx = 0; dx < 4; dx++)
            s += pl[(wy * 4 + dy) * WW + wx * 4 + dx];
    xwin[((size_t)(n << 8) + p) * 256 + c] = s * 0.0625f;
}

// ---------------------------------------------------------------------------
// qkwin[m][0:512] = (xwin @ [wq|wk]^T)*g + b  (fp32 vector GEMM, M=2048 K=256)
__global__ void k_qkwin(const float* __restrict__ xwin,
                        const float* __restrict__ wq, const float* __restrict__ wkv,
                        const float* __restrict__ gq, const float* __restrict__ bq,
                        const float* __restrict__ gkv, const float* __restrict__ bkv,
                        float* __restrict__ qkwin) {
    __shared__ float As[16][68];
    __shared__ float Bs[16][68];
    int m0 = blockIdx.x * 64, n0 = blockIdx.y * 64;
    int tid = threadIdx.x;
    int tx = tid & 15, ty = tid >> 4;
    float acc[4][4] = {};
    for (int k0 = 0; k0 < 256; k0 += 16) {
#pragma unroll
        for (int r = 0; r < 4; r++) {
            int lin = tid + r * 256;
            int row = lin >> 4, kk = lin & 15;
            As[kk][row] = xwin[(size_t)(m0 + row) * 256 + k0 + kk];
            int n = n0 + row;
            const float* wr = (n < 256) ? (wq + (size_t)n * 256) : (wkv + (size_t)(n - 256) * 256);
            Bs[kk][row] = wr[k0 + kk];
        }
        __syncthreads();
#pragma unroll
        for (int kk = 0; kk < 16; kk++) {
            float a[4], bb[4];
#pragma unroll
            for (int i = 0; i < 4; i++) a[i] = As[kk][tx * 4 + i];
#pragma unroll
            for (int j = 0; j < 4; j++) bb[j] = Bs[kk][ty * 4 + j];
#pragma unroll
            for (int i = 0; i < 4; i++)
#pragma unroll
                for (int j = 0; j < 4; j++) acc[i][j] += a[i] * bb[j];
        }
        __syncthreads();
    }
#pragma unroll
    for (int j = 0; j < 4; j++) {
        int n = n0 + ty * 4 + j;
        float gg = (n < 256) ? gq[n] : gkv[n - 256];
        float bb = (n < 256) ? bq[n] : bkv[n - 256];
#pragma unroll
        for (int i = 0; i < 4; i++)
            qkwin[(size_t)(m0 + tx * 4 + i) * 512 + n] = acc[i][j] * gg + bb;
    }
}

// ---------------------------------------------------------------------------
// Routing logits: per image, L[pq][key] = sum_c qwin[pq][c] * kwin[key][c].
__global__ void k_logits(const float* __restrict__ qkwin, float* __restrict__ logits) {
    __shared__ float As[16][68];
    __shared__ float Bs[16][68];
    int m0 = blockIdx.x * 64, n0 = blockIdx.y * 64, img = blockIdx.z;
    const float* base = qkwin + (size_t)(img << 8) * 512;
    int tid = threadIdx.x;
    int tx = tid & 15, ty = tid >> 4;
    float acc[4][4] = {};
    for (int k0 = 0; k0 < 256; k0 += 16) {
#pragma unroll
        for (int r = 0; r < 4; r++) {
            int lin = tid + r * 256;
            int row = lin >> 4, kk = lin & 15;
            As[kk][row] = base[(size_t)(m0 + row) * 512 + k0 + kk];
            Bs[kk][row] = base[(size_t)(n0 + row) * 512 + 256 + k0 + kk];
        }
        __syncthreads();
#pragma unroll
        for (int kk = 0; kk < 16; kk++) {
            float a[4], bb[4];
#pragma unroll
            for (int i = 0; i < 4; i++) a[i] = As[kk][tx * 4 + i];
#pragma unroll
            for (int j = 0; j < 4; j++) bb[j] = Bs[kk][ty * 4 + j];
#pragma unroll
            for (int i = 0; i < 4; i++)
#pragma unroll
                for (int j = 0; j < 4; j++) acc[i][j] += a[i] * bb[j];
        }
        __syncthreads();
    }
    float* Lr = logits + (size_t)(img << 8) * 256;
#pragma unroll
    for (int j = 0; j < 4; j++)
#pragma unroll
        for (int i = 0; i < 4; i++)
            Lr[(size_t)(m0 + tx * 4 + i) * 256 + n0 + ty * 4 + j] = acc[i][j];
}

// ---------------------------------------------------------------------------
// Top-4 per row of 256 logits: one wave per row, shuffle argmax, jax tie-break.
__global__ __launch_bounds__(256) void k_topk(const float* __restrict__ logits,
                                              int* __restrict__ topk) {
    int row = blockIdx.x * 4 + (threadIdx.x >> 6);
    int lane = threadIdx.x & 63;
    float4 v4 = *(const float4*)(logits + (size_t)row * 256 + lane * 4);
    float v[4] = {v4.x, v4.y, v4.z, v4.w};
#pragma unroll
    for (int sel = 0; sel < TOPK; sel++) {
        float mv = v[0]; int mi = lane * 4;
#pragma unroll
        for (int j = 1; j < 4; j++)
            if (v[j] > mv) { mv = v[j]; mi = lane * 4 + j; }
#pragma unroll
        for (int off = 1; off < 64; off <<= 1) {
            float ov = __shfl_xor(mv, off);
            int oi = __shfl_xor(mi, off);
            if (ov > mv || (ov == mv && oi < mi)) { mv = ov; mi = oi; }
        }
        if (lane == 0) topk[(size_t)row * TOPK + sel] = mi;
        if ((mi >> 2) == lane) v[mi & 3] = -INFINITY;
    }
}

// ---------------------------------------------------------------------------
// MFMA GEMM with global_load_lds width-16 staging; XCD swizzle (T1).
template <int BM, int BN>
__global__ __launch_bounds__(256) void k_mfma(const bf16* __restrict__ A,
                                              const bf16* __restrict__ Wb,
                                              const float* __restrict__ bias,
                                              bf16* __restrict__ out,
                                              int M, int N, int K) {
    constexpr int WROWS = BM / 2, WCOLS = BN / 2;     // per-wave quadrant
    constexpr int WM = WROWS / 16, WN = WCOLS / 16;   // 16x16 tiles per wave
    constexpr int CA = (BM * 4) / 256;                // 16B chunks/thread for A
    constexpr int CB = (BN * 4) / 256;
    __shared__ bf16 As[BM * 32];
    __shared__ bf16 Bs[BN * 32];
    int gx = gridDim.x;
    int lin = blockIdx.x + blockIdx.y * gx;
    int tot = gx * gridDim.y;
    int cpx = tot >> 3;
    int swz = (lin & 7) * cpx + (lin >> 3);
    int m0 = (swz % gx) * BM, n0 = (swz / gx) * BN;
    int tid = threadIdx.x;
    int w = tid >> 6, lane = tid & 63;
    int wr = w >> 1, wc = w & 1;
    int lm = lane & 15, lq = lane >> 4;
    f4v acc[WM][WN];
#pragma unroll
    for (int i = 0; i < WM; i++)
#pragma unroll
        for (int j = 0; j < WN; j++) acc[i][j] = (f4v){0.f, 0.f, 0.f, 0.f};

    for (int k0 = 0; k0 < K; k0 += 32) {
#pragma unroll
        for (int q = 0; q < CA; q++) {
            int c = tid + q * 256, row = c >> 2, col = c & 3;
            gload_lds16(A + (size_t)(m0 + row) * K + k0 + col * 8,
                        As + (size_t)(w * 64 + q * 256) * 8);
        }
#pragma unroll
        for (int q = 0; q < CB; q++) {
            int c = tid + q * 256, row = c >> 2, col = c & 3;
            gload_lds16(Wb + (size_t)(n0 + row) * K + k0 + col * 8,
                        Bs + (size_t)(w * 64 + q * 256) * 8);
        }
        asm volatile("s_waitcnt vmcnt(0)" ::: "memory");
        __syncthreads();                      // staged tile visible
        s8v af[WM], bfr[WN];
#pragma unroll
        for (int i = 0; i < WM; i++)
            af[i] = *(const s8v*)&As[(wr * WROWS + i * 16 + lm) * 32 + lq * 8];
#pragma unroll
        for (int j = 0; j < WN; j++)
            bfr[j] = *(const s8v*)&Bs[(wc * WCOLS + j * 16 + lm) * 32 + lq * 8];
#pragma unroll
        for (int i = 0; i < WM; i++)
#pragma unroll
            for (int j = 0; j < WN; j++)
                acc[i][j] = __builtin_amdgcn_mfma_f32_16x16x32_bf16(af[i], bfr[j], acc[i][j], 0, 0, 0);
        __syncthreads();                      // LDS reads done; next iter may overwrite
    }
#pragma unroll
    for (int j = 0; j < WN; j++) {
        int n = n0 + wc * WCOLS + j * 16 + lm;
        float bb = bias[n];
#pragma unroll
        for (int i = 0; i < WM; i++) {
            int mb = m0 + wr * WROWS + i * 16 + lq * 4;
#pragma unroll
            for (int r = 0; r < 4; r++)
                out[(size_t)(mb + r) * N + n] = toB(acc[i][j][r] + bb);
        }
    }
}

// ---------------------------------------------------------------------------
// LEPE token-major v2: per-image XCD affinity (blockIdx&7 = image, so each
// XCD's V working set is 2MB < 4MB L2) + per-row register sliding window
// (12 unique loads per conv row instead of 40).
__global__ __launch_bounds__(256) void k_lepe_t(const bf16* __restrict__ qkv,
                                                const float* __restrict__ w_lepe,
                                                const float* __restrict__ b_lepe,
                                                bf16* __restrict__ lepe) {
    int tid = threadIdx.x;
    int cg = tid & 63;                  // 4-channel group, lane-fast
    int slot = tid >> 6;                // wave id 0..3 (wave-uniform)
    int b = blockIdx.x;                 // 0..1023
    int n = b & 7;                      // image -> XCD (round-robin d%8)
    int bx = b >> 3;                    // 0..127: y = bx>>1, x-half = bx&1
    int y = bx >> 1;
    int x0 = (bx & 1) * 32 + slot * 8;  // 8 x-positions per thread
    float w[100], bias4[4];
#pragma unroll
    for (int i = 0; i < 100; i++) w[i] = w_lepe[cg * 100 + i];
#pragma unroll
    for (int c = 0; c < 4; c++) bias4[c] = b_lepe[cg * 4 + c];
    const bf16* vb = qkv + (size_t)n * HWSZ * QKVD + 512;
    bf16* dst = lepe + (size_t)n * HWSZ * CDIM;
    float o[8][4];
#pragma unroll
    for (int xi = 0; xi < 8; xi++)
#pragma unroll
        for (int c = 0; c < 4; c++) o[xi][c] = bias4[c];
#pragma unroll
    for (int dy = -2; dy <= 2; dy++) {
        int yy = y + dy;
        if (yy < 0 || yy >= HH) continue;          // wave-uniform
        float rf[12][4];
#pragma unroll
        for (int ii = 0; ii < 12; ii++) {
            int xx = x0 - 2 + ii;
            if (xx >= 0 && xx < WW) {              // wave-uniform
                uint2 v = *(const uint2*)(vb + (size_t)(yy * WW + xx) * QKVD + cg * 4);
                const bf16* pv = (const bf16*)&v;
#pragma unroll
                for (int c = 0; c < 4; c++) rf[ii][c] = toF(pv[c]);
            } else {
#pragma unroll
                for (int c = 0; c < 4; c++) rf[ii][c] = 0.f;
            }
        }
#pragma unroll
        for (int xi = 0; xi < 8; xi++)
#pragma unroll
            for (int dx = 0; dx < 5; dx++) {
                int k = (dy + 2) * 5 + dx;
#pragma unroll
                for (int c = 0; c < 4; c++) o[xi][c] += rf[xi + dx][c] * w[c * 25 + k];
            }
    }
#pragma unroll
    for (int xi = 0; xi < 8; xi++) {
        uint2 pk;
        bf16* pb = (bf16*)&pk;
#pragma unroll
        for (int c = 0; c < 4; c++) pb[c] = toB(o[xi][c]);
        *(uint2*)(dst + (size_t)(y * WW + x0 + xi) * CDIM + cg * 4) = pk;
    }
}

// ---------------------------------------------------------------------------
// MFMA attention: one block per (n, window). 256 thr = 4 waves, 2 heads/wave.
__global__ __launch_bounds__(256) void k_attn(const bf16* __restrict__ qkv,
                                              const int* __restrict__ topk,
                                              bf16* __restrict__ attnout) {
    __shared__ bf16 vst[256][72];      // V^T [dim][key], pad 72
    __shared__ bf16 plds[4][16][72];   // per-wave P [tok][key]
    __shared__ float lsm[4][16];       // per-wave softmax denominator per tok
    __shared__ int toks[64];           // routed key -> token index (within image)
    int b = blockIdx.x;
    int n = b >> 8, p = b & 255;
    int wy = p >> 4, wx = p & 15;
    int tid = threadIdx.x;
    if (tid < 64) {
        int rp = topk[((size_t)(n << 8) + p) * TOPK + (tid >> 4)] & 255;
        int st = tid & 15;
        toks[tid] = ((rp >> 4) * 4 + (st >> 2)) * WW + (rp & 15) * 4 + (st & 3);
    }
    __syncthreads();
    const bf16* qbase = qkv + (size_t)n * HWSZ * QKVD;
    {
        int kt = tid & 63, jj = tid >> 6;
#pragma unroll
        for (int pass = 0; pass < 8; pass++) {
            int d0 = pass * 32 + jj * 8;
            uint4 v = *(const uint4*)(qbase + (size_t)toks[kt] * QKVD + 512 + d0);
            const bf16* pv = (const bf16*)&v;
#pragma unroll
            for (int e = 0; e < 8; e++) vst[d0 + e][kt] = pv[e];
        }
    }
    __syncthreads();
    int w = tid >> 6, lane = tid & 63;
    int ln = lane & 15, lq = lane >> 4;
    int myS = (wy * 4 + (ln >> 2)) * WW + wx * 4 + (ln & 3);
    const f4v fz = {0.f, 0.f, 0.f, 0.f};
    for (int hh = 0; hh < 2; hh++) {
        int h = w * 2 + hh;
        s8v qf = *(const s8v*)(qbase + (size_t)myS * QKVD + h * 32 + lq * 8);
        f4v st4[4];
#pragma unroll
        for (int t = 0; t < 4; t++) {
            s8v kf = *(const s8v*)(qbase + (size_t)toks[t * 16 + ln] * QKVD + 256 + h * 32 + lq * 8);
            st4[t] = __builtin_amdgcn_mfma_f32_16x16x32_bf16(kf, qf, fz, 0, 0, 0);
        }
        float mx = -INFINITY;
#pragma unroll
        for (int t = 0; t < 4; t++)
#pragma unroll
            for (int r = 0; r < 4; r++) mx = fmaxf(mx, st4[t][r]);
        mx = fmaxf(mx, __shfl_xor(mx, 16));
        mx = fmaxf(mx, __shfl_xor(mx, 32));
        mx *= ATTN_SCALE;
        float sum = 0.f;
#pragma unroll
        for (int t = 0; t < 4; t++)
#pragma unroll
            for (int r = 0; r < 4; r++) {
                float pp = __expf(st4[t][r] * ATTN_SCALE - mx);
                sum += pp;
                plds[w][ln][t * 16 + lq * 4 + r] = toB(pp);
            }
        sum += __shfl_xor(sum, 16);
        sum += __shfl_xor(sum, 32);
        if (lq == 0) lsm[w][ln] = sum;
        __syncthreads();
        s8v ap0 = *(const s8v*)&plds[w][ln][lq * 8];
        s8v ap1 = *(const s8v*)&plds[w][ln][32 + lq * 8];
#pragma unroll
        for (int dt = 0; dt < 2; dt++) {
            int dim = h * 32 + dt * 16 + ln;
            s8v vv0 = *(const s8v*)&vst[dim][lq * 8];
            s8v vv1 = *(const s8v*)&vst[dim][32 + lq * 8];
            f4v o = __builtin_amdgcn_mfma_f32_16x16x32_bf16(ap0, vv0, fz, 0, 0, 0);
            o = __builtin_amdgcn_mfma_f32_16x16x32_bf16(ap1, vv1, o, 0, 0, 0);
#pragma unroll
            for (int r = 0; r < 4; r++) {
                int t = lq * 4 + r;
                float linv = 1.f / lsm[w][t];
                int s = (wy * 4 + (t >> 2)) * WW + wx * 4 + (t & 3);
                attnout[((size_t)n * HWSZ + s) * CDIM + dim] = toB(o[r] * linv);
            }
        }
        __syncthreads();
    }
}

// ---------------------------------------------------------------------------
// x1 = xt + attn + lepe  (all token-major) — pure streaming elementwise.
__global__ __launch_bounds__(256) void k_x1(const bf16* __restrict__ xt,
                                            const bf16* __restrict__ lepe,
                                            const bf16* __restrict__ attnout,
                                            bf16* __restrict__ x1) {
    size_t i = ((size_t)blockIdx.x * 256 + threadIdx.x) * 8;
    uint4 a = *(const uint4*)(xt + i);
    uint4 b = *(const uint4*)(attnout + i);
    uint4 c = *(const uint4*)(lepe + i);
    const bf16* pa = (const bf16*)&a;
    const bf16* pb = (const bf16*)&b;
    const bf16* pc = (const bf16*)&c;
    uint4 r;
    bf16* pr = (bf16*)&r;
#pragma unroll
    for (int e = 0; e < 8; e++) pr[e] = toB(toF(pa[e]) + toF(pb[e]) + toF(pc[e]));
    *(uint4*)(x1 + i) = r;
}

// ---------------------------------------------------------------------------
// Depthwise 3x3 + bias + ReLU, token-major in/out, channels lane-fast.
__global__ __launch_bounds__(256) void k_dw3_t(const bf16* __restrict__ h1,
                                               const float* __restrict__ wdwT,
                                               bf16* __restrict__ h1p) {
    int tid = threadIdx.x;
    int cg = tid & 127;
    int slot = tid >> 7;
    int seg = blockIdx.x;
    int img = blockIdx.y;
    int y = seg >> 2;
    int x0 = ((seg & 3) << 4) + (slot << 3);
    const float* wp = wdwT + cg * 80;
    float w[72], bias[8];
#pragma unroll
    for (int i = 0; i < 72; i++) w[i] = wp[i];
#pragma unroll
    for (int c = 0; c < 8; c++) bias[c] = wp[72 + c];
    const uint4* src = (const uint4*)h1 + (size_t)img * HWSZ * 128;
    uint4* dst = (uint4*)h1p + (size_t)img * HWSZ * 128;
#pragma unroll
    for (int xi = 0; xi < 8; xi++) {
        int x = x0 + xi;
        float o[8];
#pragma unroll
        for (int c = 0; c < 8; c++) o[c] = bias[c];
#pragma unroll
        for (int dy = -1; dy <= 1; dy++) {
            int yy = y + dy;
            if (yy < 0 || yy >= HH) continue;
#pragma unroll
            for (int dx = -1; dx <= 1; dx++) {
                int xx = x + dx;
                if (xx < 0 || xx >= WW) continue;
                int k = (dy + 1) * 3 + (dx + 1);
                uint4 v = src[(size_t)(yy * WW + xx) * 128 + cg];
                const bf16* pv = (const bf16*)&v;
#pragma unroll
                for (int c = 0; c < 8; c++) o[c] += toF(pv[c]) * w[c * 9 + k];
            }
        }
        uint4 pk;
        bf16* pb = (bf16*)&pk;
#pragma unroll
        for (int c = 0; c < 8; c++) pb[c] = toB(fmaxf(o[c], 0.f));
        dst[(size_t)(y * WW + x) * 128 + cg] = pk;
    }
}

// ---------------------------------------------------------------------------
// out (NCHW fp32) = x1 + h2 (both token-major bf16)
__global__ void k_final(const bf16* __restrict__ x1, const bf16* __restrict__ h2,
                        float* __restrict__ out) {
    __shared__ float tile[32][33];
    int s0 = blockIdx.x * 32, c0 = blockIdx.y * 32, n = blockIdx.z;
    int tx = threadIdx.x, ty = threadIdx.y;
#pragma unroll
    for (int r = 0; r < 4; r++) {
        int s = s0 + ty + r * 8;
        size_t idx = ((size_t)n * HWSZ + s) * CDIM + c0 + tx;
        tile[tx][ty + r * 8] = toF(x1[idx]) + toF(h2[idx]);
    }
    __syncthreads();
#pragma unroll
    for (int r = 0; r < 4; r++) {
        int c = c0 + ty + r * 8;
        out[(size_t)n * CDIM * HWSZ + (size_t)c * HWSZ + s0 + tx] = tile[ty + r * 8][tx];
    }
}

// ---------------------------------------------------------------------------
extern "C" void kernel_launch(void* const* d_in, const int* in_sizes, int n_in,
                              void* d_out, int out_size, void* d_ws, size_t ws_size,
                              hipStream_t stream) {
    (void)in_sizes; (void)n_in; (void)out_size; (void)ws_size;
    const float* x      = (const float*)d_in[0];
    const float* wq     = (const float*)d_in[1];
    const float* gq     = (const float*)d_in[2];
    const float* bq     = (const float*)d_in[3];
    const float* wkv    = (const float*)d_in[4];
    const float* gkv    = (const float*)d_in[5];
    const float* bkv    = (const float*)d_in[6];
    const float* w_lepe = (const float*)d_in[7];
    const float* b_lepe = (const float*)d_in[8];
    const float* w_fc1  = (const float*)d_in[9];
    const float* g_fc1  = (const float*)d_in[10];
    const float* b_fc1  = (const float*)d_in[11];
    const float* w_dw   = (const float*)d_in[12];
    const float* b_dw   = (const float*)d_in[13];
    const float* w_fc2  = (const float*)d_in[14];
    const float* g_fc2  = (const float*)d_in[15];
    const float* b_fc2  = (const float*)d_in[16];

    char* ws = (char*)d_ws;
    bf16*  qkv    = (bf16*)(ws);
    bf16*  lepe   = (bf16*)(ws + 50331648);   // token-major
    bf16*  attn   = (bf16*)(ws + 67108864);
    bf16*  xt     = (bf16*)(ws + 83886080);
    bf16*  x1     = (bf16*)(ws + 83886080);   // in-place over xt
    bf16*  h1     = (bf16*)(ws);              // phase B
    bf16*  h1p    = (bf16*)(ws + 33554432);
    bf16*  h2     = (bf16*)(ws + 67108864);
    float* xwin   = (float*)(ws + 100663296);
    float* qkwin  = (float*)(ws + 102760448);
    int*   tk     = (int*)(ws + 106954752);
    bf16*  wbqkv  = (bf16*)(ws + 106987520);
    bf16*  wbfc1  = (bf16*)(ws + 107380736);
    bf16*  wbfc2  = (bf16*)(ws + 107905024);
    float* bias768= (float*)(ws + 108429312);
    float* wdwT   = (float*)(ws + 108433408);  // 40 KB
    float* logits = (float*)(ws + 108478464);  // 2 MB

    k_prep<<<2856, 256, 0, stream>>>(wq, gq, wkv, gkv, w_fc1, g_fc1, w_fc2, g_fc2,
                                     bq, bkv, w_dw, b_dw,
                                     wbqkv, wbfc1, wbfc2, bias768, wdwT);
    k_xt<<<dim3(128, 8, 8), dim3(32, 8), 0, stream>>>(x, xt);
    k_xwin<<<2048, 256, 0, stream>>>(x, xwin);
    k_qkwin<<<dim3(32, 8), 256, 0, stream>>>(xwin, wq, wkv, gq, bq, gkv, bkv, qkwin);
    k_logits<<<dim3(4, 4, 8), 256, 0, stream>>>(qkwin, logits);
    k_topk<<<512, 256, 0, stream>>>(logits, tk);
    k_mfma<128, 128><<<dim3(256, 6), 256, 0, stream>>>(
        xt, wbqkv, bias768, qkv, TT, QKVD, CDIM);
    k_lepe_t<<<1024, 256, 0, stream>>>(qkv, w_lepe, b_lepe, lepe);
    k_attn<<<2048, 256, 0, stream>>>(qkv, tk, attn);
    k_x1<<<4096, 256, 0, stream>>>(xt, lepe, attn, x1);
    for (int c = 0; c < 2; c++) {
        bf16* x1c = x1 + (size_t)c * 16384 * CDIM;
        bf16* h2c = h2 + (size_t)c * 16384 * CDIM;
        k_mfma<128, 128><<<dim3(128, 8), 256, 0, stream>>>(
            x1c, wbfc1, b_fc1, h1, 16384, HID, CDIM);
        k_dw3_t<<<dim3(256, 4), 256, 0, stream>>>(h1, wdwT, h1p);
        k_mfma<64, 128><<<dim3(256, 2), 256, 0, stream>>>(
            h1p, wbfc2, b_fc2, h2c, 16384, CDIM, HID);
    }
    k_final<<<dim3(128, 8, 8), dim3(32, 8), 0, stream>>>(x1, h2, (float*)d_out);
}

// Round 6
// 429.766 us; speedup vs baseline: 1.1335x; 1.0334x over previous
//
#include <hip/hip_runtime.h>
#include <hip/hip_bf16.h>

#define NBATCH 8
#define CDIM 256
#define HH 64
#define WW 64
#define HWSZ 4096
#define TT 32768        // NBATCH * HWSZ tokens
#define QKVD 768        // q(256) | k(256) | v(256)
#define TOPK 4
#define HID 1024
#define ATTN_SCALE 0.0625f   // 256^-0.5

typedef __hip_bfloat16 bf16;
typedef __attribute__((ext_vector_type(8))) short s8v;   // 8 bf16 = 4 VGPR
typedef __attribute__((ext_vector_type(4))) float f4v;   // MFMA acc

__device__ __forceinline__ float toF(bf16 v) { return __bfloat162float(v); }
__device__ __forceinline__ bf16  toB(float v) { return __float2bfloat16(v); }

// async 16B global -> LDS (wave-uniform LDS base + lane*16)
__device__ __forceinline__ void gload_lds16(const bf16* g, bf16* l) {
    __builtin_amdgcn_global_load_lds(
        (const __attribute__((address_space(1))) void*)g,
        (__attribute__((address_space(3))) void*)l, 16, 0, 0);
}

// ---------------------------------------------------------------------------
// Prep: fold gamma into weights, cast to bf16; concat qkv bias; and build
// wdwT: per-cg-contiguous dw3 weights+bias fp32.
__global__ void k_prep(const float* __restrict__ wq, const float* __restrict__ gq,
                       const float* __restrict__ wkv, const float* __restrict__ gkv,
                       const float* __restrict__ wfc1, const float* __restrict__ gfc1,
                       const float* __restrict__ wfc2, const float* __restrict__ gfc2,
                       const float* __restrict__ bq, const float* __restrict__ bkv,
                       const float* __restrict__ w_dw, const float* __restrict__ b_dw,
                       bf16* __restrict__ wbqkv, bf16* __restrict__ wbfc1,
                       bf16* __restrict__ wbfc2, float* __restrict__ bias768,
                       float* __restrict__ wdwT) {
    int i = blockIdx.x * 256 + threadIdx.x;
    if (i < 196608) {                       // wbqkv [768][256]
        int r = i >> 8;
        float g = (r < 256) ? gq[r] : gkv[r - 256];
        float w = (r < 256) ? wq[i] : wkv[i - 65536];
        wbqkv[i] = toB(w * g);
        if (i < 768) bias768[i] = (i < 256) ? bq[i] : bkv[i - 256];
    } else if (i < 458752) {                // wbfc1 [1024][256]
        int j = i - 196608;
        wbfc1[j] = toB(wfc1[j] * gfc1[j >> 8]);
    } else if (i < 720896) {                // wbfc2 [256][1024]
        int j = i - 458752;
        wbfc2[j] = toB(wfc2[j] * gfc2[j >> 10]);
    } else if (i < 731136) {                // wdwT [128][80]
        int j = i - 720896;
        int cg = j / 80, r = j - cg * 80;
        wdwT[j] = (r < 72) ? w_dw[(cg * 8 + r / 9) * 9 + (r % 9)]
                           : b_dw[cg * 8 + (r - 72)];
    }
}

// ---------------------------------------------------------------------------
// x NCHW fp32 -> token-major bf16 xt[m][c]
__global__ void k_xt(const float* __restrict__ x, bf16* __restrict__ xt) {
    __shared__ float tile[32][33];
    int s0 = blockIdx.x * 32, c0 = blockIdx.y * 32, n = blockIdx.z;
    int tx = threadIdx.x, ty = threadIdx.y;
#pragma unroll
    for (int r = 0; r < 4; r++)
        tile[ty + r * 8][tx] = x[(size_t)n * CDIM * HWSZ + (size_t)(c0 + ty + r * 8) * HWSZ + s0 + tx];
    __syncthreads();
#pragma unroll
    for (int r = 0; r < 4; r++)
        xt[((size_t)n * HWSZ + s0 + ty + r * 8) * CDIM + c0 + tx] = toB(tile[tx][ty + r * 8]);
}

// ---------------------------------------------------------------------------
// Window means of x (fp32-exact routing path). Block=(n,c), thread=window p.
__global__ void k_xwin(const float* __restrict__ x, float* __restrict__ xwin) {
    int b = blockIdx.x;
    int n = b >> 8, c = b & 255;
    int p = threadIdx.x, wy = p >> 4, wx = p & 15;
    const float* pl = x + ((size_t)n * CDIM + c) * HWSZ;
    float s = 0.f;
#pragma unroll
    for (int dy = 0; dy < 4; dy++)
#pragma unroll
        for (int dx = 0; dx < 4; dx++)
            s += pl[(wy * 4 + dy) * WW + wx * 4 + dx];
    xwin[((size_t)(n << 8) + p) * 256 + c] = s * 0.0625f;
}

// ---------------------------------------------------------------------------
// qkwin[m][0:512] = (xwin @ [wq|wk]^T)*g + b  (fp32 vector GEMM, M=2048 K=256)
__global__ void k_qkwin(const float* __restrict__ xwin,
                        const float* __restrict__ wq, const float* __restrict__ wkv,
                        const float* __restrict__ gq, const float* __restrict__ bq,
                        const float* __restrict__ gkv, const float* __restrict__ bkv,
                        float* __restrict__ qkwin) {
    __shared__ float As[16][68];
    __shared__ float Bs[16][68];
    int m0 = blockIdx.x * 64, n0 = blockIdx.y * 64;
    int tid = threadIdx.x;
    int tx = tid & 15, ty = tid >> 4;
    float acc[4][4] = {};
    for (int k0 = 0; k0 < 256; k0 += 16) {
#pragma unroll
        for (int r = 0; r < 4; r++) {
            int lin = tid + r * 256;
            int row = lin >> 4, kk = lin & 15;
            As[kk][row] = xwin[(size_t)(m0 + row) * 256 + k0 + kk];
            int n = n0 + row;
            const float* wr = (n < 256) ? (wq + (size_t)n * 256) : (wkv + (size_t)(n - 256) * 256);
            Bs[kk][row] = wr[k0 + kk];
        }
        __syncthreads();
#pragma unroll
        for (int kk = 0; kk < 16; kk++) {
            float a[4], bb[4];
#pragma unroll
            for (int i = 0; i < 4; i++) a[i] = As[kk][tx * 4 + i];
#pragma unroll
            for (int j = 0; j < 4; j++) bb[j] = Bs[kk][ty * 4 + j];
#pragma unroll
            for (int i = 0; i < 4; i++)
#pragma unroll
                for (int j = 0; j < 4; j++) acc[i][j] += a[i] * bb[j];
        }
        __syncthreads();
    }
#pragma unroll
    for (int j = 0; j < 4; j++) {
        int n = n0 + ty * 4 + j;
        float gg = (n < 256) ? gq[n] : gkv[n - 256];
        float bb = (n < 256) ? bq[n] : bkv[n - 256];
#pragma unroll
        for (int i = 0; i < 4; i++)
            qkwin[(size_t)(m0 + tx * 4 + i) * 512 + n] = acc[i][j] * gg + bb;
    }
}

// ---------------------------------------------------------------------------
// Routing logits: per image, L[pq][key] = sum_c qwin[pq][c] * kwin[key][c].
__global__ void k_logits(const float* __restrict__ qkwin, float* __restrict__ logits) {
    __shared__ float As[16][68];
    __shared__ float Bs[16][68];
    int m0 = blockIdx.x * 64, n0 = blockIdx.y * 64, img = blockIdx.z;
    const float* base = qkwin + (size_t)(img << 8) * 512;
    int tid = threadIdx.x;
    int tx = tid & 15, ty = tid >> 4;
    float acc[4][4] = {};
    for (int k0 = 0; k0 < 256; k0 += 16) {
#pragma unroll
        for (int r = 0; r < 4; r++) {
            int lin = tid + r * 256;
            int row = lin >> 4, kk = lin & 15;
            As[kk][row] = base[(size_t)(m0 + row) * 512 + k0 + kk];
            Bs[kk][row] = base[(size_t)(n0 + row) * 512 + 256 + k0 + kk];
        }
        __syncthreads();
#pragma unroll
        for (int kk = 0; kk < 16; kk++) {
            float a[4], bb[4];
#pragma unroll
            for (int i = 0; i < 4; i++) a[i] = As[kk][tx * 4 + i];
#pragma unroll
            for (int j = 0; j < 4; j++) bb[j] = Bs[kk][ty * 4 + j];
#pragma unroll
            for (int i = 0; i < 4; i++)
#pragma unroll
                for (int j = 0; j < 4; j++) acc[i][j] += a[i] * bb[j];
        }
        __syncthreads();
    }
    float* Lr = logits + (size_t)(img << 8) * 256;
#pragma unroll
    for (int j = 0; j < 4; j++)
#pragma unroll
        for (int i = 0; i < 4; i++)
            Lr[(size_t)(m0 + tx * 4 + i) * 256 + n0 + ty * 4 + j] = acc[i][j];
}

// ---------------------------------------------------------------------------
// Top-4 per row of 256 logits: one wave per row, shuffle argmax, jax tie-break.
__global__ __launch_bounds__(256) void k_topk(const float* __restrict__ logits,
                                              int* __restrict__ topk) {
    int row = blockIdx.x * 4 + (threadIdx.x >> 6);
    int lane = threadIdx.x & 63;
    float4 v4 = *(const float4*)(logits + (size_t)row * 256 + lane * 4);
    float v[4] = {v4.x, v4.y, v4.z, v4.w};
#pragma unroll
    for (int sel = 0; sel < TOPK; sel++) {
        float mv = v[0]; int mi = lane * 4;
#pragma unroll
        for (int j = 1; j < 4; j++)
            if (v[j] > mv) { mv = v[j]; mi = lane * 4 + j; }
#pragma unroll
        for (int off = 1; off < 64; off <<= 1) {
            float ov = __shfl_xor(mv, off);
            int oi = __shfl_xor(mi, off);
            if (ov > mv || (ov == mv && oi < mi)) { mv = ov; mi = oi; }
        }
        if (lane == 0) topk[(size_t)row * TOPK + sel] = mi;
        if ((mi >> 2) == lane) v[mi & 3] = -INFINITY;
    }
}

// ---------------------------------------------------------------------------
// MFMA GEMM with global_load_lds width-16 staging; XCD swizzle (T1).
template <int BM, int BN>
__global__ __launch_bounds__(256) void k_mfma(const bf16* __restrict__ A,
                                              const bf16* __restrict__ Wb,
                                              const float* __restrict__ bias,
                                              bf16* __restrict__ out,
                                              int M, int N, int K) {
    constexpr int WROWS = BM / 2, WCOLS = BN / 2;     // per-wave quadrant
    constexpr int WM = WROWS / 16, WN = WCOLS / 16;   // 16x16 tiles per wave
    constexpr int CA = (BM * 4) / 256;                // 16B chunks/thread for A
    constexpr int CB = (BN * 4) / 256;
    __shared__ bf16 As[BM * 32];
    __shared__ bf16 Bs[BN * 32];
    int gx = gridDim.x;
    int lin = blockIdx.x + blockIdx.y * gx;
    int tot = gx * gridDim.y;
    int cpx = tot >> 3;
    int swz = (lin & 7) * cpx + (lin >> 3);
    int m0 = (swz % gx) * BM, n0 = (swz / gx) * BN;
    int tid = threadIdx.x;
    int w = tid >> 6, lane = tid & 63;
    int wr = w >> 1, wc = w & 1;
    int lm = lane & 15, lq = lane >> 4;
    f4v acc[WM][WN];
#pragma unroll
    for (int i = 0; i < WM; i++)
#pragma unroll
        for (int j = 0; j < WN; j++) acc[i][j] = (f4v){0.f, 0.f, 0.f, 0.f};

    for (int k0 = 0; k0 < K; k0 += 32) {
#pragma unroll
        for (int q = 0; q < CA; q++) {
            int c = tid + q * 256, row = c >> 2, col = c & 3;
            gload_lds16(A + (size_t)(m0 + row) * K + k0 + col * 8,
                        As + (size_t)(w * 64 + q * 256) * 8);
        }
#pragma unroll
        for (int q = 0; q < CB; q++) {
            int c = tid + q * 256, row = c >> 2, col = c & 3;
            gload_lds16(Wb + (size_t)(n0 + row) * K + k0 + col * 8,
                        Bs + (size_t)(w * 64 + q * 256) * 8);
        }
        asm volatile("s_waitcnt vmcnt(0)" ::: "memory");
        __syncthreads();                      // staged tile visible
        s8v af[WM], bfr[WN];
#pragma unroll
        for (int i = 0; i < WM; i++)
            af[i] = *(const s8v*)&As[(wr * WROWS + i * 16 + lm) * 32 + lq * 8];
#pragma unroll
        for (int j = 0; j < WN; j++)
            bfr[j] = *(const s8v*)&Bs[(wc * WCOLS + j * 16 + lm) * 32 + lq * 8];
#pragma unroll
        for (int i = 0; i < WM; i++)
#pragma unroll
            for (int j = 0; j < WN; j++)
                acc[i][j] = __builtin_amdgcn_mfma_f32_16x16x32_bf16(af[i], bfr[j], acc[i][j], 0, 0, 0);
        __syncthreads();                      // LDS reads done; next iter may overwrite
    }
#pragma unroll
    for (int j = 0; j < WN; j++) {
        int n = n0 + wc * WCOLS + j * 16 + lm;
        float bb = bias[n];
#pragma unroll
        for (int i = 0; i < WM; i++) {
            int mb = m0 + wr * WROWS + i * 16 + lq * 4;
#pragma unroll
            for (int r = 0; r < 4; r++)
                out[(size_t)(mb + r) * N + n] = toB(acc[i][j][r] + bb);
        }
    }
}

// ---------------------------------------------------------------------------
// LEPE token-major v3: per-image XCD affinity (b&7 = image, V L2-resident) +
// row register window + weights staged through LDS:
//   - 25 COALESCED global loads/thread fill lw[tap][cg] (float4 = 4 ch weights)
//   - tap loop reads ONE float4 per (dy,dx) from LDS, reused over 8 x-positions
// -> kills the 64-line uncoalesced per-lane weight reads (the 41us TA serial).
__global__ __launch_bounds__(256) void k_lepe_t(const bf16* __restrict__ qkv,
                                                const float* __restrict__ w_lepe,
                                                const float* __restrict__ b_lepe,
                                                bf16* __restrict__ lepe) {
    __shared__ float lw[25 * 64 * 4];   // [tap][cg][4ch] = 25.6 KB
    int tid = threadIdx.x;
    int cg = tid & 63;                  // 4-channel group, lane-fast
    int slot = tid >> 6;                // wave id 0..3 (wave-uniform)
    int b = blockIdx.x;                 // 0..1023
    int n = b & 7;                      // image -> XCD (round-robin d%8)
    int bx = b >> 3;                    // 0..127: y = bx>>1, x-half = bx&1
    int y = bx >> 1;
    int x0 = (bx & 1) * 32 + slot * 8;  // 8 x-positions per thread
    // stage weights: coalesced global read, transposed LDS write
#pragma unroll
    for (int j = 0; j < 25; j++) {
        int g = tid + j * 256;          // 0..6399
        float val = w_lepe[g];
        int ch = g / 25, k = g - ch * 25;
        lw[(k * 64 + (ch >> 2)) * 4 + (ch & 3)] = val;
    }
    float4 b4 = *(const float4*)(b_lepe + cg * 4);
    const float* bias4 = (const float*)&b4;
    __syncthreads();
    const bf16* vb = qkv + (size_t)n * HWSZ * QKVD + 512;
    bf16* dst = lepe + (size_t)n * HWSZ * CDIM;
    float o[8][4];
#pragma unroll
    for (int xi = 0; xi < 8; xi++)
#pragma unroll
        for (int c = 0; c < 4; c++) o[xi][c] = bias4[c];
#pragma unroll
    for (int dy = -2; dy <= 2; dy++) {
        int yy = y + dy;
        if (yy < 0 || yy >= HH) continue;          // wave-uniform
        float rf[12][4];
#pragma unroll
        for (int ii = 0; ii < 12; ii++) {
            int xx = x0 - 2 + ii;
            if (xx >= 0 && xx < WW) {              // wave-uniform
                uint2 v = *(const uint2*)(vb + (size_t)(yy * WW + xx) * QKVD + cg * 4);
                const bf16* pv = (const bf16*)&v;
#pragma unroll
                for (int c = 0; c < 4; c++) rf[ii][c] = toF(pv[c]);
            } else {
#pragma unroll
                for (int c = 0; c < 4; c++) rf[ii][c] = 0.f;
            }
        }
#pragma unroll
        for (int dx = 0; dx < 5; dx++) {
            int k = (dy + 2) * 5 + dx;
            float4 w4v = *(const float4*)&lw[(k * 64 + cg) * 4];
            const float* w4 = (const float*)&w4v;
#pragma unroll
            for (int xi = 0; xi < 8; xi++)
#pragma unroll
                for (int c = 0; c < 4; c++) o[xi][c] += rf[xi + dx][c] * w4[c];
        }
    }
#pragma unroll
    for (int xi = 0; xi < 8; xi++) {
        uint2 pk;
        bf16* pb = (bf16*)&pk;
#pragma unroll
        for (int c = 0; c < 4; c++) pb[c] = toB(o[xi][c]);
        *(uint2*)(dst + (size_t)(y * WW + x0 + xi) * CDIM + cg * 4) = pk;
    }
}

// ---------------------------------------------------------------------------
// MFMA attention: one block per (n, window). 256 thr = 4 waves, 2 heads/wave.
__global__ __launch_bounds__(256) void k_attn(const bf16* __restrict__ qkv,
                                              const int* __restrict__ topk,
                                              bf16* __restrict__ attnout) {
    __shared__ bf16 vst[256][72];      // V^T [dim][key], pad 72
    __shared__ bf16 plds[4][16][72];   // per-wave P [tok][key]
    __shared__ float lsm[4][16];       // per-wave softmax denominator per tok
    __shared__ int toks[64];           // routed key -> token index (within image)
    int b = blockIdx.x;
    int n = b >> 8, p = b & 255;
    int wy = p >> 4, wx = p & 15;
    int tid = threadIdx.x;
    if (tid < 64) {
        int rp = topk[((size_t)(n << 8) + p) * TOPK + (tid >> 4)] & 255;
        int st = tid & 15;
        toks[tid] = ((rp >> 4) * 4 + (st >> 2)) * WW + (rp & 15) * 4 + (st & 3);
    }
    __syncthreads();
    const bf16* qbase = qkv + (size_t)n * HWSZ * QKVD;
    {
        int kt = tid & 63, jj = tid >> 6;
#pragma unroll
        for (int pass = 0; pass < 8; pass++) {
            int d0 = pass * 32 + jj * 8;
            uint4 v = *(const uint4*)(qbase + (size_t)toks[kt] * QKVD + 512 + d0);
            const bf16* pv = (const bf16*)&v;
#pragma unroll
            for (int e = 0; e < 8; e++) vst[d0 + e][kt] = pv[e];
        }
    }
    __syncthreads();
    int w = tid >> 6, lane = tid & 63;
    int ln = lane & 15, lq = lane >> 4;
    int myS = (wy * 4 + (ln >> 2)) * WW + wx * 4 + (ln & 3);
    const f4v fz = {0.f, 0.f, 0.f, 0.f};
    for (int hh = 0; hh < 2; hh++) {
        int h = w * 2 + hh;
        s8v qf = *(const s8v*)(qbase + (size_t)myS * QKVD + h * 32 + lq * 8);
        f4v st4[4];
#pragma unroll
        for (int t = 0; t < 4; t++) {
            s8v kf = *(const s8v*)(qbase + (size_t)toks[t * 16 + ln] * QKVD + 256 + h * 32 + lq * 8);
            st4[t] = __builtin_amdgcn_mfma_f32_16x16x32_bf16(kf, qf, fz, 0, 0, 0);
        }
        float mx = -INFINITY;
#pragma unroll
        for (int t = 0; t < 4; t++)
#pragma unroll
            for (int r = 0; r < 4; r++) mx = fmaxf(mx, st4[t][r]);
        mx = fmaxf(mx, __shfl_xor(mx, 16));
        mx = fmaxf(mx, __shfl_xor(mx, 32));
        mx *= ATTN_SCALE;
        float sum = 0.f;
#pragma unroll
        for (int t = 0; t < 4; t++)
#pragma unroll
            for (int r = 0; r < 4; r++) {
                float pp = __expf(st4[t][r] * ATTN_SCALE - mx);
                sum += pp;
                plds[w][ln][t * 16 + lq * 4 + r] = toB(pp);
            }
        sum += __shfl_xor(sum, 16);
        sum += __shfl_xor(sum, 32);
        if (lq == 0) lsm[w][ln] = sum;
        __syncthreads();
        s8v ap0 = *(const s8v*)&plds[w][ln][lq * 8];
        s8v ap1 = *(const s8v*)&plds[w][ln][32 + lq * 8];
#pragma unroll
        for (int dt = 0; dt < 2; dt++) {
            int dim = h * 32 + dt * 16 + ln;
            s8v vv0 = *(const s8v*)&vst[dim][lq * 8];
            s8v vv1 = *(const s8v*)&vst[dim][32 + lq * 8];
            f4v o = __builtin_amdgcn_mfma_f32_16x16x32_bf16(ap0, vv0, fz, 0, 0, 0);
            o = __builtin_amdgcn_mfma_f32_16x16x32_bf16(ap1, vv1, o, 0, 0, 0);
#pragma unroll
            for (int r = 0; r < 4; r++) {
                int t = lq * 4 + r;
                float linv = 1.f / lsm[w][t];
                int s = (wy * 4 + (t >> 2)) * WW + wx * 4 + (t & 3);
                attnout[((size_t)n * HWSZ + s) * CDIM + dim] = toB(o[r] * linv);
            }
        }
        __syncthreads();
    }
}

// ---------------------------------------------------------------------------
// x1 = xt + attn + lepe  (all token-major) — pure streaming elementwise.
__global__ __launch_bounds__(256) void k_x1(const bf16* __restrict__ xt,
                                            const bf16* __restrict__ lepe,
                                            const bf16* __restrict__ attnout,
                                            bf16* __restrict__ x1) {
    size_t i = ((size_t)blockIdx.x * 256 + threadIdx.x) * 8;
    uint4 a = *(const uint4*)(xt + i);
    uint4 b = *(const uint4*)(attnout + i);
    uint4 c = *(const uint4*)(lepe + i);
    const bf16* pa = (const bf16*)&a;
    const bf16* pb = (const bf16*)&b;
    const bf16* pc = (const bf16*)&c;
    uint4 r;
    bf16* pr = (bf16*)&r;
#pragma unroll
    for (int e = 0; e < 8; e++) pr[e] = toB(toF(pa[e]) + toF(pb[e]) + toF(pc[e]));
    *(uint4*)(x1 + i) = r;
}

// ---------------------------------------------------------------------------
// Depthwise 3x3 + bias + ReLU, token-major in/out, channels lane-fast.
__global__ __launch_bounds__(256) void k_dw3_t(const bf16* __restrict__ h1,
                                               const float* __restrict__ wdwT,
                                               bf16* __restrict__ h1p) {
    int tid = threadIdx.x;
    int cg = tid & 127;
    int slot = tid >> 7;
    int seg = blockIdx.x;
    int img = blockIdx.y;
    int y = seg >> 2;
    int x0 = ((seg & 3) << 4) + (slot << 3);
    const float* wp = wdwT + cg * 80;
    float w[72], bias[8];
#pragma unroll
    for (int i = 0; i < 72; i++) w[i] = wp[i];
#pragma unroll
    for (int c = 0; c < 8; c++) bias[c] = wp[72 + c];
    const uint4* src = (const uint4*)h1 + (size_t)img * HWSZ * 128;
    uint4* dst = (uint4*)h1p + (size_t)img * HWSZ * 128;
#pragma unroll
    for (int xi = 0; xi < 8; xi++) {
        int x = x0 + xi;
        float o[8];
#pragma unroll
        for (int c = 0; c < 8; c++) o[c] = bias[c];
#pragma unroll
        for (int dy = -1; dy <= 1; dy++) {
            int yy = y + dy;
            if (yy < 0 || yy >= HH) continue;
#pragma unroll
            for (int dx = -1; dx <= 1; dx++) {
                int xx = x + dx;
                if (xx < 0 || xx >= WW) continue;
                int k = (dy + 1) * 3 + (dx + 1);
                uint4 v = src[(size_t)(yy * WW + xx) * 128 + cg];
                const bf16* pv = (const bf16*)&v;
#pragma unroll
                for (int c = 0; c < 8; c++) o[c] += toF(pv[c]) * w[c * 9 + k];
            }
        }
        uint4 pk;
        bf16* pb = (bf16*)&pk;
#pragma unroll
        for (int c = 0; c < 8; c++) pb[c] = toB(fmaxf(o[c], 0.f));
        dst[(size_t)(y * WW + x) * 128 + cg] = pk;
    }
}

// ---------------------------------------------------------------------------
// out (NCHW fp32) = x1 + h2 (both token-major bf16)
__global__ void k_final(const bf16* __restrict__ x1, const bf16* __restrict__ h2,
                        float* __restrict__ out) {
    __shared__ float tile[32][33];
    int s0 = blockIdx.x * 32, c0 = blockIdx.y * 32, n = blockIdx.z;
    int tx = threadIdx.x, ty = threadIdx.y;
#pragma unroll
    for (int r = 0; r < 4; r++) {
        int s = s0 + ty + r * 8;
        size_t idx = ((size_t)n * HWSZ + s) * CDIM + c0 + tx;
        tile[tx][ty + r * 8] = toF(x1[idx]) + toF(h2[idx]);
    }
    __syncthreads();
#pragma unroll
    for (int r = 0; r < 4; r++) {
        int c = c0 + ty + r * 8;
        out[(size_t)n * CDIM * HWSZ + (size_t)c * HWSZ + s0 + tx] = tile[ty + r * 8][tx];
    }
}

// ---------------------------------------------------------------------------
extern "C" void kernel_launch(void* const* d_in, const int* in_sizes, int n_in,
                              void* d_out, int out_size, void* d_ws, size_t ws_size,
                              hipStream_t stream) {
    (void)in_sizes; (void)n_in; (void)out_size; (void)ws_size;
    const float* x      = (const float*)d_in[0];
    const float* wq     = (const float*)d_in[1];
    const float* gq     = (const float*)d_in[2];
    const float* bq     = (const float*)d_in[3];
    const float* wkv    = (const float*)d_in[4];
    const float* gkv    = (const float*)d_in[5];
    const float* bkv    = (const float*)d_in[6];
    const float* w_lepe = (const float*)d_in[7];
    const float* b_lepe = (const float*)d_in[8];
    const float* w_fc1  = (const float*)d_in[9];
    const float* g_fc1  = (const float*)d_in[10];
    const float* b_fc1  = (const float*)d_in[11];
    const float* w_dw   = (const float*)d_in[12];
    const float* b_dw   = (const float*)d_in[13];
    const float* w_fc2  = (const float*)d_in[14];
    const float* g_fc2  = (const float*)d_in[15];
    const float* b_fc2  = (const float*)d_in[16];

    char* ws = (char*)d_ws;
    bf16*  qkv    = (bf16*)(ws);
    bf16*  lepe   = (bf16*)(ws + 50331648);   // token-major
    bf16*  attn   = (bf16*)(ws + 67108864);
    bf16*  xt     = (bf16*)(ws + 83886080);
    bf16*  x1     = (bf16*)(ws + 83886080);   // in-place over xt
    bf16*  h1     = (bf16*)(ws);              // phase B
    bf16*  h1p    = (bf16*)(ws + 33554432);
    bf16*  h2     = (bf16*)(ws + 67108864);
    float* xwin   = (float*)(ws + 100663296);
    float* qkwin  = (float*)(ws + 102760448);
    int*   tk     = (int*)(ws + 106954752);
    bf16*  wbqkv  = (bf16*)(ws + 106987520);
    bf16*  wbfc1  = (bf16*)(ws + 107380736);
    bf16*  wbfc2  = (bf16*)(ws + 107905024);
    float* bias768= (float*)(ws + 108429312);
    float* wdwT   = (float*)(ws + 108433408);  // 40 KB
    float* logits = (float*)(ws + 108478464);  // 2 MB

    k_prep<<<2856, 256, 0, stream>>>(wq, gq, wkv, gkv, w_fc1, g_fc1, w_fc2, g_fc2,
                                     bq, bkv, w_dw, b_dw,
                                     wbqkv, wbfc1, wbfc2, bias768, wdwT);
    k_xt<<<dim3(128, 8, 8), dim3(32, 8), 0, stream>>>(x, xt);
    k_xwin<<<2048, 256, 0, stream>>>(x, xwin);
    k_qkwin<<<dim3(32, 8), 256, 0, stream>>>(xwin, wq, wkv, gq, bq, gkv, bkv, qkwin);
    k_logits<<<dim3(4, 4, 8), 256, 0, stream>>>(qkwin, logits);
    k_topk<<<512, 256, 0, stream>>>(logits, tk);
    k_mfma<128, 128><<<dim3(256, 6), 256, 0, stream>>>(
        xt, wbqkv, bias768, qkv, TT, QKVD, CDIM);
    k_lepe_t<<<1024, 256, 0, stream>>>(qkv, w_lepe, b_lepe, lepe);
    k_attn<<<2048, 256, 0, stream>>>(qkv, tk, attn);
    k_x1<<<4096, 256, 0, stream>>>(xt, lepe, attn, x1);
    for (int c = 0; c < 2; c++) {
        bf16* x1c = x1 + (size_t)c * 16384 * CDIM;
        bf16* h2c = h2 + (size_t)c * 16384 * CDIM;
        k_mfma<128, 128><<<dim3(128, 8), 256, 0, stream>>>(
            x1c, wbfc1, b_fc1, h1, 16384, HID, CDIM);
        k_dw3_t<<<dim3(256, 4), 256, 0, stream>>>(h1, wdwT, h1p);
        k_mfma<64, 128><<<dim3(256, 2), 256, 0, stream>>>(
            h1p, wbfc2, b_fc2, h2c, 16384, CDIM, HID);
    }
    k_final<<<dim3(128, 8, 8), dim3(32, 8), 0, stream>>>(x1, h2, (float*)d_out);
}

// Round 10
// 405.632 us; speedup vs baseline: 1.2009x; 1.0595x over previous
//
#include <hip/hip_runtime.h>
#include <hip/hip_bf16.h>

#define NBATCH 8
#define CDIM 256
#define HH 64
#define WW 64
#define HWSZ 4096
#define TT 32768        // NBATCH * HWSZ tokens
#define QKVD 768        // q(256) | k(256) | v(256)
#define TOPK 4
#define HID 1024
#define ATTN_SCALE 0.0625f   // 256^-0.5

typedef __hip_bfloat16 bf16;
typedef __attribute__((ext_vector_type(8))) short s8v;   // 8 bf16 = 4 VGPR
typedef __attribute__((ext_vector_type(4))) float f4v;   // MFMA acc

__device__ __forceinline__ float toF(bf16 v) { return __bfloat162float(v); }
__device__ __forceinline__ bf16  toB(float v) { return __float2bfloat16(v); }

// async 16B global -> LDS (wave-uniform LDS base + lane*16)
__device__ __forceinline__ void gload_lds16(const bf16* g, bf16* l) {
    __builtin_amdgcn_global_load_lds(
        (const __attribute__((address_space(1))) void*)g,
        (__attribute__((address_space(3))) void*)l, 16, 0, 0);
}

// ---------------------------------------------------------------------------
// Prep: fold gamma into weights, cast to bf16; concat qkv bias; and build
// wdwT: per-cg-contiguous dw3 weights+bias fp32.
__global__ void k_prep(const float* __restrict__ wq, const float* __restrict__ gq,
                       const float* __restrict__ wkv, const float* __restrict__ gkv,
                       const float* __restrict__ wfc1, const float* __restrict__ gfc1,
                       const float* __restrict__ wfc2, const float* __restrict__ gfc2,
                       const float* __restrict__ bq, const float* __restrict__ bkv,
                       const float* __restrict__ w_dw, const float* __restrict__ b_dw,
                       bf16* __restrict__ wbqkv, bf16* __restrict__ wbfc1,
                       bf16* __restrict__ wbfc2, float* __restrict__ bias768,
                       float* __restrict__ wdwT) {
    int i = blockIdx.x * 256 + threadIdx.x;
    if (i < 196608) {                       // wbqkv [768][256]
        int r = i >> 8;
        float g = (r < 256) ? gq[r] : gkv[r - 256];
        float w = (r < 256) ? wq[i] : wkv[i - 65536];
        wbqkv[i] = toB(w * g);
        if (i < 768) bias768[i] = (i < 256) ? bq[i] : bkv[i - 256];
    } else if (i < 458752) {                // wbfc1 [1024][256]
        int j = i - 196608;
        wbfc1[j] = toB(wfc1[j] * gfc1[j >> 8]);
    } else if (i < 720896) {                // wbfc2 [256][1024]
        int j = i - 458752;
        wbfc2[j] = toB(wfc2[j] * gfc2[j >> 10]);
    } else if (i < 731136) {                // wdwT [128][80]
        int j = i - 720896;
        int cg = j / 80, r = j - cg * 80;
        wdwT[j] = (r < 72) ? w_dw[(cg * 8 + r / 9) * 9 + (r % 9)]
                           : b_dw[cg * 8 + (r - 72)];
    }
}

// ---------------------------------------------------------------------------
// x NCHW fp32 -> token-major bf16 xt[m][c]
__global__ void k_xt(const float* __restrict__ x, bf16* __restrict__ xt) {
    __shared__ float tile[32][33];
    int s0 = blockIdx.x * 32, c0 = blockIdx.y * 32, n = blockIdx.z;
    int tx = threadIdx.x, ty = threadIdx.y;
#pragma unroll
    for (int r = 0; r < 4; r++)
        tile[ty + r * 8][tx] = x[(size_t)n * CDIM * HWSZ + (size_t)(c0 + ty + r * 8) * HWSZ + s0 + tx];
    __syncthreads();
#pragma unroll
    for (int r = 0; r < 4; r++)
        xt[((size_t)n * HWSZ + s0 + ty + r * 8) * CDIM + c0 + tx] = toB(tile[tx][ty + r * 8]);
}

// ---------------------------------------------------------------------------
// Window means of x (fp32-exact routing path). Block=(n,c), thread=window p.
__global__ void k_xwin(const float* __restrict__ x, float* __restrict__ xwin) {
    int b = blockIdx.x;
    int n = b >> 8, c = b & 255;
    int p = threadIdx.x, wy = p >> 4, wx = p & 15;
    const float* pl = x + ((size_t)n * CDIM + c) * HWSZ;
    float s = 0.f;
#pragma unroll
    for (int dy = 0; dy < 4; dy++)
#pragma unroll
        for (int dx = 0; dx < 4; dx++)
            s += pl[(wy * 4 + dy) * WW + wx * 4 + dx];
    xwin[((size_t)(n << 8) + p) * 256 + c] = s * 0.0625f;
}

// ---------------------------------------------------------------------------
// qkwin[m][0:512] = (xwin @ [wq|wk]^T)*g + b  (fp32 vector GEMM, M=2048 K=256)
__global__ void k_qkwin(const float* __restrict__ xwin,
                        const float* __restrict__ wq, const float* __restrict__ wkv,
                        const float* __restrict__ gq, const float* __restrict__ bq,
                        const float* __restrict__ gkv, const float* __restrict__ bkv,
                        float* __restrict__ qkwin) {
    __shared__ float As[16][68];
    __shared__ float Bs[16][68];
    int m0 = blockIdx.x * 64, n0 = blockIdx.y * 64;
    int tid = threadIdx.x;
    int tx = tid & 15, ty = tid >> 4;
    float acc[4][4] = {};
    for (int k0 = 0; k0 < 256; k0 += 16) {
#pragma unroll
        for (int r = 0; r < 4; r++) {
            int lin = tid + r * 256;
            int row = lin >> 4, kk = lin & 15;
            As[kk][row] = xwin[(size_t)(m0 + row) * 256 + k0 + kk];
            int n = n0 + row;
            const float* wr = (n < 256) ? (wq + (size_t)n * 256) : (wkv + (size_t)(n - 256) * 256);
            Bs[kk][row] = wr[k0 + kk];
        }
        __syncthreads();
#pragma unroll
        for (int kk = 0; kk < 16; kk++) {
            float a[4], bb[4];
#pragma unroll
            for (int i = 0; i < 4; i++) a[i] = As[kk][tx * 4 + i];
#pragma unroll
            for (int j = 0; j < 4; j++) bb[j] = Bs[kk][ty * 4 + j];
#pragma unroll
            for (int i = 0; i < 4; i++)
#pragma unroll
                for (int j = 0; j < 4; j++) acc[i][j] += a[i] * bb[j];
        }
        __syncthreads();
    }
#pragma unroll
    for (int j = 0; j < 4; j++) {
        int n = n0 + ty * 4 + j;
        float gg = (n < 256) ? gq[n] : gkv[n - 256];
        float bb = (n < 256) ? bq[n] : bkv[n - 256];
#pragma unroll
        for (int i = 0; i < 4; i++)
            qkwin[(size_t)(m0 + tx * 4 + i) * 512 + n] = acc[i][j] * gg + bb;
    }
}

// ---------------------------------------------------------------------------
// Routing logits: per image, L[pq][key] = sum_c qwin[pq][c] * kwin[key][c].
__global__ void k_logits(const float* __restrict__ qkwin, float* __restrict__ logits) {
    __shared__ float As[16][68];
    __shared__ float Bs[16][68];
    int m0 = blockIdx.x * 64, n0 = blockIdx.y * 64, img = blockIdx.z;
    const float* base = qkwin + (size_t)(img << 8) * 512;
    int tid = threadIdx.x;
    int tx = tid & 15, ty = tid >> 4;
    float acc[4][4] = {};
    for (int k0 = 0; k0 < 256; k0 += 16) {
#pragma unroll
        for (int r = 0; r < 4; r++) {
            int lin = tid + r * 256;
            int row = lin >> 4, kk = lin & 15;
            As[kk][row] = base[(size_t)(m0 + row) * 512 + k0 + kk];
            Bs[kk][row] = base[(size_t)(n0 + row) * 512 + 256 + k0 + kk];
        }
        __syncthreads();
#pragma unroll
        for (int kk = 0; kk < 16; kk++) {
            float a[4], bb[4];
#pragma unroll
            for (int i = 0; i < 4; i++) a[i] = As[kk][tx * 4 + i];
#pragma unroll
            for (int j = 0; j < 4; j++) bb[j] = Bs[kk][ty * 4 + j];
#pragma unroll
            for (int i = 0; i < 4; i++)
#pragma unroll
                for (int j = 0; j < 4; j++) acc[i][j] += a[i] * bb[j];
        }
        __syncthreads();
    }
    float* Lr = logits + (size_t)(img << 8) * 256;
#pragma unroll
    for (int j = 0; j < 4; j++)
#pragma unroll
        for (int i = 0; i < 4; i++)
            Lr[(size_t)(m0 + tx * 4 + i) * 256 + n0 + ty * 4 + j] = acc[i][j];
}

// ---------------------------------------------------------------------------
// Top-4 per row of 256 logits: one wave per row, shuffle argmax, jax tie-break.
__global__ __launch_bounds__(256) void k_topk(const float* __restrict__ logits,
                                              int* __restrict__ topk) {
    int row = blockIdx.x * 4 + (threadIdx.x >> 6);
    int lane = threadIdx.x & 63;
    float4 v4 = *(const float4*)(logits + (size_t)row * 256 + lane * 4);
    float v[4] = {v4.x, v4.y, v4.z, v4.w};
#pragma unroll
    for (int sel = 0; sel < TOPK; sel++) {
        float mv = v[0]; int mi = lane * 4;
#pragma unroll
        for (int j = 1; j < 4; j++)
            if (v[j] > mv) { mv = v[j]; mi = lane * 4 + j; }
#pragma unroll
        for (int off = 1; off < 64; off <<= 1) {
            float ov = __shfl_xor(mv, off);
            int oi = __shfl_xor(mi, off);
            if (ov > mv || (ov == mv && oi < mi)) { mv = ov; mi = oi; }
        }
        if (lane == 0) topk[(size_t)row * TOPK + sel] = mi;
        if ((mi >> 2) == lane) v[mi & 3] = -INFINITY;
    }
}

// ---------------------------------------------------------------------------
// MFMA GEMM with global_load_lds width-16 staging; XCD swizzle (T1).
template <int BM, int BN>
__global__ __launch_bounds__(256) void k_mfma(const bf16* __restrict__ A,
                                              const bf16* __restrict__ Wb,
                                              const float* __restrict__ bias,
                                              bf16* __restrict__ out,
                                              int M, int N, int K) {
    constexpr int WROWS = BM / 2, WCOLS = BN / 2;     // per-wave quadrant
    constexpr int WM = WROWS / 16, WN = WCOLS / 16;   // 16x16 tiles per wave
    constexpr int CA = (BM * 4) / 256;                // 16B chunks/thread for A
    constexpr int CB = (BN * 4) / 256;
    __shared__ bf16 As[BM * 32];
    __shared__ bf16 Bs[BN * 32];
    int gx = gridDim.x;
    int lin = blockIdx.x + blockIdx.y * gx;
    int tot = gx * gridDim.y;
    int cpx = tot >> 3;
    int swz = (lin & 7) * cpx + (lin >> 3);
    int m0 = (swz % gx) * BM, n0 = (swz / gx) * BN;
    int tid = threadIdx.x;
    int w = tid >> 6, lane = tid & 63;
    int wr = w >> 1, wc = w & 1;
    int lm = lane & 15, lq = lane >> 4;
    f4v acc[WM][WN];
#pragma unroll
    for (int i = 0; i < WM; i++)
#pragma unroll
        for (int j = 0; j < WN; j++) acc[i][j] = (f4v){0.f, 0.f, 0.f, 0.f};

    for (int k0 = 0; k0 < K; k0 += 32) {
#pragma unroll
        for (int q = 0; q < CA; q++) {
            int c = tid + q * 256, row = c >> 2, col = c & 3;
            gload_lds16(A + (size_t)(m0 + row) * K + k0 + col * 8,
                        As + (size_t)(w * 64 + q * 256) * 8);
        }
#pragma unroll
        for (int q = 0; q < CB; q++) {
            int c = tid + q * 256, row = c >> 2, col = c & 3;
            gload_lds16(Wb + (size_t)(n0 + row) * K + k0 + col * 8,
                        Bs + (size_t)(w * 64 + q * 256) * 8);
        }
        asm volatile("s_waitcnt vmcnt(0)" ::: "memory");
        __syncthreads();                      // staged tile visible
        s8v af[WM], bfr[WN];
#pragma unroll
        for (int i = 0; i < WM; i++)
            af[i] = *(const s8v*)&As[(wr * WROWS + i * 16 + lm) * 32 + lq * 8];
#pragma unroll
        for (int j = 0; j < WN; j++)
            bfr[j] = *(const s8v*)&Bs[(wc * WCOLS + j * 16 + lm) * 32 + lq * 8];
#pragma unroll
        for (int i = 0; i < WM; i++)
#pragma unroll
            for (int j = 0; j < WN; j++)
                acc[i][j] = __builtin_amdgcn_mfma_f32_16x16x32_bf16(af[i], bfr[j], acc[i][j], 0, 0, 0);
        __syncthreads();                      // LDS reads done; next iter may overwrite
    }
#pragma unroll
    for (int j = 0; j < WN; j++) {
        int n = n0 + wc * WCOLS + j * 16 + lm;
        float bb = bias[n];
#pragma unroll
        for (int i = 0; i < WM; i++) {
            int mb = m0 + wr * WROWS + i * 16 + lq * 4;
#pragma unroll
            for (int r = 0; r < 4; r++)
                out[(size_t)(mb + r) * N + n] = toB(acc[i][j][r] + bb);
        }
    }
}

// ---------------------------------------------------------------------------
// LEPE token-major: per-image XCD affinity + row register window + weights
// staged through LDS (coalesced load, transposed [tap][cg][4ch] layout).
__global__ __launch_bounds__(256) void k_lepe_t(const bf16* __restrict__ qkv,
                                                const float* __restrict__ w_lepe,
                                                const float* __restrict__ b_lepe,
                                                bf16* __restrict__ lepe) {
    __shared__ float lw[25 * 64 * 4];   // [tap][cg][4ch] = 25.6 KB
    int tid = threadIdx.x;
    int cg = tid & 63;                  // 4-channel group, lane-fast
    int slot = tid >> 6;                // wave id 0..3 (wave-uniform)
    int b = blockIdx.x;                 // 0..1023
    int n = b & 7;                      // image -> XCD (round-robin d%8)
    int bx = b >> 3;                    // 0..127: y = bx>>1, x-half = bx&1
    int y = bx >> 1;
    int x0 = (bx & 1) * 32 + slot * 8;  // 8 x-positions per thread
#pragma unroll
    for (int j = 0; j < 25; j++) {
        int g = tid + j * 256;          // 0..6399
        float val = w_lepe[g];
        int ch = g / 25, k = g - ch * 25;
        lw[(k * 64 + (ch >> 2)) * 4 + (ch & 3)] = val;
    }
    float4 b4 = *(const float4*)(b_lepe + cg * 4);
    const float* bias4 = (const float*)&b4;
    __syncthreads();
    const bf16* vb = qkv + (size_t)n * HWSZ * QKVD + 512;
    bf16* dst = lepe + (size_t)n * HWSZ * CDIM;
    float o[8][4];
#pragma unroll
    for (int xi = 0; xi < 8; xi++)
#pragma unroll
        for (int c = 0; c < 4; c++) o[xi][c] = bias4[c];
#pragma unroll
    for (int dy = -2; dy <= 2; dy++) {
        int yy = y + dy;
        if (yy < 0 || yy >= HH) continue;          // wave-uniform
        float rf[12][4];
#pragma unroll
        for (int ii = 0; ii < 12; ii++) {
            int xx = x0 - 2 + ii;
            if (xx >= 0 && xx < WW) {              // wave-uniform
                uint2 v = *(const uint2*)(vb + (size_t)(yy * WW + xx) * QKVD + cg * 4);
                const bf16* pv = (const bf16*)&v;
#pragma unroll
                for (int c = 0; c < 4; c++) rf[ii][c] = toF(pv[c]);
            } else {
#pragma unroll
                for (int c = 0; c < 4; c++) rf[ii][c] = 0.f;
            }
        }
#pragma unroll
        for (int dx = 0; dx < 5; dx++) {
            int k = (dy + 2) * 5 + dx;
            float4 w4v = *(const float4*)&lw[(k * 64 + cg) * 4];
            const float* w4 = (const float*)&w4v;
#pragma unroll
            for (int xi = 0; xi < 8; xi++)
#pragma unroll
                for (int c = 0; c < 4; c++) o[xi][c] += rf[xi + dx][c] * w4[c];
        }
    }
#pragma unroll
    for (int xi = 0; xi < 8; xi++) {
        uint2 pk;
        bf16* pb = (bf16*)&pk;
#pragma unroll
        for (int c = 0; c < 4; c++) pb[c] = toB(o[xi][c]);
        *(uint2*)(dst + (size_t)(y * WW + x0 + xi) * CDIM + cg * 4) = pk;
    }
}

// ---------------------------------------------------------------------------
// MFMA attention + FUSED residual: writes x1 = xt + attn + lepe directly
// (in-place over xt: each (s,dim) owned by exactly one lane of one block).
// Per-image XCD affinity: n = b&7 so XCD k works only image k's qkv slice.
__global__ __launch_bounds__(256) void k_attn(const bf16* __restrict__ qkv,
                                              const int* __restrict__ topk,
                                              const bf16* __restrict__ lepe,
                                              bf16* x1t) {
    __shared__ bf16 vst[256][72];      // V^T [dim][key], pad 72
    __shared__ bf16 plds[4][16][72];   // per-wave P [tok][key]
    __shared__ float lsm[4][16];       // per-wave softmax denominator per tok
    __shared__ int toks[64];           // routed key -> token index (within image)
    int b = blockIdx.x;
    int n = b & 7, p = b >> 3;         // XCD affinity: XCD = b%8 = image
    int wy = p >> 4, wx = p & 15;
    int tid = threadIdx.x;
    if (tid < 64) {
        int rp = topk[((size_t)(n << 8) + p) * TOPK + (tid >> 4)] & 255;
        int st = tid & 15;
        toks[tid] = ((rp >> 4) * 4 + (st >> 2)) * WW + (rp & 15) * 4 + (st & 3);
    }
    __syncthreads();
    const bf16* qbase = qkv + (size_t)n * HWSZ * QKVD;
    {
        int kt = tid & 63, jj = tid >> 6;
#pragma unroll
        for (int pass = 0; pass < 8; pass++) {
            int d0 = pass * 32 + jj * 8;
            uint4 v = *(const uint4*)(qbase + (size_t)toks[kt] * QKVD + 512 + d0);
            const bf16* pv = (const bf16*)&v;
#pragma unroll
            for (int e = 0; e < 8; e++) vst[d0 + e][kt] = pv[e];
        }
    }
    __syncthreads();
    int w = tid >> 6, lane = tid & 63;
    int ln = lane & 15, lq = lane >> 4;
    int myS = (wy * 4 + (ln >> 2)) * WW + wx * 4 + (ln & 3);
    const f4v fz = {0.f, 0.f, 0.f, 0.f};
    for (int hh = 0; hh < 2; hh++) {
        int h = w * 2 + hh;
        s8v qf = *(const s8v*)(qbase + (size_t)myS * QKVD + h * 32 + lq * 8);
        f4v st4[4];
#pragma unroll
        for (int t = 0; t < 4; t++) {
            s8v kf = *(const s8v*)(qbase + (size_t)toks[t * 16 + ln] * QKVD + 256 + h * 32 + lq * 8);
            st4[t] = __builtin_amdgcn_mfma_f32_16x16x32_bf16(kf, qf, fz, 0, 0, 0);
        }
        float mx = -INFINITY;
#pragma unroll
        for (int t = 0; t < 4; t++)
#pragma unroll
            for (int r = 0; r < 4; r++) mx = fmaxf(mx, st4[t][r]);
        mx = fmaxf(mx, __shfl_xor(mx, 16));
        mx = fmaxf(mx, __shfl_xor(mx, 32));
        mx *= ATTN_SCALE;
        float sum = 0.f;
#pragma unroll
        for (int t = 0; t < 4; t++)
#pragma unroll
            for (int r = 0; r < 4; r++) {
                float pp = __expf(st4[t][r] * ATTN_SCALE - mx);
                sum += pp;
                plds[w][ln][t * 16 + lq * 4 + r] = toB(pp);
            }
        sum += __shfl_xor(sum, 16);
        sum += __shfl_xor(sum, 32);
        if (lq == 0) lsm[w][ln] = sum;
        __syncthreads();
        s8v ap0 = *(const s8v*)&plds[w][ln][lq * 8];
        s8v ap1 = *(const s8v*)&plds[w][ln][32 + lq * 8];
#pragma unroll
        for (int dt = 0; dt < 2; dt++) {
            int dim = h * 32 + dt * 16 + ln;
            s8v vv0 = *(const s8v*)&vst[dim][lq * 8];
            s8v vv1 = *(const s8v*)&vst[dim][32 + lq * 8];
            f4v o = __builtin_amdgcn_mfma_f32_16x16x32_bf16(ap0, vv0, fz, 0, 0, 0);
            o = __builtin_amdgcn_mfma_f32_16x16x32_bf16(ap1, vv1, o, 0, 0, 0);
#pragma unroll
            for (int r = 0; r < 4; r++) {
                int t = lq * 4 + r;
                float linv = 1.f / lsm[w][t];
                int s = (wy * 4 + (t >> 2)) * WW + wx * 4 + (t & 3);
                size_t idx = ((size_t)n * HWSZ + s) * CDIM + dim;
                x1t[idx] = toB(o[r] * linv + toF(x1t[idx]) + toF(lepe[idx]));
            }
        }
        __syncthreads();
    }
}

// ---------------------------------------------------------------------------
// Depthwise 3x3 + bias + ReLU, token-major, channels lane-fast.
// Flat grid 2048 with per-image XCD affinity: img = lin&7, seg = lin>>3
// (XCD k sweeps image k in ascending y -> 3-row reuse window stays in L2).
__global__ __launch_bounds__(256) void k_dw3_t(const bf16* __restrict__ h1,
                                               const float* __restrict__ wdwT,
                                               bf16* __restrict__ h1p) {
    int tid = threadIdx.x;
    int cg = tid & 127;
    int slot = tid >> 7;
    int lin = blockIdx.x;               // 0..2047
    int img = lin & 7;                  // image -> XCD
    int seg = lin >> 3;                 // 0..255: y = seg>>2, x-quarter = seg&3
    int y = seg >> 2;
    int x0 = ((seg & 3) << 4) + (slot << 3);
    const float* wp = wdwT + cg * 80;
    float w[72], bias[8];
#pragma unroll
    for (int i = 0; i < 72; i++) w[i] = wp[i];
#pragma unroll
    for (int c = 0; c < 8; c++) bias[c] = wp[72 + c];
    const uint4* src = (const uint4*)h1 + (size_t)img * HWSZ * 128;
    uint4* dst = (uint4*)h1p + (size_t)img * HWSZ * 128;
#pragma unroll
    for (int xi = 0; xi < 8; xi++) {
        int x = x0 + xi;
        float o[8];
#pragma unroll
        for (int c = 0; c < 8; c++) o[c] = bias[c];
#pragma unroll
        for (int dy = -1; dy <= 1; dy++) {
            int yy = y + dy;
            if (yy < 0 || yy >= HH) continue;
#pragma unroll
            for (int dx = -1; dx <= 1; dx++) {
                int xx = x + dx;
                if (xx < 0 || xx >= WW) continue;
                int k = (dy + 1) * 3 + (dx + 1);
                uint4 v = src[(size_t)(yy * WW + xx) * 128 + cg];
                const bf16* pv = (const bf16*)&v;
#pragma unroll
                for (int c = 0; c < 8; c++) o[c] += toF(pv[c]) * w[c * 9 + k];
            }
        }
        uint4 pk;
        bf16* pb = (bf16*)&pk;
#pragma unroll
        for (int c = 0; c < 8; c++) pb[c] = toB(fmaxf(o[c], 0.f));
        dst[(size_t)(y * WW + x) * 128 + cg] = pk;
    }
}

// ---------------------------------------------------------------------------
// out (NCHW fp32) = x1 + h2 (both token-major bf16)
__global__ void k_final(const bf16* __restrict__ x1, const bf16* __restrict__ h2,
                        float* __restrict__ out) {
    __shared__ float tile[32][33];
    int s0 = blockIdx.x * 32, c0 = blockIdx.y * 32, n = blockIdx.z;
    int tx = threadIdx.x, ty = threadIdx.y;
#pragma unroll
    for (int r = 0; r < 4; r++) {
        int s = s0 + ty + r * 8;
        size_t idx = ((size_t)n * HWSZ + s) * CDIM + c0 + tx;
        tile[tx][ty + r * 8] = toF(x1[idx]) + toF(h2[idx]);
    }
    __syncthreads();
#pragma unroll
    for (int r = 0; r < 4; r++) {
        int c = c0 + ty + r * 8;
        out[(size_t)n * CDIM * HWSZ + (size_t)c * HWSZ + s0 + tx] = tile[ty + r * 8][tx];
    }
}

// ---------------------------------------------------------------------------
extern "C" void kernel_launch(void* const* d_in, const int* in_sizes, int n_in,
                              void* d_out, int out_size, void* d_ws, size_t ws_size,
                              hipStream_t stream) {
    (void)in_sizes; (void)n_in; (void)out_size; (void)ws_size;
    const float* x      = (const float*)d_in[0];
    const float* wq     = (const float*)d_in[1];
    const float* gq     = (const float*)d_in[2];
    const float* bq     = (const float*)d_in[3];
    const float* wkv    = (const float*)d_in[4];
    const float* gkv    = (const float*)d_in[5];
    const float* bkv    = (const float*)d_in[6];
    const float* w_lepe = (const float*)d_in[7];
    const float* b_lepe = (const float*)d_in[8];
    const float* w_fc1  = (const float*)d_in[9];
    const float* g_fc1  = (const float*)d_in[10];
    const float* b_fc1  = (const float*)d_in[11];
    const float* w_dw   = (const float*)d_in[12];
    const float* b_dw   = (const float*)d_in[13];
    const float* w_fc2  = (const float*)d_in[14];
    const float* g_fc2  = (const float*)d_in[15];
    const float* b_fc2  = (const float*)d_in[16];

    // ws layout (ws_size = 256 MiB; fill size confirms). Unchunked phase B.
    char* ws = (char*)d_ws;
    bf16*  qkv    = (bf16*)(ws);                    //   0.0 MB, 50.3
    bf16*  lepe   = (bf16*)(ws + 50331648);         //  48.0 MiB, 16.8
    bf16*  xt     = (bf16*)(ws + 67108864);         //  64.0 MiB, 16.8 (x1 in-place)
    bf16*  x1     = (bf16*)(ws + 67108864);
    bf16*  h1     = (bf16*)(ws + 83886080);         //  80.0 MiB, 67.1
    bf16*  h1p    = (bf16*)(ws + 150994944);        // 144.0 MiB, 67.1
    bf16*  h2     = (bf16*)(ws + 218103808);        // 208.0 MiB, 16.8
    float* xwin   = (float*)(ws + 234881024);       // 224.0 MiB, 2.1
    float* qkwin  = (float*)(ws + 236978176);       // 4.2
    float* logits = (float*)(ws + 241172480);       // 2.1
    int*   tk     = (int*)(ws + 243269632);
    bf16*  wbqkv  = (bf16*)(ws + 243302400);
    bf16*  wbfc1  = (bf16*)(ws + 243695616);
    bf16*  wbfc2  = (bf16*)(ws + 244219904);
    float* bias768= (float*)(ws + 244744192);
    float* wdwT   = (float*)(ws + 244747264);       // ends ~233.5 MiB < 256 MiB

    k_prep<<<2856, 256, 0, stream>>>(wq, gq, wkv, gkv, w_fc1, g_fc1, w_fc2, g_fc2,
                                     bq, bkv, w_dw, b_dw,
                                     wbqkv, wbfc1, wbfc2, bias768, wdwT);
    k_xt<<<dim3(128, 8, 8), dim3(32, 8), 0, stream>>>(x, xt);
    k_xwin<<<2048, 256, 0, stream>>>(x, xwin);
    k_qkwin<<<dim3(32, 8), 256, 0, stream>>>(xwin, wq, wkv, gq, bq, gkv, bkv, qkwin);
    k_logits<<<dim3(4, 4, 8), 256, 0, stream>>>(qkwin, logits);
    k_topk<<<512, 256, 0, stream>>>(logits, tk);
    k_mfma<128, 128><<<dim3(256, 6), 256, 0, stream>>>(
        xt, wbqkv, bias768, qkv, TT, QKVD, CDIM);
    k_lepe_t<<<1024, 256, 0, stream>>>(qkv, w_lepe, b_lepe, lepe);
    k_attn<<<2048, 256, 0, stream>>>(qkv, tk, lepe, x1);   // x1 = xt+attn+lepe fused
    k_mfma<128, 128><<<dim3(256, 8), 256, 0, stream>>>(
        x1, wbfc1, b_fc1, h1, TT, HID, CDIM);
    k_dw3_t<<<2048, 256, 0, stream>>>(h1, wdwT, h1p);
    k_mfma<64, 128><<<dim3(512, 2), 256, 0, stream>>>(
        h1p, wbfc2, b_fc2, h2, TT, CDIM, HID);
    k_final<<<dim3(128, 8, 8), dim3(32, 8), 0, stream>>>(x1, h2, (float*)d_out);
}

// Round 13
// 397.189 us; speedup vs baseline: 1.2264x; 1.0213x over previous
//
#include <hip/hip_runtime.h>
#include <hip/hip_bf16.h>

#define NBATCH 8
#define CDIM 256
#define HH 64
#define WW 64
#define HWSZ 4096
#define TT 32768        // NBATCH * HWSZ tokens
#define QKVD 768        // q(256) | k(256) | v(256)
#define TOPK 4
#define HID 1024
#define ATTN_SCALE 0.0625f   // 256^-0.5

typedef __hip_bfloat16 bf16;
typedef __attribute__((ext_vector_type(8))) short s8v;   // 8 bf16 = 4 VGPR
typedef __attribute__((ext_vector_type(4))) float f4v;   // MFMA acc

__device__ __forceinline__ float toF(bf16 v) { return __bfloat162float(v); }
__device__ __forceinline__ bf16  toB(float v) { return __float2bfloat16(v); }

// async 16B global -> LDS (wave-uniform LDS base + lane*16)
__device__ __forceinline__ void gload_lds16(const bf16* g, bf16* l) {
    __builtin_amdgcn_global_load_lds(
        (const __attribute__((address_space(1))) void*)g,
        (__attribute__((address_space(3))) void*)l, 16, 0, 0);
}

// ---------------------------------------------------------------------------
// Prep: fold gamma into weights, cast to bf16; concat qkv bias; and build
// wdwT: per-cg-contiguous dw3 weights+bias fp32, TAP-MAJOR within cg:
// wdwT[cg*80 + k*8 + c] (k=tap 0..8, c=channel 0..7), bias at wdwT[cg*80+72+c].
__global__ void k_prep(const float* __restrict__ wq, const float* __restrict__ gq,
                       const float* __restrict__ wkv, const float* __restrict__ gkv,
                       const float* __restrict__ wfc1, const float* __restrict__ gfc1,
                       const float* __restrict__ wfc2, const float* __restrict__ gfc2,
                       const float* __restrict__ bq, const float* __restrict__ bkv,
                       const float* __restrict__ w_dw, const float* __restrict__ b_dw,
                       bf16* __restrict__ wbqkv, bf16* __restrict__ wbfc1,
                       bf16* __restrict__ wbfc2, float* __restrict__ bias768,
                       float* __restrict__ wdwT) {
    int i = blockIdx.x * 256 + threadIdx.x;
    if (i < 196608) {                       // wbqkv [768][256]
        int r = i >> 8;
        float g = (r < 256) ? gq[r] : gkv[r - 256];
        float w = (r < 256) ? wq[i] : wkv[i - 65536];
        wbqkv[i] = toB(w * g);
        if (i < 768) bias768[i] = (i < 256) ? bq[i] : bkv[i - 256];
    } else if (i < 458752) {                // wbfc1 [1024][256]
        int j = i - 196608;
        wbfc1[j] = toB(wfc1[j] * gfc1[j >> 8]);
    } else if (i < 720896) {                // wbfc2 [256][1024]
        int j = i - 458752;
        wbfc2[j] = toB(wfc2[j] * gfc2[j >> 10]);
    } else if (i < 731136) {                // wdwT [128][80], tap-major
        int j = i - 720896;
        int cg = j / 80, r = j - cg * 80;
        wdwT[j] = (r < 72) ? w_dw[(cg * 8 + (r & 7)) * 9 + (r >> 3)]
                           : b_dw[cg * 8 + (r - 72)];
    }
}

// ---------------------------------------------------------------------------
// x NCHW fp32 -> token-major bf16 xt[m][c]
__global__ void k_xt(const float* __restrict__ x, bf16* __restrict__ xt) {
    __shared__ float tile[32][33];
    int s0 = blockIdx.x * 32, c0 = blockIdx.y * 32, n = blockIdx.z;
    int tx = threadIdx.x, ty = threadIdx.y;
#pragma unroll
    for (int r = 0; r < 4; r++)
        tile[ty + r * 8][tx] = x[(size_t)n * CDIM * HWSZ + (size_t)(c0 + ty + r * 8) * HWSZ + s0 + tx];
    __syncthreads();
#pragma unroll
    for (int r = 0; r < 4; r++)
        xt[((size_t)n * HWSZ + s0 + ty + r * 8) * CDIM + c0 + tx] = toB(tile[tx][ty + r * 8]);
}

// ---------------------------------------------------------------------------
// Window means of x (fp32-exact routing path). Block=(n,c), thread=window p.
__global__ void k_xwin(const float* __restrict__ x, float* __restrict__ xwin) {
    int b = blockIdx.x;
    int n = b >> 8, c = b & 255;
    int p = threadIdx.x, wy = p >> 4, wx = p & 15;
    const float* pl = x + ((size_t)n * CDIM + c) * HWSZ;
    float s = 0.f;
#pragma unroll
    for (int dy = 0; dy < 4; dy++)
#pragma unroll
        for (int dx = 0; dx < 4; dx++)
            s += pl[(wy * 4 + dy) * WW + wx * 4 + dx];
    xwin[((size_t)(n << 8) + p) * 256 + c] = s * 0.0625f;
}

// ---------------------------------------------------------------------------
// qkwin[m][0:512] = (xwin @ [wq|wk]^T)*g + b  (fp32 vector GEMM, M=2048 K=256)
__global__ void k_qkwin(const float* __restrict__ xwin,
                        const float* __restrict__ wq, const float* __restrict__ wkv,
                        const float* __restrict__ gq, const float* __restrict__ bq,
                        const float* __restrict__ gkv, const float* __restrict__ bkv,
                        float* __restrict__ qkwin) {
    __shared__ float As[16][68];
    __shared__ float Bs[16][68];
    int m0 = blockIdx.x * 64, n0 = blockIdx.y * 64;
    int tid = threadIdx.x;
    int tx = tid & 15, ty = tid >> 4;
    float acc[4][4] = {};
    for (int k0 = 0; k0 < 256; k0 += 16) {
#pragma unroll
        for (int r = 0; r < 4; r++) {
            int lin = tid + r * 256;
            int row = lin >> 4, kk = lin & 15;
            As[kk][row] = xwin[(size_t)(m0 + row) * 256 + k0 + kk];
            int n = n0 + row;
            const float* wr = (n < 256) ? (wq + (size_t)n * 256) : (wkv + (size_t)(n - 256) * 256);
            Bs[kk][row] = wr[k0 + kk];
        }
        __syncthreads();
#pragma unroll
        for (int kk = 0; kk < 16; kk++) {
            float a[4], bb[4];
#pragma unroll
            for (int i = 0; i < 4; i++) a[i] = As[kk][tx * 4 + i];
#pragma unroll
            for (int j = 0; j < 4; j++) bb[j] = Bs[kk][ty * 4 + j];
#pragma unroll
            for (int i = 0; i < 4; i++)
#pragma unroll
                for (int j = 0; j < 4; j++) acc[i][j] += a[i] * bb[j];
        }
        __syncthreads();
    }
#pragma unroll
    for (int j = 0; j < 4; j++) {
        int n = n0 + ty * 4 + j;
        float gg = (n < 256) ? gq[n] : gkv[n - 256];
        float bb = (n < 256) ? bq[n] : bkv[n - 256];
#pragma unroll
        for (int i = 0; i < 4; i++)
            qkwin[(size_t)(m0 + tx * 4 + i) * 512 + n] = acc[i][j] * gg + bb;
    }
}

// ---------------------------------------------------------------------------
// Routing logits: per image, L[pq][key] = sum_c qwin[pq][c] * kwin[key][c].
__global__ void k_logits(const float* __restrict__ qkwin, float* __restrict__ logits) {
    __shared__ float As[16][68];
    __shared__ float Bs[16][68];
    int m0 = blockIdx.x * 64, n0 = blockIdx.y * 64, img = blockIdx.z;
    const float* base = qkwin + (size_t)(img << 8) * 512;
    int tid = threadIdx.x;
    int tx = tid & 15, ty = tid >> 4;
    float acc[4][4] = {};
    for (int k0 = 0; k0 < 256; k0 += 16) {
#pragma unroll
        for (int r = 0; r < 4; r++) {
            int lin = tid + r * 256;
            int row = lin >> 4, kk = lin & 15;
            As[kk][row] = base[(size_t)(m0 + row) * 512 + k0 + kk];
            Bs[kk][row] = base[(size_t)(n0 + row) * 512 + 256 + k0 + kk];
        }
        __syncthreads();
#pragma unroll
        for (int kk = 0; kk < 16; kk++) {
            float a[4], bb[4];
#pragma unroll
            for (int i = 0; i < 4; i++) a[i] = As[kk][tx * 4 + i];
#pragma unroll
            for (int j = 0; j < 4; j++) bb[j] = Bs[kk][ty * 4 + j];
#pragma unroll
            for (int i = 0; i < 4; i++)
#pragma unroll
                for (int j = 0; j < 4; j++) acc[i][j] += a[i] * bb[j];
        }
        __syncthreads();
    }
    float* Lr = logits + (size_t)(img << 8) * 256;
#pragma unroll
    for (int j = 0; j < 4; j++)
#pragma unroll
        for (int i = 0; i < 4; i++)
            Lr[(size_t)(m0 + tx * 4 + i) * 256 + n0 + ty * 4 + j] = acc[i][j];
}

// ---------------------------------------------------------------------------
// Top-4 per row of 256 logits: one wave per row, shuffle argmax, jax tie-break.
__global__ __launch_bounds__(256) void k_topk(const float* __restrict__ logits,
                                              int* __restrict__ topk) {
    int row = blockIdx.x * 4 + (threadIdx.x >> 6);
    int lane = threadIdx.x & 63;
    float4 v4 = *(const float4*)(logits + (size_t)row * 256 + lane * 4);
    float v[4] = {v4.x, v4.y, v4.z, v4.w};
#pragma unroll
    for (int sel = 0; sel < TOPK; sel++) {
        float mv = v[0]; int mi = lane * 4;
#pragma unroll
        for (int j = 1; j < 4; j++)
            if (v[j] > mv) { mv = v[j]; mi = lane * 4 + j; }
#pragma unroll
        for (int off = 1; off < 64; off <<= 1) {
            float ov = __shfl_xor(mv, off);
            int oi = __shfl_xor(mi, off);
            if (ov > mv || (ov == mv && oi < mi)) { mv = ov; mi = oi; }
        }
        if (lane == 0) topk[(size_t)row * TOPK + sel] = mi;
        if ((mi >> 2) == lane) v[mi & 3] = -INFINITY;
    }
}

// ---------------------------------------------------------------------------
// MFMA GEMM with global_load_lds width-16 staging; XCD swizzle (T1).
template <int BM, int BN>
__global__ __launch_bounds__(256) void k_mfma(const bf16* __restrict__ A,
                                              const bf16* __restrict__ Wb,
                                              const float* __restrict__ bias,
                                              bf16* __restrict__ out,
                                              int M, int N, int K) {
    constexpr int WROWS = BM / 2, WCOLS = BN / 2;     // per-wave quadrant
    constexpr int WM = WROWS / 16, WN = WCOLS / 16;   // 16x16 tiles per wave
    constexpr int CA = (BM * 4) / 256;                // 16B chunks/thread for A
    constexpr int CB = (BN * 4) / 256;
    __shared__ bf16 As[BM * 32];
    __shared__ bf16 Bs[BN * 32];
    int gx = gridDim.x;
    int lin = blockIdx.x + blockIdx.y * gx;
    int tot = gx * gridDim.y;
    int cpx = tot >> 3;
    int swz = (lin & 7) * cpx + (lin >> 3);
    int m0 = (swz % gx) * BM, n0 = (swz / gx) * BN;
    int tid = threadIdx.x;
    int w = tid >> 6, lane = tid & 63;
    int wr = w >> 1, wc = w & 1;
    int lm = lane & 15, lq = lane >> 4;
    f4v acc[WM][WN];
#pragma unroll
    for (int i = 0; i < WM; i++)
#pragma unroll
        for (int j = 0; j < WN; j++) acc[i][j] = (f4v){0.f, 0.f, 0.f, 0.f};

    for (int k0 = 0; k0 < K; k0 += 32) {
#pragma unroll
        for (int q = 0; q < CA; q++) {
            int c = tid + q * 256, row = c >> 2, col = c & 3;
            gload_lds16(A + (size_t)(m0 + row) * K + k0 + col * 8,
                        As + (size_t)(w * 64 + q * 256) * 8);
        }
#pragma unroll
        for (int q = 0; q < CB; q++) {
            int c = tid + q * 256, row = c >> 2, col = c & 3;
            gload_lds16(Wb + (size_t)(n0 + row) * K + k0 + col * 8,
                        Bs + (size_t)(w * 64 + q * 256) * 8);
        }
        asm volatile("s_waitcnt vmcnt(0)" ::: "memory");
        __syncthreads();                      // staged tile visible
        s8v af[WM], bfr[WN];
#pragma unroll
        for (int i = 0; i < WM; i++)
            af[i] = *(const s8v*)&As[(wr * WROWS + i * 16 + lm) * 32 + lq * 8];
#pragma unroll
        for (int j = 0; j < WN; j++)
            bfr[j] = *(const s8v*)&Bs[(wc * WCOLS + j * 16 + lm) * 32 + lq * 8];
#pragma unroll
        for (int i = 0; i < WM; i++)
#pragma unroll
            for (int j = 0; j < WN; j++)
                acc[i][j] = __builtin_amdgcn_mfma_f32_16x16x32_bf16(af[i], bfr[j], acc[i][j], 0, 0, 0);
        __syncthreads();                      // LDS reads done; next iter may overwrite
    }
#pragma unroll
    for (int j = 0; j < WN; j++) {
        int n = n0 + wc * WCOLS + j * 16 + lm;
        float bb = bias[n];
#pragma unroll
        for (int i = 0; i < WM; i++) {
            int mb = m0 + wr * WROWS + i * 16 + lq * 4;
#pragma unroll
            for (int r = 0; r < 4; r++)
                out[(size_t)(mb + r) * N + n] = toB(acc[i][j][r] + bb);
        }
    }
}

// ---------------------------------------------------------------------------
// LEPE token-major: per-image XCD affinity + row register window + weights
// staged through LDS (coalesced load, transposed [tap][cg][4ch] layout).
__global__ __launch_bounds__(256) void k_lepe_t(const bf16* __restrict__ qkv,
                                                const float* __restrict__ w_lepe,
                                                const float* __restrict__ b_lepe,
                                                bf16* __restrict__ lepe) {
    __shared__ float lw[25 * 64 * 4];   // [tap][cg][4ch] = 25.6 KB
    int tid = threadIdx.x;
    int cg = tid & 63;                  // 4-channel group, lane-fast
    int slot = tid >> 6;                // wave id 0..3 (wave-uniform)
    int b = blockIdx.x;                 // 0..1023
    int n = b & 7;                      // image -> XCD (round-robin d%8)
    int bx = b >> 3;                    // 0..127: y = bx>>1, x-half = bx&1
    int y = bx >> 1;
    int x0 = (bx & 1) * 32 + slot * 8;  // 8 x-positions per thread
#pragma unroll
    for (int j = 0; j < 25; j++) {
        int g = tid + j * 256;          // 0..6399
        float val = w_lepe[g];
        int ch = g / 25, k = g - ch * 25;
        lw[(k * 64 + (ch >> 2)) * 4 + (ch & 3)] = val;
    }
    float4 b4 = *(const float4*)(b_lepe + cg * 4);
    const float* bias4 = (const float*)&b4;
    __syncthreads();
    const bf16* vb = qkv + (size_t)n * HWSZ * QKVD + 512;
    bf16* dst = lepe + (size_t)n * HWSZ * CDIM;
    float o[8][4];
#pragma unroll
    for (int xi = 0; xi < 8; xi++)
#pragma unroll
        for (int c = 0; c < 4; c++) o[xi][c] = bias4[c];
#pragma unroll
    for (int dy = -2; dy <= 2; dy++) {
        int yy = y + dy;
        if (yy < 0 || yy >= HH) continue;          // wave-uniform
        float rf[12][4];
#pragma unroll
        for (int ii = 0; ii < 12; ii++) {
            int xx = x0 - 2 + ii;
            if (xx >= 0 && xx < WW) {              // wave-uniform
                uint2 v = *(const uint2*)(vb + (size_t)(yy * WW + xx) * QKVD + cg * 4);
                const bf16* pv = (const bf16*)&v;
#pragma unroll
                for (int c = 0; c < 4; c++) rf[ii][c] = toF(pv[c]);
            } else {
#pragma unroll
                for (int c = 0; c < 4; c++) rf[ii][c] = 0.f;
            }
        }
#pragma unroll
        for (int dx = 0; dx < 5; dx++) {
            int k = (dy + 2) * 5 + dx;
            float4 w4v = *(const float4*)&lw[(k * 64 + cg) * 4];
            const float* w4 = (const float*)&w4v;
#pragma unroll
            for (int xi = 0; xi < 8; xi++)
#pragma unroll
                for (int c = 0; c < 4; c++) o[xi][c] += rf[xi + dx][c] * w4[c];
        }
    }
#pragma unroll
    for (int xi = 0; xi < 8; xi++) {
        uint2 pk;
        bf16* pb = (bf16*)&pk;
#pragma unroll
        for (int c = 0; c < 4; c++) pb[c] = toB(o[xi][c]);
        *(uint2*)(dst + (size_t)(y * WW + x0 + xi) * CDIM + cg * 4) = pk;
    }
}

// ---------------------------------------------------------------------------
// MFMA attention + FUSED residual: writes x1 = xt + attn + lepe directly
// (in-place over xt: each (s,dim) owned by exactly one lane of one block).
// Per-image XCD affinity: n = b&7 so XCD k works only image k's qkv slice.
__global__ __launch_bounds__(256) void k_attn(const bf16* __restrict__ qkv,
                                              const int* __restrict__ topk,
                                              const bf16* __restrict__ lepe,
                                              bf16* x1t) {
    __shared__ bf16 vst[256][72];      // V^T [dim][key], pad 72
    __shared__ bf16 plds[4][16][72];   // per-wave P [tok][key]
    __shared__ float lsm[4][16];       // per-wave softmax denominator per tok
    __shared__ int toks[64];           // routed key -> token index (within image)
    int b = blockIdx.x;
    int n = b & 7, p = b >> 3;         // XCD affinity: XCD = b%8 = image
    int wy = p >> 4, wx = p & 15;
    int tid = threadIdx.x;
    if (tid < 64) {
        int rp = topk[((size_t)(n << 8) + p) * TOPK + (tid >> 4)] & 255;
        int st = tid & 15;
        toks[tid] = ((rp >> 4) * 4 + (st >> 2)) * WW + (rp & 15) * 4 + (st & 3);
    }
    __syncthreads();
    const bf16* qbase = qkv + (size_t)n * HWSZ * QKVD;
    {
        int kt = tid & 63, jj = tid >> 6;
#pragma unroll
        for (int pass = 0; pass < 8; pass++) {
            int d0 = pass * 32 + jj * 8;
            uint4 v = *(const uint4*)(qbase + (size_t)toks[kt] * QKVD + 512 + d0);
            const bf16* pv = (const bf16*)&v;
#pragma unroll
            for (int e = 0; e < 8; e++) vst[d0 + e][kt] = pv[e];
        }
    }
    __syncthreads();
    int w = tid >> 6, lane = tid & 63;
    int ln = lane & 15, lq = lane >> 4;
    int myS = (wy * 4 + (ln >> 2)) * WW + wx * 4 + (ln & 3);
    const f4v fz = {0.f, 0.f, 0.f, 0.f};
    for (int hh = 0; hh < 2; hh++) {
        int h = w * 2 + hh;
        s8v qf = *(const s8v*)(qbase + (size_t)myS * QKVD + h * 32 + lq * 8);
        f4v st4[4];
#pragma unroll
        for (int t = 0; t < 4; t++) {
            s8v kf = *(const s8v*)(qbase + (size_t)toks[t * 16 + ln] * QKVD + 256 + h * 32 + lq * 8);
            st4[t] = __builtin_amdgcn_mfma_f32_16x16x32_bf16(kf, qf, fz, 0, 0, 0);
        }
        float mx = -INFINITY;
#pragma unroll
        for (int t = 0; t < 4; t++)
#pragma unroll
            for (int r = 0; r < 4; r++) mx = fmaxf(mx, st4[t][r]);
        mx = fmaxf(mx, __shfl_xor(mx, 16));
        mx = fmaxf(mx, __shfl_xor(mx, 32));
        mx *= ATTN_SCALE;
        float sum = 0.f;
#pragma unroll
        for (int t = 0; t < 4; t++)
#pragma unroll
            for (int r = 0; r < 4; r++) {
                float pp = __expf(st4[t][r] * ATTN_SCALE - mx);
                sum += pp;
                plds[w][ln][t * 16 + lq * 4 + r] = toB(pp);
            }
        sum += __shfl_xor(sum, 16);
        sum += __shfl_xor(sum, 32);
        if (lq == 0) lsm[w][ln] = sum;
        __syncthreads();
        s8v ap0 = *(const s8v*)&plds[w][ln][lq * 8];
        s8v ap1 = *(const s8v*)&plds[w][ln][32 + lq * 8];
#pragma unroll
        for (int dt = 0; dt < 2; dt++) {
            int dim = h * 32 + dt * 16 + ln;
            s8v vv0 = *(const s8v*)&vst[dim][lq * 8];
            s8v vv1 = *(const s8v*)&vst[dim][32 + lq * 8];
            f4v o = __builtin_amdgcn_mfma_f32_16x16x32_bf16(ap0, vv0, fz, 0, 0, 0);
            o = __builtin_amdgcn_mfma_f32_16x16x32_bf16(ap1, vv1, o, 0, 0, 0);
#pragma unroll
            for (int r = 0; r < 4; r++) {
                int t = lq * 4 + r;
                float linv = 1.f / lsm[w][t];
                int s = (wy * 4 + (t >> 2)) * WW + wx * 4 + (t & 3);
                size_t idx = ((size_t)n * HWSZ + s) * CDIM + dim;
                x1t[idx] = toB(o[r] * linv + toF(x1t[idx]) + toF(lepe[idx]));
            }
        }
        __syncthreads();
    }
}

// ---------------------------------------------------------------------------
// Depthwise 3x3 + bias + ReLU, token-major, channels lane-fast.
// v2: weights staged in LDS ([cg][tap*8+ch], pad-81 rows -> 2-way-free b128
// reads), tap-major wdwT layout, per-row sliding window rf[10] (30 loads vs
// 72, 240 cvt vs 576). Fixes the VGPR-starved uncoalesced weight reloads.
__global__ __launch_bounds__(256) void k_dw3_t(const bf16* __restrict__ h1,
                                               const float* __restrict__ wdwT,
                                               bf16* __restrict__ h1p) {
    __shared__ float lw[128 * 81];      // 41.5 KB
    int tid = threadIdx.x;
#pragma unroll
    for (int j = 0; j < 40; j++) {
        int g = tid + j * 256;          // 0..10239, coalesced
        int cgg = g / 80, r = g - cgg * 80;
        lw[cgg * 81 + r] = wdwT[g];
    }
    __syncthreads();
    int cg = tid & 127;
    int slot = tid >> 7;
    int lin = blockIdx.x;               // 0..2047
    int img = lin & 7;                  // image -> XCD
    int seg = lin >> 3;                 // 0..255: y = seg>>2, x-quarter = seg&3
    int y = seg >> 2;
    int x0 = ((seg & 3) << 4) + (slot << 3);
    const float* wl = lw + cg * 81;
    float o[8][8];
    {
        float4 b0 = *(const float4*)&wl[72];
        float4 b1 = *(const float4*)&wl[76];
        const float* p0 = (const float*)&b0;
        const float* p1 = (const float*)&b1;
#pragma unroll
        for (int xi = 0; xi < 8; xi++)
#pragma unroll
            for (int c = 0; c < 4; c++) { o[xi][c] = p0[c]; o[xi][c + 4] = p1[c]; }
    }
    const uint4* src = (const uint4*)h1 + (size_t)img * HWSZ * 128;
    uint4* dst = (uint4*)h1p + (size_t)img * HWSZ * 128;
#pragma unroll
    for (int dy = -1; dy <= 1; dy++) {
        int yy = y + dy;
        if (yy < 0 || yy >= HH) continue;          // wave-uniform
        float rf[10][8];
#pragma unroll
        for (int ii = 0; ii < 10; ii++) {
            int xx = x0 - 1 + ii;
            if (xx >= 0 && xx < WW) {              // wave-uniform
                uint4 v = src[(size_t)(yy * WW + xx) * 128 + cg];
                const bf16* pv = (const bf16*)&v;
#pragma unroll
                for (int c = 0; c < 8; c++) rf[ii][c] = toF(pv[c]);
            } else {
#pragma unroll
                for (int c = 0; c < 8; c++) rf[ii][c] = 0.f;
            }
        }
#pragma unroll
        for (int dx = 0; dx < 3; dx++) {
            int k = (dy + 1) * 3 + dx;
            float4 w0 = *(const float4*)&wl[k * 8];
            float4 w1 = *(const float4*)&wl[k * 8 + 4];
            const float* pw0 = (const float*)&w0;
            const float* pw1 = (const float*)&w1;
#pragma unroll
            for (int xi = 0; xi < 8; xi++)
#pragma unroll
                for (int c = 0; c < 4; c++) {
                    o[xi][c]     += rf[xi + dx][c]     * pw0[c];
                    o[xi][c + 4] += rf[xi + dx][c + 4] * pw1[c];
                }
        }
    }
#pragma unroll
    for (int xi = 0; xi < 8; xi++) {
        uint4 pk;
        bf16* pb = (bf16*)&pk;
#pragma unroll
        for (int c = 0; c < 8; c++) pb[c] = toB(fmaxf(o[xi][c], 0.f));
        dst[(size_t)(y * WW + x0 + xi) * 128 + cg] = pk;
    }
}

// ---------------------------------------------------------------------------
// out (NCHW fp32) = x1 + h2 (both token-major bf16)
__global__ void k_final(const bf16* __restrict__ x1, const bf16* __restrict__ h2,
                        float* __restrict__ out) {
    __shared__ float tile[32][33];
    int s0 = blockIdx.x * 32, c0 = blockIdx.y * 32, n = blockIdx.z;
    int tx = threadIdx.x, ty = threadIdx.y;
#pragma unroll
    for (int r = 0; r < 4; r++) {
        int s = s0 + ty + r * 8;
        size_t idx = ((size_t)n * HWSZ + s) * CDIM + c0 + tx;
        tile[tx][ty + r * 8] = toF(x1[idx]) + toF(h2[idx]);
    }
    __syncthreads();
#pragma unroll
    for (int r = 0; r < 4; r++) {
        int c = c0 + ty + r * 8;
        out[(size_t)n * CDIM * HWSZ + (size_t)c * HWSZ + s0 + tx] = tile[ty + r * 8][tx];
    }
}

// ---------------------------------------------------------------------------
extern "C" void kernel_launch(void* const* d_in, const int* in_sizes, int n_in,
                              void* d_out, int out_size, void* d_ws, size_t ws_size,
                              hipStream_t stream) {
    (void)in_sizes; (void)n_in; (void)out_size; (void)ws_size;
    const float* x      = (const float*)d_in[0];
    const float* wq     = (const float*)d_in[1];
    const float* gq     = (const float*)d_in[2];
    const float* bq     = (const float*)d_in[3];
    const float* wkv    = (const float*)d_in[4];
    const float* gkv    = (const float*)d_in[5];
    const float* bkv    = (const float*)d_in[6];
    const float* w_lepe = (const float*)d_in[7];
    const float* b_lepe = (const float*)d_in[8];
    const float* w_fc1  = (const float*)d_in[9];
    const float* g_fc1  = (const float*)d_in[10];
    const float* b_fc1  = (const float*)d_in[11];
    const float* w_dw   = (const float*)d_in[12];
    const float* b_dw   = (const float*)d_in[13];
    const float* w_fc2  = (const float*)d_in[14];
    const float* g_fc2  = (const float*)d_in[15];
    const float* b_fc2  = (const float*)d_in[16];

    // ws layout (ws_size = 256 MiB). Unchunked phase B.
    char* ws = (char*)d_ws;
    bf16*  qkv    = (bf16*)(ws);                    //   0.0 MB, 50.3
    bf16*  lepe   = (bf16*)(ws + 50331648);         //  48.0 MiB, 16.8
    bf16*  xt     = (bf16*)(ws + 67108864);         //  64.0 MiB, 16.8 (x1 in-place)
    bf16*  x1     = (bf16*)(ws + 67108864);
    bf16*  h1     = (bf16*)(ws + 83886080);         //  80.0 MiB, 67.1
    bf16*  h1p    = (bf16*)(ws + 150994944);        // 144.0 MiB, 67.1
    bf16*  h2     = (bf16*)(ws + 218103808);        // 208.0 MiB, 16.8
    float* xwin   = (float*)(ws + 234881024);       // 224.0 MiB, 2.1
    float* qkwin  = (float*)(ws + 236978176);       // 4.2
    float* logits = (float*)(ws + 241172480);       // 2.1
    int*   tk     = (int*)(ws + 243269632);
    bf16*  wbqkv  = (bf16*)(ws + 243302400);
    bf16*  wbfc1  = (bf16*)(ws + 243695616);
    bf16*  wbfc2  = (bf16*)(ws + 244219904);
    float* bias768= (float*)(ws + 244744192);
    float* wdwT   = (float*)(ws + 244747264);       // 40 KB

    k_prep<<<2856, 256, 0, stream>>>(wq, gq, wkv, gkv, w_fc1, g_fc1, w_fc2, g_fc2,
                                     bq, bkv, w_dw, b_dw,
                                     wbqkv, wbfc1, wbfc2, bias768, wdwT);
    k_xt<<<dim3(128, 8, 8), dim3(32, 8), 0, stream>>>(x, xt);
    k_xwin<<<2048, 256, 0, stream>>>(x, xwin);
    k_qkwin<<<dim3(32, 8), 256, 0, stream>>>(xwin, wq, wkv, gq, bq, gkv, bkv, qkwin);
    k_logits<<<dim3(4, 4, 8), 256, 0, stream>>>(qkwin, logits);
    k_topk<<<512, 256, 0, stream>>>(logits, tk);
    k_mfma<128, 128><<<dim3(256, 6), 256, 0, stream>>>(
        xt, wbqkv, bias768, qkv, TT, QKVD, CDIM);
    k_lepe_t<<<1024, 256, 0, stream>>>(qkv, w_lepe, b_lepe, lepe);
    k_attn<<<2048, 256, 0, stream>>>(qkv, tk, lepe, x1);   // x1 = xt+attn+lepe fused
    k_mfma<128, 128><<<dim3(256, 8), 256, 0, stream>>>(
        x1, wbfc1, b_fc1, h1, TT, HID, CDIM);
    k_dw3_t<<<2048, 256, 0, stream>>>(h1, wdwT, h1p);
    k_mfma<64, 128><<<dim3(512, 2), 256, 0, stream>>>(
        h1p, wbfc2, b_fc2, h2, TT, CDIM, HID);
    k_final<<<dim3(128, 8, 8), dim3(32, 8), 0, stream>>>(x1, h2, (float*)d_out);
}

// Round 17
// 395.665 us; speedup vs baseline: 1.2312x; 1.0039x over previous
//
#include <hip/hip_runtime.h>
#include <hip/hip_bf16.h>

#define NBATCH 8
#define CDIM 256
#define HH 64
#define WW 64
#define HWSZ 4096
#define TT 32768        // NBATCH * HWSZ tokens
#define QKVD 768        // q(256) | k(256) | v(256)
#define TOPK 4
#define HID 1024
#define ATTN_SCALE 0.0625f   // 256^-0.5

typedef __hip_bfloat16 bf16;
typedef __attribute__((ext_vector_type(8))) short s8v;   // 8 bf16 = 4 VGPR
typedef __attribute__((ext_vector_type(4))) float f4v;   // MFMA acc

__device__ __forceinline__ float toF(bf16 v) { return __bfloat162float(v); }
__device__ __forceinline__ bf16  toB(float v) { return __float2bfloat16(v); }

// async 16B global -> LDS (wave-uniform LDS base + lane*16)
__device__ __forceinline__ void gload_lds16(const bf16* g, bf16* l) {
    __builtin_amdgcn_global_load_lds(
        (const __attribute__((address_space(1))) void*)g,
        (__attribute__((address_space(3))) void*)l, 16, 0, 0);
}

// ---------------------------------------------------------------------------
// Prep: fold gamma into weights, cast to bf16; concat qkv bias; and build
// wdwT: per-cg-contiguous dw3 weights+bias fp32, TAP-MAJOR within cg:
// wdwT[cg*80 + k*8 + c] (k=tap 0..8, c=channel 0..7), bias at wdwT[cg*80+72+c].
__global__ void k_prep(const float* __restrict__ wq, const float* __restrict__ gq,
                       const float* __restrict__ wkv, const float* __restrict__ gkv,
                       const float* __restrict__ wfc1, const float* __restrict__ gfc1,
                       const float* __restrict__ wfc2, const float* __restrict__ gfc2,
                       const float* __restrict__ bq, const float* __restrict__ bkv,
                       const float* __restrict__ w_dw, const float* __restrict__ b_dw,
                       bf16* __restrict__ wbqkv, bf16* __restrict__ wbfc1,
                       bf16* __restrict__ wbfc2, float* __restrict__ bias768,
                       float* __restrict__ wdwT) {
    int i = blockIdx.x * 256 + threadIdx.x;
    if (i < 196608) {                       // wbqkv [768][256]
        int r = i >> 8;
        float g = (r < 256) ? gq[r] : gkv[r - 256];
        float w = (r < 256) ? wq[i] : wkv[i - 65536];
        wbqkv[i] = toB(w * g);
        if (i < 768) bias768[i] = (i < 256) ? bq[i] : bkv[i - 256];
    } else if (i < 458752) {                // wbfc1 [1024][256]
        int j = i - 196608;
        wbfc1[j] = toB(wfc1[j] * gfc1[j >> 8]);
    } else if (i < 720896) {                // wbfc2 [256][1024]
        int j = i - 458752;
        wbfc2[j] = toB(wfc2[j] * gfc2[j >> 10]);
    } else if (i < 731136) {                // wdwT [128][80], tap-major
        int j = i - 720896;
        int cg = j / 80, r = j - cg * 80;
        wdwT[j] = (r < 72) ? w_dw[(cg * 8 + (r & 7)) * 9 + (r >> 3)]
                           : b_dw[cg * 8 + (r - 72)];
    }
}

// ---------------------------------------------------------------------------
// x NCHW fp32 -> token-major bf16 xt[m][c]
__global__ void k_xt(const float* __restrict__ x, bf16* __restrict__ xt) {
    __shared__ float tile[32][33];
    int s0 = blockIdx.x * 32, c0 = blockIdx.y * 32, n = blockIdx.z;
    int tx = threadIdx.x, ty = threadIdx.y;
#pragma unroll
    for (int r = 0; r < 4; r++)
        tile[ty + r * 8][tx] = x[(size_t)n * CDIM * HWSZ + (size_t)(c0 + ty + r * 8) * HWSZ + s0 + tx];
    __syncthreads();
#pragma unroll
    for (int r = 0; r < 4; r++)
        xt[((size_t)n * HWSZ + s0 + ty + r * 8) * CDIM + c0 + tx] = toB(tile[tx][ty + r * 8]);
}

// ---------------------------------------------------------------------------
// Window means of x (fp32-exact routing path). Block=(n,c), thread=window p.
__global__ void k_xwin(const float* __restrict__ x, float* __restrict__ xwin) {
    int b = blockIdx.x;
    int n = b >> 8, c = b & 255;
    int p = threadIdx.x, wy = p >> 4, wx = p & 15;
    const float* pl = x + ((size_t)n * CDIM + c) * HWSZ;
    float s = 0.f;
#pragma unroll
    for (int dy = 0; dy < 4; dy++)
#pragma unroll
        for (int dx = 0; dx < 4; dx++)
            s += pl[(wy * 4 + dy) * WW + wx * 4 + dx];
    xwin[((size_t)(n << 8) + p) * 256 + c] = s * 0.0625f;
}

// ---------------------------------------------------------------------------
// qkwin[m][0:512] = (xwin @ [wq|wk]^T)*g + b  (fp32 vector GEMM, M=2048 K=256)
__global__ void k_qkwin(const float* __restrict__ xwin,
                        const float* __restrict__ wq, const float* __restrict__ wkv,
                        const float* __restrict__ gq, const float* __restrict__ bq,
                        const float* __restrict__ gkv, const float* __restrict__ bkv,
                        float* __restrict__ qkwin) {
    __shared__ float As[16][68];
    __shared__ float Bs[16][68];
    int m0 = blockIdx.x * 64, n0 = blockIdx.y * 64;
    int tid = threadIdx.x;
    int tx = tid & 15, ty = tid >> 4;
    float acc[4][4] = {};
    for (int k0 = 0; k0 < 256; k0 += 16) {
#pragma unroll
        for (int r = 0; r < 4; r++) {
            int lin = tid + r * 256;
            int row = lin >> 4, kk = lin & 15;
            As[kk][row] = xwin[(size_t)(m0 + row) * 256 + k0 + kk];
            int n = n0 + row;
            const float* wr = (n < 256) ? (wq + (size_t)n * 256) : (wkv + (size_t)(n - 256) * 256);
            Bs[kk][row] = wr[k0 + kk];
        }
        __syncthreads();
#pragma unroll
        for (int kk = 0; kk < 16; kk++) {
            float a[4], bb[4];
#pragma unroll
            for (int i = 0; i < 4; i++) a[i] = As[kk][tx * 4 + i];
#pragma unroll
            for (int j = 0; j < 4; j++) bb[j] = Bs[kk][ty * 4 + j];
#pragma unroll
            for (int i = 0; i < 4; i++)
#pragma unroll
                for (int j = 0; j < 4; j++) acc[i][j] += a[i] * bb[j];
        }
        __syncthreads();
    }
#pragma unroll
    for (int j = 0; j < 4; j++) {
        int n = n0 + ty * 4 + j;
        float gg = (n < 256) ? gq[n] : gkv[n - 256];
        float bb = (n < 256) ? bq[n] : bkv[n - 256];
#pragma unroll
        for (int i = 0; i < 4; i++)
            qkwin[(size_t)(m0 + tx * 4 + i) * 512 + n] = acc[i][j] * gg + bb;
    }
}

// ---------------------------------------------------------------------------
// Routing logits: per image, L[pq][key] = sum_c qwin[pq][c] * kwin[key][c].
__global__ void k_logits(const float* __restrict__ qkwin, float* __restrict__ logits) {
    __shared__ float As[16][68];
    __shared__ float Bs[16][68];
    int m0 = blockIdx.x * 64, n0 = blockIdx.y * 64, img = blockIdx.z;
    const float* base = qkwin + (size_t)(img << 8) * 512;
    int tid = threadIdx.x;
    int tx = tid & 15, ty = tid >> 4;
    float acc[4][4] = {};
    for (int k0 = 0; k0 < 256; k0 += 16) {
#pragma unroll
        for (int r = 0; r < 4; r++) {
            int lin = tid + r * 256;
            int row = lin >> 4, kk = lin & 15;
            As[kk][row] = base[(size_t)(m0 + row) * 512 + k0 + kk];
            Bs[kk][row] = base[(size_t)(n0 + row) * 512 + 256 + k0 + kk];
        }
        __syncthreads();
#pragma unroll
        for (int kk = 0; kk < 16; kk++) {
            float a[4], bb[4];
#pragma unroll
            for (int i = 0; i < 4; i++) a[i] = As[kk][tx * 4 + i];
#pragma unroll
            for (int j = 0; j < 4; j++) bb[j] = Bs[kk][ty * 4 + j];
#pragma unroll
            for (int i = 0; i < 4; i++)
#pragma unroll
                for (int j = 0; j < 4; j++) acc[i][j] += a[i] * bb[j];
        }
        __syncthreads();
    }
    float* Lr = logits + (size_t)(img << 8) * 256;
#pragma unroll
    for (int j = 0; j < 4; j++)
#pragma unroll
        for (int i = 0; i < 4; i++)
            Lr[(size_t)(m0 + tx * 4 + i) * 256 + n0 + ty * 4 + j] = acc[i][j];
}

// ---------------------------------------------------------------------------
// Top-4 per row of 256 logits: one wave per row, shuffle argmax, jax tie-break.
__global__ __launch_bounds__(256) void k_topk(const float* __restrict__ logits,
                                              int* __restrict__ topk) {
    int row = blockIdx.x * 4 + (threadIdx.x >> 6);
    int lane = threadIdx.x & 63;
    float4 v4 = *(const float4*)(logits + (size_t)row * 256 + lane * 4);
    float v[4] = {v4.x, v4.y, v4.z, v4.w};
#pragma unroll
    for (int sel = 0; sel < TOPK; sel++) {
        float mv = v[0]; int mi = lane * 4;
#pragma unroll
        for (int j = 1; j < 4; j++)
            if (v[j] > mv) { mv = v[j]; mi = lane * 4 + j; }
#pragma unroll
        for (int off = 1; off < 64; off <<= 1) {
            float ov = __shfl_xor(mv, off);
            int oi = __shfl_xor(mi, off);
            if (ov > mv || (ov == mv && oi < mi)) { mv = ov; mi = oi; }
        }
        if (lane == 0) topk[(size_t)row * TOPK + sel] = mi;
        if ((mi >> 2) == lane) v[mi & 3] = -INFINITY;
    }
}

// ---------------------------------------------------------------------------
// MFMA GEMM with global_load_lds width-16 staging; XCD swizzle (T1).
template <int BM, int BN>
__global__ __launch_bounds__(256) void k_mfma(const bf16* __restrict__ A,
                                              const bf16* __restrict__ Wb,
                                              const float* __restrict__ bias,
                                              bf16* __restrict__ out,
                                              int M, int N, int K) {
    constexpr int WROWS = BM / 2, WCOLS = BN / 2;     // per-wave quadrant
    constexpr int WM = WROWS / 16, WN = WCOLS / 16;   // 16x16 tiles per wave
    constexpr int CA = (BM * 4) / 256;                // 16B chunks/thread for A
    constexpr int CB = (BN * 4) / 256;
    __shared__ bf16 As[BM * 32];
    __shared__ bf16 Bs[BN * 32];
    int gx = gridDim.x;
    int lin = blockIdx.x + blockIdx.y * gx;
    int tot = gx * gridDim.y;
    int cpx = tot >> 3;
    int swz = (lin & 7) * cpx + (lin >> 3);
    int m0 = (swz % gx) * BM, n0 = (swz / gx) * BN;
    int tid = threadIdx.x;
    int w = tid >> 6, lane = tid & 63;
    int wr = w >> 1, wc = w & 1;
    int lm = lane & 15, lq = lane >> 4;
    f4v acc[WM][WN];
#pragma unroll
    for (int i = 0; i < WM; i++)
#pragma unroll
        for (int j = 0; j < WN; j++) acc[i][j] = (f4v){0.f, 0.f, 0.f, 0.f};

    for (int k0 = 0; k0 < K; k0 += 32) {
#pragma unroll
        for (int q = 0; q < CA; q++) {
            int c = tid + q * 256, row = c >> 2, col = c & 3;
            gload_lds16(A + (size_t)(m0 + row) * K + k0 + col * 8,
                        As + (size_t)(w * 64 + q * 256) * 8);
        }
#pragma unroll
        for (int q = 0; q < CB; q++) {
            int c = tid + q * 256, row = c >> 2, col = c & 3;
            gload_lds16(Wb + (size_t)(n0 + row) * K + k0 + col * 8,
                        Bs + (size_t)(w * 64 + q * 256) * 8);
        }
        asm volatile("s_waitcnt vmcnt(0)" ::: "memory");
        __syncthreads();                      // staged tile visible
        s8v af[WM], bfr[WN];
#pragma unroll
        for (int i = 0; i < WM; i++)
            af[i] = *(const s8v*)&As[(wr * WROWS + i * 16 + lm) * 32 + lq * 8];
#pragma unroll
        for (int j = 0; j < WN; j++)
            bfr[j] = *(const s8v*)&Bs[(wc * WCOLS + j * 16 + lm) * 32 + lq * 8];
#pragma unroll
        for (int i = 0; i < WM; i++)
#pragma unroll
            for (int j = 0; j < WN; j++)
                acc[i][j] = __builtin_amdgcn_mfma_f32_16x16x32_bf16(af[i], bfr[j], acc[i][j], 0, 0, 0);
        __syncthreads();                      // LDS reads done; next iter may overwrite
    }
#pragma unroll
    for (int j = 0; j < WN; j++) {
        int n = n0 + wc * WCOLS + j * 16 + lm;
        float bb = bias[n];
#pragma unroll
        for (int i = 0; i < WM; i++) {
            int mb = m0 + wr * WROWS + i * 16 + lq * 4;
#pragma unroll
            for (int r = 0; r < 4; r++)
                out[(size_t)(mb + r) * N + n] = toB(acc[i][j][r] + bb);
        }
    }
}

// ---------------------------------------------------------------------------
// LEPE token-major: per-image XCD affinity + row register window + weights
// staged through LDS (coalesced load, transposed [tap][cg][4ch] layout).
__global__ __launch_bounds__(256) void k_lepe_t(const bf16* __restrict__ qkv,
                                                const float* __restrict__ w_lepe,
                                                const float* __restrict__ b_lepe,
                                                bf16* __restrict__ lepe) {
    __shared__ float lw[25 * 64 * 4];   // [tap][cg][4ch] = 25.6 KB
    int tid = threadIdx.x;
    int cg = tid & 63;                  // 4-channel group, lane-fast
    int slot = tid >> 6;                // wave id 0..3 (wave-uniform)
    int b = blockIdx.x;                 // 0..1023
    int n = b & 7;                      // image -> XCD (round-robin d%8)
    int bx = b >> 3;                    // 0..127: y = bx>>1, x-half = bx&1
    int y = bx >> 1;
    int x0 = (bx & 1) * 32 + slot * 8;  // 8 x-positions per thread
#pragma unroll
    for (int j = 0; j < 25; j++) {
        int g = tid + j * 256;          // 0..6399
        float val = w_lepe[g];
        int ch = g / 25, k = g - ch * 25;
        lw[(k * 64 + (ch >> 2)) * 4 + (ch & 3)] = val;
    }
    float4 b4 = *(const float4*)(b_lepe + cg * 4);
    const float* bias4 = (const float*)&b4;
    __syncthreads();
    const bf16* vb = qkv + (size_t)n * HWSZ * QKVD + 512;
    bf16* dst = lepe + (size_t)n * HWSZ * CDIM;
    float o[8][4];
#pragma unroll
    for (int xi = 0; xi < 8; xi++)
#pragma unroll
        for (int c = 0; c < 4; c++) o[xi][c] = bias4[c];
#pragma unroll
    for (int dy = -2; dy <= 2; dy++) {
        int yy = y + dy;
        if (yy < 0 || yy >= HH) continue;          // wave-uniform
        float rf[12][4];
#pragma unroll
        for (int ii = 0; ii < 12; ii++) {
            int xx = x0 - 2 + ii;
            if (xx >= 0 && xx < WW) {              // wave-uniform
                uint2 v = *(const uint2*)(vb + (size_t)(yy * WW + xx) * QKVD + cg * 4);
                const bf16* pv = (const bf16*)&v;
#pragma unroll
                for (int c = 0; c < 4; c++) rf[ii][c] = toF(pv[c]);
            } else {
#pragma unroll
                for (int c = 0; c < 4; c++) rf[ii][c] = 0.f;
            }
        }
#pragma unroll
        for (int dx = 0; dx < 5; dx++) {
            int k = (dy + 2) * 5 + dx;
            float4 w4v = *(const float4*)&lw[(k * 64 + cg) * 4];
            const float* w4 = (const float*)&w4v;
#pragma unroll
            for (int xi = 0; xi < 8; xi++)
#pragma unroll
                for (int c = 0; c < 4; c++) o[xi][c] += rf[xi + dx][c] * w4[c];
        }
    }
#pragma unroll
    for (int xi = 0; xi < 8; xi++) {
        uint2 pk;
        bf16* pb = (bf16*)&pk;
#pragma unroll
        for (int c = 0; c < 4; c++) pb[c] = toB(o[xi][c]);
        *(uint2*)(dst + (size_t)(y * WW + x0 + xi) * CDIM + cg * 4) = pk;
    }
}

// ---------------------------------------------------------------------------
// MFMA attention + FUSED residual: writes x1 = xt + attn + lepe directly
// (in-place over xt: each (s,dim) owned by exactly one lane of one block).
// Per-image XCD affinity: n = b&7 so XCD k works only image k's qkv slice.
__global__ __launch_bounds__(256) void k_attn(const bf16* __restrict__ qkv,
                                              const int* __restrict__ topk,
                                              const bf16* __restrict__ lepe,
                                              bf16* x1t) {
    __shared__ bf16 vst[256][72];      // V^T [dim][key], pad 72
    __shared__ bf16 plds[4][16][72];   // per-wave P [tok][key]
    __shared__ float lsm[4][16];       // per-wave softmax denominator per tok
    __shared__ int toks[64];           // routed key -> token index (within image)
    int b = blockIdx.x;
    int n = b & 7, p = b >> 3;         // XCD affinity: XCD = b%8 = image
    int wy = p >> 4, wx = p & 15;
    int tid = threadIdx.x;
    if (tid < 64) {
        int rp = topk[((size_t)(n << 8) + p) * TOPK + (tid >> 4)] & 255;
        int st = tid & 15;
        toks[tid] = ((rp >> 4) * 4 + (st >> 2)) * WW + (rp & 15) * 4 + (st & 3);
    }
    __syncthreads();
    const bf16* qbase = qkv + (size_t)n * HWSZ * QKVD;
    {
        int kt = tid & 63, jj = tid >> 6;
#pragma unroll
        for (int pass = 0; pass < 8; pass++) {
            int d0 = pass * 32 + jj * 8;
            uint4 v = *(const uint4*)(qbase + (size_t)toks[kt] * QKVD + 512 + d0);
            const bf16* pv = (const bf16*)&v;
#pragma unroll
            for (int e = 0; e < 8; e++) vst[d0 + e][kt] = pv[e];
        }
    }
    __syncthreads();
    int w = tid >> 6, lane = tid & 63;
    int ln = lane & 15, lq = lane >> 4;
    int myS = (wy * 4 + (ln >> 2)) * WW + wx * 4 + (ln & 3);
    const f4v fz = {0.f, 0.f, 0.f, 0.f};
    for (int hh = 0; hh < 2; hh++) {
        int h = w * 2 + hh;
        s8v qf = *(const s8v*)(qbase + (size_t)myS * QKVD + h * 32 + lq * 8);
        f4v st4[4];
#pragma unroll
        for (int t = 0; t < 4; t++) {
            s8v kf = *(const s8v*)(qbase + (size_t)toks[t * 16 + ln] * QKVD + 256 + h * 32 + lq * 8);
            st4[t] = __builtin_amdgcn_mfma_f32_16x16x32_bf16(kf, qf, fz, 0, 0, 0);
        }
        float mx = -INFINITY;
#pragma unroll
        for (int t = 0; t < 4; t++)
#pragma unroll
            for (int r = 0; r < 4; r++) mx = fmaxf(mx, st4[t][r]);
        mx = fmaxf(mx, __shfl_xor(mx, 16));
        mx = fmaxf(mx, __shfl_xor(mx, 32));
        mx *= ATTN_SCALE;
        float sum = 0.f;
#pragma unroll
        for (int t = 0; t < 4; t++)
#pragma unroll
            for (int r = 0; r < 4; r++) {
                float pp = __expf(st4[t][r] * ATTN_SCALE - mx);
                sum += pp;
                plds[w][ln][t * 16 + lq * 4 + r] = toB(pp);
            }
        sum += __shfl_xor(sum, 16);
        sum += __shfl_xor(sum, 32);
        if (lq == 0) lsm[w][ln] = sum;
        __syncthreads();
        s8v ap0 = *(const s8v*)&plds[w][ln][lq * 8];
        s8v ap1 = *(const s8v*)&plds[w][ln][32 + lq * 8];
#pragma unroll
        for (int dt = 0; dt < 2; dt++) {
            int dim = h * 32 + dt * 16 + ln;
            s8v vv0 = *(const s8v*)&vst[dim][lq * 8];
            s8v vv1 = *(const s8v*)&vst[dim][32 + lq * 8];
            f4v o = __builtin_amdgcn_mfma_f32_16x16x32_bf16(ap0, vv0, fz, 0, 0, 0);
            o = __builtin_amdgcn_mfma_f32_16x16x32_bf16(ap1, vv1, o, 0, 0, 0);
#pragma unroll
            for (int r = 0; r < 4; r++) {
                int t = lq * 4 + r;
                float linv = 1.f / lsm[w][t];
                int s = (wy * 4 + (t >> 2)) * WW + wx * 4 + (t & 3);
                size_t idx = ((size_t)n * HWSZ + s) * CDIM + dim;
                x1t[idx] = toB(o[r] * linv + toF(x1t[idx]) + toF(lepe[idx]));
            }
        }
        __syncthreads();
    }
}

// ---------------------------------------------------------------------------
// Depthwise 3x3 + bias + ReLU, token-major, channels lane-fast.
// v3: HALF-CHANNEL blocks — 64 cgs/block -> LDS 20.7 KB -> 7 blocks/CU
// (v2's 41.5 KB capped residency at 3 blocks/CU, Occupancy 16%). Same
// per-thread work; grid still 2048 with img = lin&7 XCD affinity.
__global__ __launch_bounds__(256) void k_dw3_t(const bf16* __restrict__ h1,
                                               const float* __restrict__ wdwT,
                                               bf16* __restrict__ h1p) {
    __shared__ float lw[64 * 81];       // 20.7 KB
    int tid = threadIdx.x;
    int lin = blockIdx.x;               // 0..2047
    int img = lin & 7;                  // image -> XCD
    int rest = lin >> 3;                // 0..255
    int chalf = rest & 1;               // cg half: 0..63 or 64..127
    int seg = rest >> 1;                // 0..127: y = seg>>1, x-half = seg&1
    int y = seg >> 1;
    int xh = seg & 1;
    // stage this half's weights: 5120 floats, coalesced
#pragma unroll
    for (int j = 0; j < 20; j++) {
        int g = tid + j * 256;          // 0..5119
        int cgg = g / 80, r = g - cgg * 80;
        lw[cgg * 81 + r] = wdwT[chalf * 5120 + g];
    }
    __syncthreads();
    int cgl = tid & 63;                 // local cg, lane-fast
    int slot = tid >> 6;                // 0..3 (wave-uniform)
    int cg = chalf * 64 + cgl;
    int x0 = xh * 32 + slot * 8;        // 8 x-positions per thread
    const float* wl = lw + cgl * 81;
    float o[8][8];
    {
        float4 b0 = *(const float4*)&wl[72];
        float4 b1 = *(const float4*)&wl[76];
        const float* p0 = (const float*)&b0;
        const float* p1 = (const float*)&b1;
#pragma unroll
        for (int xi = 0; xi < 8; xi++)
#pragma unroll
            for (int c = 0; c < 4; c++) { o[xi][c] = p0[c]; o[xi][c + 4] = p1[c]; }
    }
    const uint4* src = (const uint4*)h1 + (size_t)img * HWSZ * 128;
    uint4* dst = (uint4*)h1p + (size_t)img * HWSZ * 128;
#pragma unroll
    for (int dy = -1; dy <= 1; dy++) {
        int yy = y + dy;
        if (yy < 0 || yy >= HH) continue;          // wave-uniform
        float rf[10][8];
#pragma unroll
        for (int ii = 0; ii < 10; ii++) {
            int xx = x0 - 1 + ii;
            if (xx >= 0 && xx < WW) {              // wave-uniform
                uint4 v = src[(size_t)(yy * WW + xx) * 128 + cg];
                const bf16* pv = (const bf16*)&v;
#pragma unroll
                for (int c = 0; c < 8; c++) rf[ii][c] = toF(pv[c]);
            } else {
#pragma unroll
                for (int c = 0; c < 8; c++) rf[ii][c] = 0.f;
            }
        }
#pragma unroll
        for (int dx = 0; dx < 3; dx++) {
            int k = (dy + 1) * 3 + dx;
            float4 w0 = *(const float4*)&wl[k * 8];
            float4 w1 = *(const float4*)&wl[k * 8 + 4];
            const float* pw0 = (const float*)&w0;
            const float* pw1 = (const float*)&w1;
#pragma unroll
            for (int xi = 0; xi < 8; xi++)
#pragma unroll
                for (int c = 0; c < 4; c++) {
                    o[xi][c]     += rf[xi + dx][c]     * pw0[c];
                    o[xi][c + 4] += rf[xi + dx][c + 4] * pw1[c];
                }
        }
    }
#pragma unroll
    for (int xi = 0; xi < 8; xi++) {
        uint4 pk;
        bf16* pb = (bf16*)&pk;
#pragma unroll
        for (int c = 0; c < 8; c++) pb[c] = toB(fmaxf(o[xi][c], 0.f));
        dst[(size_t)(y * WW + x0 + xi) * 128 + cg] = pk;
    }
}

// ---------------------------------------------------------------------------
// out (NCHW fp32) = x1 + h2 (both token-major bf16)
__global__ void k_final(const bf16* __restrict__ x1, const bf16* __restrict__ h2,
                        float* __restrict__ out) {
    __shared__ float tile[32][33];
    int s0 = blockIdx.x * 32, c0 = blockIdx.y * 32, n = blockIdx.z;
    int tx = threadIdx.x, ty = threadIdx.y;
#pragma unroll
    for (int r = 0; r < 4; r++) {
        int s = s0 + ty + r * 8;
        size_t idx = ((size_t)n * HWSZ + s) * CDIM + c0 + tx;
        tile[tx][ty + r * 8] = toF(x1[idx]) + toF(h2[idx]);
    }
    __syncthreads();
#pragma unroll
    for (int r = 0; r < 4; r++) {
        int c = c0 + ty + r * 8;
        out[(size_t)n * CDIM * HWSZ + (size_t)c * HWSZ + s0 + tx] = tile[ty + r * 8][tx];
    }
}

// ---------------------------------------------------------------------------
extern "C" void kernel_launch(void* const* d_in, const int* in_sizes, int n_in,
                              void* d_out, int out_size, void* d_ws, size_t ws_size,
                              hipStream_t stream) {
    (void)in_sizes; (void)n_in; (void)out_size; (void)ws_size;
    const float* x      = (const float*)d_in[0];
    const float* wq     = (const float*)d_in[1];
    const float* gq     = (const float*)d_in[2];
    const float* bq     = (const float*)d_in[3];
    const float* wkv    = (const float*)d_in[4];
    const float* gkv    = (const float*)d_in[5];
    const float* bkv    = (const float*)d_in[6];
    const float* w_lepe = (const float*)d_in[7];
    const float* b_lepe = (const float*)d_in[8];
    const float* w_fc1  = (const float*)d_in[9];
    const float* g_fc1  = (const float*)d_in[10];
    const float* b_fc1  = (const float*)d_in[11];
    const float* w_dw   = (const float*)d_in[12];
    const float* b_dw   = (const float*)d_in[13];
    const float* w_fc2  = (const float*)d_in[14];
    const float* g_fc2  = (const float*)d_in[15];
    const float* b_fc2  = (const float*)d_in[16];

    // ws layout (ws_size = 256 MiB). Unchunked phase B.
    char* ws = (char*)d_ws;
    bf16*  qkv    = (bf16*)(ws);                    //   0.0 MB, 50.3
    bf16*  lepe   = (bf16*)(ws + 50331648);         //  48.0 MiB, 16.8
    bf16*  xt     = (bf16*)(ws + 67108864);         //  64.0 MiB, 16.8 (x1 in-place)
    bf16*  x1     = (bf16*)(ws + 67108864);
    bf16*  h1     = (bf16*)(ws + 83886080);         //  80.0 MiB, 67.1
    bf16*  h1p    = (bf16*)(ws + 150994944);        // 144.0 MiB, 67.1
    bf16*  h2     = (bf16*)(ws + 218103808);        // 208.0 MiB, 16.8
    float* xwin   = (float*)(ws + 234881024);       // 224.0 MiB, 2.1
    float* qkwin  = (float*)(ws + 236978176);       // 4.2
    float* logits = (float*)(ws + 241172480);       // 2.1
    int*   tk     = (int*)(ws + 243269632);
    bf16*  wbqkv  = (bf16*)(ws + 243302400);
    bf16*  wbfc1  = (bf16*)(ws + 243695616);
    bf16*  wbfc2  = (bf16*)(ws + 244219904);
    float* bias768= (float*)(ws + 244744192);
    float* wdwT   = (float*)(ws + 244747264);       // 40 KB

    k_prep<<<2856, 256, 0, stream>>>(wq, gq, wkv, gkv, w_fc1, g_fc1, w_fc2, g_fc2,
                                     bq, bkv, w_dw, b_dw,
                                     wbqkv, wbfc1, wbfc2, bias768, wdwT);
    k_xt<<<dim3(128, 8, 8), dim3(32, 8), 0, stream>>>(x, xt);
    k_xwin<<<2048, 256, 0, stream>>>(x, xwin);
    k_qkwin<<<dim3(32, 8), 256, 0, stream>>>(xwin, wq, wkv, gq, bq, gkv, bkv, qkwin);
    k_logits<<<dim3(4, 4, 8), 256, 0, stream>>>(qkwin, logits);
    k_topk<<<512, 256, 0, stream>>>(logits, tk);
    k_mfma<128, 128><<<dim3(256, 6), 256, 0, stream>>>(
        xt, wbqkv, bias768, qkv, TT, QKVD, CDIM);
    k_lepe_t<<<1024, 256, 0, stream>>>(qkv, w_lepe, b_lepe, lepe);
    k_attn<<<2048, 256, 0, stream>>>(qkv, tk, lepe, x1);   // x1 = xt+attn+lepe fused
    k_mfma<128, 128><<<dim3(256, 8), 256, 0, stream>>>(
        x1, wbfc1, b_fc1, h1, TT, HID, CDIM);
    k_dw3_t<<<2048, 256, 0, stream>>>(h1, wdwT, h1p);
    k_mfma<64, 128><<<dim3(512, 2), 256, 0, stream>>>(
        h1p, wbfc2, b_fc2, h2, TT, CDIM, HID);
    k_final<<<dim3(128, 8, 8), dim3(32, 8), 0, stream>>>(x1, h2, (float*)d_out);
}

// Round 19
// 386.740 us; speedup vs baseline: 1.2596x; 1.0231x over previous
//
#include <hip/hip_runtime.h>
#include <hip/hip_bf16.h>

#define NBATCH 8
#define CDIM 256
#define HH 64
#define WW 64
#define HWSZ 4096
#define TT 32768        // NBATCH * HWSZ tokens
#define QKVD 768        // q(256) | k(256) | v(256)
#define TOPK 4
#define HID 1024
#define ATTN_SCALE 0.0625f   // 256^-0.5

typedef __hip_bfloat16 bf16;
typedef __attribute__((ext_vector_type(8))) short s8v;   // 8 bf16 = 4 VGPR
typedef __attribute__((ext_vector_type(4))) float f4v;   // MFMA acc

__device__ __forceinline__ float toF(bf16 v) { return __bfloat162float(v); }
__device__ __forceinline__ bf16  toB(float v) { return __float2bfloat16(v); }

// async 16B global -> LDS (wave-uniform LDS base + lane*16)
__device__ __forceinline__ void gload_lds16(const bf16* g, bf16* l) {
    __builtin_amdgcn_global_load_lds(
        (const __attribute__((address_space(1))) void*)g,
        (__attribute__((address_space(3))) void*)l, 16, 0, 0);
}

// ---------------------------------------------------------------------------
// Prep: fold gamma into weights, cast to bf16; concat qkv bias; and build
// wdwT: per-cg-contiguous dw3 weights+bias fp32, TAP-MAJOR within cg:
// wdwT[cg*80 + k*8 + c] (k=tap 0..8, c=channel 0..7), bias at wdwT[cg*80+72+c].
__global__ void k_prep(const float* __restrict__ wq, const float* __restrict__ gq,
                       const float* __restrict__ wkv, const float* __restrict__ gkv,
                       const float* __restrict__ wfc1, const float* __restrict__ gfc1,
                       const float* __restrict__ wfc2, const float* __restrict__ gfc2,
                       const float* __restrict__ bq, const float* __restrict__ bkv,
                       const float* __restrict__ w_dw, const float* __restrict__ b_dw,
                       bf16* __restrict__ wbqkv, bf16* __restrict__ wbfc1,
                       bf16* __restrict__ wbfc2, float* __restrict__ bias768,
                       float* __restrict__ wdwT) {
    int i = blockIdx.x * 256 + threadIdx.x;
    if (i < 196608) {                       // wbqkv [768][256]
        int r = i >> 8;
        float g = (r < 256) ? gq[r] : gkv[r - 256];
        float w = (r < 256) ? wq[i] : wkv[i - 65536];
        wbqkv[i] = toB(w * g);
        if (i < 768) bias768[i] = (i < 256) ? bq[i] : bkv[i - 256];
    } else if (i < 458752) {                // wbfc1 [1024][256]
        int j = i - 196608;
        wbfc1[j] = toB(wfc1[j] * gfc1[j >> 8]);
    } else if (i < 720896) {                // wbfc2 [256][1024]
        int j = i - 458752;
        wbfc2[j] = toB(wfc2[j] * gfc2[j >> 10]);
    } else if (i < 731136) {                // wdwT [128][80], tap-major
        int j = i - 720896;
        int cg = j / 80, r = j - cg * 80;
        wdwT[j] = (r < 72) ? w_dw[(cg * 8 + (r & 7)) * 9 + (r >> 3)]
                           : b_dw[cg * 8 + (r - 72)];
    }
}

// ---------------------------------------------------------------------------
// x NCHW fp32 -> token-major bf16 xt[m][c]
__global__ void k_xt(const float* __restrict__ x, bf16* __restrict__ xt) {
    __shared__ float tile[32][33];
    int s0 = blockIdx.x * 32, c0 = blockIdx.y * 32, n = blockIdx.z;
    int tx = threadIdx.x, ty = threadIdx.y;
#pragma unroll
    for (int r = 0; r < 4; r++)
        tile[ty + r * 8][tx] = x[(size_t)n * CDIM * HWSZ + (size_t)(c0 + ty + r * 8) * HWSZ + s0 + tx];
    __syncthreads();
#pragma unroll
    for (int r = 0; r < 4; r++)
        xt[((size_t)n * HWSZ + s0 + ty + r * 8) * CDIM + c0 + tx] = toB(tile[tx][ty + r * 8]);
}

// ---------------------------------------------------------------------------
// Window means of x (fp32-exact routing path). Block=(n,c), thread=window p.
__global__ void k_xwin(const float* __restrict__ x, float* __restrict__ xwin) {
    int b = blockIdx.x;
    int n = b >> 8, c = b & 255;
    int p = threadIdx.x, wy = p >> 4, wx = p & 15;
    const float* pl = x + ((size_t)n * CDIM + c) * HWSZ;
    float s = 0.f;
#pragma unroll
    for (int dy = 0; dy < 4; dy++)
#pragma unroll
        for (int dx = 0; dx < 4; dx++)
            s += pl[(wy * 4 + dy) * WW + wx * 4 + dx];
    xwin[((size_t)(n << 8) + p) * 256 + c] = s * 0.0625f;
}

// ---------------------------------------------------------------------------
// qkwin[m][0:512] = (xwin @ [wq|wk]^T)*g + b  (fp32 vector GEMM, M=2048 K=256)
__global__ void k_qkwin(const float* __restrict__ xwin,
                        const float* __restrict__ wq, const float* __restrict__ wkv,
                        const float* __restrict__ gq, const float* __restrict__ bq,
                        const float* __restrict__ gkv, const float* __restrict__ bkv,
                        float* __restrict__ qkwin) {
    __shared__ float As[16][68];
    __shared__ float Bs[16][68];
    int m0 = blockIdx.x * 64, n0 = blockIdx.y * 64;
    int tid = threadIdx.x;
    int tx = tid & 15, ty = tid >> 4;
    float acc[4][4] = {};
    for (int k0 = 0; k0 < 256; k0 += 16) {
#pragma unroll
        for (int r = 0; r < 4; r++) {
            int lin = tid + r * 256;
            int row = lin >> 4, kk = lin & 15;
            As[kk][row] = xwin[(size_t)(m0 + row) * 256 + k0 + kk];
            int n = n0 + row;
            const float* wr = (n < 256) ? (wq + (size_t)n * 256) : (wkv + (size_t)(n - 256) * 256);
            Bs[kk][row] = wr[k0 + kk];
        }
        __syncthreads();
#pragma unroll
        for (int kk = 0; kk < 16; kk++) {
            float a[4], bb[4];
#pragma unroll
            for (int i = 0; i < 4; i++) a[i] = As[kk][tx * 4 + i];
#pragma unroll
            for (int j = 0; j < 4; j++) bb[j] = Bs[kk][ty * 4 + j];
#pragma unroll
            for (int i = 0; i < 4; i++)
#pragma unroll
                for (int j = 0; j < 4; j++) acc[i][j] += a[i] * bb[j];
        }
        __syncthreads();
    }
#pragma unroll
    for (int j = 0; j < 4; j++) {
        int n = n0 + ty * 4 + j;
        float gg = (n < 256) ? gq[n] : gkv[n - 256];
        float bb = (n < 256) ? bq[n] : bkv[n - 256];
#pragma unroll
        for (int i = 0; i < 4; i++)
            qkwin[(size_t)(m0 + tx * 4 + i) * 512 + n] = acc[i][j] * gg + bb;
    }
}

// ---------------------------------------------------------------------------
// Routing logits: per image, L[pq][key] = sum_c qwin[pq][c] * kwin[key][c].
__global__ void k_logits(const float* __restrict__ qkwin, float* __restrict__ logits) {
    __shared__ float As[16][68];
    __shared__ float Bs[16][68];
    int m0 = blockIdx.x * 64, n0 = blockIdx.y * 64, img = blockIdx.z;
    const float* base = qkwin + (size_t)(img << 8) * 512;
    int tid = threadIdx.x;
    int tx = tid & 15, ty = tid >> 4;
    float acc[4][4] = {};
    for (int k0 = 0; k0 < 256; k0 += 16) {
#pragma unroll
        for (int r = 0; r < 4; r++) {
            int lin = tid + r * 256;
            int row = lin >> 4, kk = lin & 15;
            As[kk][row] = base[(size_t)(m0 + row) * 512 + k0 + kk];
            Bs[kk][row] = base[(size_t)(n0 + row) * 512 + 256 + k0 + kk];
        }
        __syncthreads();
#pragma unroll
        for (int kk = 0; kk < 16; kk++) {
            float a[4], bb[4];
#pragma unroll
            for (int i = 0; i < 4; i++) a[i] = As[kk][tx * 4 + i];
#pragma unroll
            for (int j = 0; j < 4; j++) bb[j] = Bs[kk][ty * 4 + j];
#pragma unroll
            for (int i = 0; i < 4; i++)
#pragma unroll
                for (int j = 0; j < 4; j++) acc[i][j] += a[i] * bb[j];
        }
        __syncthreads();
    }
    float* Lr = logits + (size_t)(img << 8) * 256;
#pragma unroll
    for (int j = 0; j < 4; j++)
#pragma unroll
        for (int i = 0; i < 4; i++)
            Lr[(size_t)(m0 + tx * 4 + i) * 256 + n0 + ty * 4 + j] = acc[i][j];
}

// ---------------------------------------------------------------------------
// Top-4 per row of 256 logits: one wave per row, shuffle argmax, jax tie-break.
__global__ __launch_bounds__(256) void k_topk(const float* __restrict__ logits,
                                              int* __restrict__ topk) {
    int row = blockIdx.x * 4 + (threadIdx.x >> 6);
    int lane = threadIdx.x & 63;
    float4 v4 = *(const float4*)(logits + (size_t)row * 256 + lane * 4);
    float v[4] = {v4.x, v4.y, v4.z, v4.w};
#pragma unroll
    for (int sel = 0; sel < TOPK; sel++) {
        float mv = v[0]; int mi = lane * 4;
#pragma unroll
        for (int j = 1; j < 4; j++)
            if (v[j] > mv) { mv = v[j]; mi = lane * 4 + j; }
#pragma unroll
        for (int off = 1; off < 64; off <<= 1) {
            float ov = __shfl_xor(mv, off);
            int oi = __shfl_xor(mi, off);
            if (ov > mv || (ov == mv && oi < mi)) { mv = ov; mi = oi; }
        }
        if (lane == 0) topk[(size_t)row * TOPK + sel] = mi;
        if ((mi >> 2) == lane) v[mi & 3] = -INFINITY;
    }
}

// ---------------------------------------------------------------------------
// MFMA GEMM, 2-PHASE double-buffered staging (T3 minimal recipe):
// prologue stage buf0; per tile: STAGE(buf^1, t+1) || ds_read+MFMA buf[cur];
// then vmcnt(0) + raw s_barrier (loads flew during compute). XCD swizzle (T1).
template <int BM, int BN>
__global__ __launch_bounds__(256) void k_mfma(const bf16* __restrict__ A,
                                              const bf16* __restrict__ Wb,
                                              const float* __restrict__ bias,
                                              bf16* __restrict__ out,
                                              int M, int N, int K) {
    constexpr int WROWS = BM / 2, WCOLS = BN / 2;     // per-wave quadrant
    constexpr int WM = WROWS / 16, WN = WCOLS / 16;   // 16x16 tiles per wave
    constexpr int CA = (BM * 4) / 256;                // 16B chunks/thread for A
    constexpr int CB = (BN * 4) / 256;
    __shared__ bf16 As[2][BM * 32];
    __shared__ bf16 Bs[2][BN * 32];
    int gx = gridDim.x;
    int lin = blockIdx.x + blockIdx.y * gx;
    int tot = gx * gridDim.y;
    int cpx = tot >> 3;
    int swz = (lin & 7) * cpx + (lin >> 3);
    int m0 = (swz % gx) * BM, n0 = (swz / gx) * BN;
    int tid = threadIdx.x;
    int w = tid >> 6, lane = tid & 63;
    int wr = w >> 1, wc = w & 1;
    int lm = lane & 15, lq = lane >> 4;
    f4v acc[WM][WN];
#pragma unroll
    for (int i = 0; i < WM; i++)
#pragma unroll
        for (int j = 0; j < WN; j++) acc[i][j] = (f4v){0.f, 0.f, 0.f, 0.f};

    auto stage = [&](int buf, int k0) {
#pragma unroll
        for (int q = 0; q < CA; q++) {
            int c = tid + q * 256, row = c >> 2, col = c & 3;
            gload_lds16(A + (size_t)(m0 + row) * K + k0 + col * 8,
                        As[buf] + (size_t)(w * 64 + q * 256) * 8);
        }
#pragma unroll
        for (int q = 0; q < CB; q++) {
            int c = tid + q * 256, row = c >> 2, col = c & 3;
            gload_lds16(Wb + (size_t)(n0 + row) * K + k0 + col * 8,
                        Bs[buf] + (size_t)(w * 64 + q * 256) * 8);
        }
    };

    const int NT = K / 32;
    stage(0, 0);
    asm volatile("s_waitcnt vmcnt(0)" ::: "memory");
    __builtin_amdgcn_s_barrier();
    __builtin_amdgcn_sched_barrier(0);
    int cur = 0;
    for (int t = 0; t < NT; t++) {
        if (t + 1 < NT) stage(cur ^ 1, (t + 1) * 32);   // prefetch in flight
        s8v af[WM], bfr[WN];
#pragma unroll
        for (int i = 0; i < WM; i++)
            af[i] = *(const s8v*)&As[cur][(wr * WROWS + i * 16 + lm) * 32 + lq * 8];
#pragma unroll
        for (int j = 0; j < WN; j++)
            bfr[j] = *(const s8v*)&Bs[cur][(wc * WCOLS + j * 16 + lm) * 32 + lq * 8];
#pragma unroll
        for (int i = 0; i < WM; i++)
#pragma unroll
            for (int j = 0; j < WN; j++)
                acc[i][j] = __builtin_amdgcn_mfma_f32_16x16x32_bf16(af[i], bfr[j], acc[i][j], 0, 0, 0);
        if (t + 1 < NT) {
            asm volatile("s_waitcnt vmcnt(0)" ::: "memory");   // prefetch landed (hid under MFMA)
            __builtin_amdgcn_s_barrier();                      // everyone done reading buf[cur]
            __builtin_amdgcn_sched_barrier(0);
            cur ^= 1;
        }
    }
    // Epilogue. C/D layout: col(n) = lane&15, row(m) = (lane>>4)*4 + reg.
#pragma unroll
    for (int j = 0; j < WN; j++) {
        int n = n0 + wc * WCOLS + j * 16 + lm;
        float bb = bias[n];
#pragma unroll
        for (int i = 0; i < WM; i++) {
            int mb = m0 + wr * WROWS + i * 16 + lq * 4;
#pragma unroll
            for (int r = 0; r < 4; r++)
                out[(size_t)(mb + r) * N + n] = toB(acc[i][j][r] + bb);
        }
    }
}

// ---------------------------------------------------------------------------
// LEPE token-major: per-image XCD affinity + row register window + weights
// staged through LDS (coalesced load, transposed [tap][cg][4ch] layout).
__global__ __launch_bounds__(256) void k_lepe_t(const bf16* __restrict__ qkv,
                                                const float* __restrict__ w_lepe,
                                                const float* __restrict__ b_lepe,
                                                bf16* __restrict__ lepe) {
    __shared__ float lw[25 * 64 * 4];   // [tap][cg][4ch] = 25.6 KB
    int tid = threadIdx.x;
    int cg = tid & 63;                  // 4-channel group, lane-fast
    int slot = tid >> 6;                // wave id 0..3 (wave-uniform)
    int b = blockIdx.x;                 // 0..1023
    int n = b & 7;                      // image -> XCD (round-robin d%8)
    int bx = b >> 3;                    // 0..127: y = bx>>1, x-half = bx&1
    int y = bx >> 1;
    int x0 = (bx & 1) * 32 + slot * 8;  // 8 x-positions per thread
#pragma unroll
    for (int j = 0; j < 25; j++) {
        int g = tid + j * 256;          // 0..6399
        float val = w_lepe[g];
        int ch = g / 25, k = g - ch * 25;
        lw[(k * 64 + (ch >> 2)) * 4 + (ch & 3)] = val;
    }
    float4 b4 = *(const float4*)(b_lepe + cg * 4);
    const float* bias4 = (const float*)&b4;
    __syncthreads();
    const bf16* vb = qkv + (size_t)n * HWSZ * QKVD + 512;
    bf16* dst = lepe + (size_t)n * HWSZ * CDIM;
    float o[8][4];
#pragma unroll
    for (int xi = 0; xi < 8; xi++)
#pragma unroll
        for (int c = 0; c < 4; c++) o[xi][c] = bias4[c];
#pragma unroll
    for (int dy = -2; dy <= 2; dy++) {
        int yy = y + dy;
        if (yy < 0 || yy >= HH) continue;          // wave-uniform
        float rf[12][4];
#pragma unroll
        for (int ii = 0; ii < 12; ii++) {
            int xx = x0 - 2 + ii;
            if (xx >= 0 && xx < WW) {              // wave-uniform
                uint2 v = *(const uint2*)(vb + (size_t)(yy * WW + xx) * QKVD + cg * 4);
                const bf16* pv = (const bf16*)&v;
#pragma unroll
                for (int c = 0; c < 4; c++) rf[ii][c] = toF(pv[c]);
            } else {
#pragma unroll
                for (int c = 0; c < 4; c++) rf[ii][c] = 0.f;
            }
        }
#pragma unroll
        for (int dx = 0; dx < 5; dx++) {
            int k = (dy + 2) * 5 + dx;
            float4 w4v = *(const float4*)&lw[(k * 64 + cg) * 4];
            const float* w4 = (const float*)&w4v;
#pragma unroll
            for (int xi = 0; xi < 8; xi++)
#pragma unroll
                for (int c = 0; c < 4; c++) o[xi][c] += rf[xi + dx][c] * w4[c];
        }
    }
#pragma unroll
    for (int xi = 0; xi < 8; xi++) {
        uint2 pk;
        bf16* pb = (bf16*)&pk;
#pragma unroll
        for (int c = 0; c < 4; c++) pb[c] = toB(o[xi][c]);
        *(uint2*)(dst + (size_t)(y * WW + x0 + xi) * CDIM + cg * 4) = pk;
    }
}

// ---------------------------------------------------------------------------
// MFMA attention + FUSED residual: writes x1 = xt + attn + lepe directly
// (in-place over xt: each (s,dim) owned by exactly one lane of one block).
// Per-image XCD affinity: n = b&7 so XCD k works only image k's qkv slice.
__global__ __launch_bounds__(256) void k_attn(const bf16* __restrict__ qkv,
                                              const int* __restrict__ topk,
                                              const bf16* __restrict__ lepe,
                                              bf16* x1t) {
    __shared__ bf16 vst[256][72];      // V^T [dim][key], pad 72
    __shared__ bf16 plds[4][16][72];   // per-wave P [tok][key]
    __shared__ float lsm[4][16];       // per-wave softmax denominator per tok
    __shared__ int toks[64];           // routed key -> token index (within image)
    int b = blockIdx.x;
    int n = b & 7, p = b >> 3;         // XCD affinity: XCD = b%8 = image
    int wy = p >> 4, wx = p & 15;
    int tid = threadIdx.x;
    if (tid < 64) {
        int rp = topk[((size_t)(n << 8) + p) * TOPK + (tid >> 4)] & 255;
        int st = tid & 15;
        toks[tid] = ((rp >> 4) * 4 + (st >> 2)) * WW + (rp & 15) * 4 + (st & 3);
    }
    __syncthreads();
    const bf16* qbase = qkv + (size_t)n * HWSZ * QKVD;
    {
        int kt = tid & 63, jj = tid >> 6;
#pragma unroll
        for (int pass = 0; pass < 8; pass++) {
            int d0 = pass * 32 + jj * 8;
            uint4 v = *(const uint4*)(qbase + (size_t)toks[kt] * QKVD + 512 + d0);
            const bf16* pv = (const bf16*)&v;
#pragma unroll
            for (int e = 0; e < 8; e++) vst[d0 + e][kt] = pv[e];
        }
    }
    __syncthreads();
    int w = tid >> 6, lane = tid & 63;
    int ln = lane & 15, lq = lane >> 4;
    int myS = (wy * 4 + (ln >> 2)) * WW + wx * 4 + (ln & 3);
    const f4v fz = {0.f, 0.f, 0.f, 0.f};
    for (int hh = 0; hh < 2; hh++) {
        int h = w * 2 + hh;
        s8v qf = *(const s8v*)(qbase + (size_t)myS * QKVD + h * 32 + lq * 8);
        f4v st4[4];
#pragma unroll
        for (int t = 0; t < 4; t++) {
            s8v kf = *(const s8v*)(qbase + (size_t)toks[t * 16 + ln] * QKVD + 256 + h * 32 + lq * 8);
            st4[t] = __builtin_amdgcn_mfma_f32_16x16x32_bf16(kf, qf, fz, 0, 0, 0);
        }
        float mx = -INFINITY;
#pragma unroll
        for (int t = 0; t < 4; t++)
#pragma unroll
            for (int r = 0; r < 4; r++) mx = fmaxf(mx, st4[t][r]);
        mx = fmaxf(mx, __shfl_xor(mx, 16));
        mx = fmaxf(mx, __shfl_xor(mx, 32));
        mx *= ATTN_SCALE;
        float sum = 0.f;
#pragma unroll
        for (int t = 0; t < 4; t++)
#pragma unroll
            for (int r = 0; r < 4; r++) {
                float pp = __expf(st4[t][r] * ATTN_SCALE - mx);
                sum += pp;
                plds[w][ln][t * 16 + lq * 4 + r] = toB(pp);
            }
        sum += __shfl_xor(sum, 16);
        sum += __shfl_xor(sum, 32);
        if (lq == 0) lsm[w][ln] = sum;
        __syncthreads();
        s8v ap0 = *(const s8v*)&plds[w][ln][lq * 8];
        s8v ap1 = *(const s8v*)&plds[w][ln][32 + lq * 8];
#pragma unroll
        for (int dt = 0; dt < 2; dt++) {
            int dim = h * 32 + dt * 16 + ln;
            s8v vv0 = *(const s8v*)&vst[dim][lq * 8];
            s8v vv1 = *(const s8v*)&vst[dim][32 + lq * 8];
            f4v o = __builtin_amdgcn_mfma_f32_16x16x32_bf16(ap0, vv0, fz, 0, 0, 0);
            o = __builtin_amdgcn_mfma_f32_16x16x32_bf16(ap1, vv1, o, 0, 0, 0);
#pragma unroll
            for (int r = 0; r < 4; r++) {
                int t = lq * 4 + r;
                float linv = 1.f / lsm[w][t];
                int s = (wy * 4 + (t >> 2)) * WW + wx * 4 + (t & 3);
                size_t idx = ((size_t)n * HWSZ + s) * CDIM + dim;
                x1t[idx] = toB(o[r] * linv + toF(x1t[idx]) + toF(lepe[idx]));
            }
        }
        __syncthreads();
    }
}

// ---------------------------------------------------------------------------
// Depthwise 3x3 + bias + ReLU, token-major, channels lane-fast.
// v3: HALF-CHANNEL blocks — 64 cgs/block -> LDS 20.7 KB. (Occupancy chase
// stopped at 54us: LDS/VGPR both non-binding per R17 counters; latency floor
// under this structure. Revisit only with new evidence.)
__global__ __launch_bounds__(256) void k_dw3_t(const bf16* __restrict__ h1,
                                               const float* __restrict__ wdwT,
                                               bf16* __restrict__ h1p) {
    __shared__ float lw[64 * 81];       // 20.7 KB
    int tid = threadIdx.x;
    int lin = blockIdx.x;               // 0..2047
    int img = lin & 7;                  // image -> XCD
    int rest = lin >> 3;                // 0..255
    int chalf = rest & 1;               // cg half: 0..63 or 64..127
    int seg = rest >> 1;                // 0..127: y = seg>>1, x-half = seg&1
    int y = seg >> 1;
    int xh = seg & 1;
    // stage this half's weights: 5120 floats, coalesced
#pragma unroll
    for (int j = 0; j < 20; j++) {
        int g = tid + j * 256;          // 0..5119
        int cgg = g / 80, r = g - cgg * 80;
        lw[cgg * 81 + r] = wdwT[chalf * 5120 + g];
    }
    __syncthreads();
    int cgl = tid & 63;                 // local cg, lane-fast
    int slot = tid >> 6;                // 0..3 (wave-uniform)
    int cg = chalf * 64 + cgl;
    int x0 = xh * 32 + slot * 8;        // 8 x-positions per thread
    const float* wl = lw + cgl * 81;
    float o[8][8];
    {
        float4 b0 = *(const float4*)&wl[72];
        float4 b1 = *(const float4*)&wl[76];
        const float* p0 = (const float*)&b0;
        const float* p1 = (const float*)&b1;
#pragma unroll
        for (int xi = 0; xi < 8; xi++)
#pragma unroll
            for (int c = 0; c < 4; c++) { o[xi][c] = p0[c]; o[xi][c + 4] = p1[c]; }
    }
    const uint4* src = (const uint4*)h1 + (size_t)img * HWSZ * 128;
    uint4* dst = (uint4*)h1p + (size_t)img * HWSZ * 128;
#pragma unroll
    for (int dy = -1; dy <= 1; dy++) {
        int yy = y + dy;
        if (yy < 0 || yy >= HH) continue;          // wave-uniform
        float rf[10][8];
#pragma unroll
        for (int ii = 0; ii < 10; ii++) {
            int xx = x0 - 1 + ii;
            if (xx >= 0 && xx < WW) {              // wave-uniform
                uint4 v = src[(size_t)(yy * WW + xx) * 128 + cg];
                const bf16* pv = (const bf16*)&v;
#pragma unroll
                for (int c = 0; c < 8; c++) rf[ii][c] = toF(pv[c]);
            } else {
#pragma unroll
                for (int c = 0; c < 8; c++) rf[ii][c] = 0.f;
            }
        }
#pragma unroll
        for (int dx = 0; dx < 3; dx++) {
            int k = (dy + 1) * 3 + dx;
            float4 w0 = *(const float4*)&wl[k * 8];
            float4 w1 = *(const float4*)&wl[k * 8 + 4];
            const float* pw0 = (const float*)&w0;
            const float* pw1 = (const float*)&w1;
#pragma unroll
            for (int xi = 0; xi < 8; xi++)
#pragma unroll
                for (int c = 0; c < 4; c++) {
                    o[xi][c]     += rf[xi + dx][c]     * pw0[c];
                    o[xi][c + 4] += rf[xi + dx][c + 4] * pw1[c];
                }
        }
    }
#pragma unroll
    for (int xi = 0; xi < 8; xi++) {
        uint4 pk;
        bf16* pb = (bf16*)&pk;
#pragma unroll
        for (int c = 0; c < 8; c++) pb[c] = toB(fmaxf(o[xi][c], 0.f));
        dst[(size_t)(y * WW + x0 + xi) * 128 + cg] = pk;
    }
}

// ---------------------------------------------------------------------------
// out (NCHW fp32) = x1 + h2 (both token-major bf16)
__global__ void k_final(const bf16* __restrict__ x1, const bf16* __restrict__ h2,
                        float* __restrict__ out) {
    __shared__ float tile[32][33];
    int s0 = blockIdx.x * 32, c0 = blockIdx.y * 32, n = blockIdx.z;
    int tx = threadIdx.x, ty = threadIdx.y;
#pragma unroll
    for (int r = 0; r < 4; r++) {
        int s = s0 + ty + r * 8;
        size_t idx = ((size_t)n * HWSZ + s) * CDIM + c0 + tx;
        tile[tx][ty + r * 8] = toF(x1[idx]) + toF(h2[idx]);
    }
    __syncthreads();
#pragma unroll
    for (int r = 0; r < 4; r++) {
        int c = c0 + ty + r * 8;
        out[(size_t)n * CDIM * HWSZ + (size_t)c * HWSZ + s0 + tx] = tile[ty + r * 8][tx];
    }
}

// ---------------------------------------------------------------------------
extern "C" void kernel_launch(void* const* d_in, const int* in_sizes, int n_in,
                              void* d_out, int out_size, void* d_ws, size_t ws_size,
                              hipStream_t stream) {
    (void)in_sizes; (void)n_in; (void)out_size; (void)ws_size;
    const float* x      = (const float*)d_in[0];
    const float* wq     = (const float*)d_in[1];
    const float* gq     = (const float*)d_in[2];
    const float* bq     = (const float*)d_in[3];
    const float* wkv    = (const float*)d_in[4];
    const float* gkv    = (const float*)d_in[5];
    const float* bkv    = (const float*)d_in[6];
    const float* w_lepe = (const float*)d_in[7];
    const float* b_lepe = (const float*)d_in[8];
    const float* w_fc1  = (const float*)d_in[9];
    const float* g_fc1  = (const float*)d_in[10];
    const float* b_fc1  = (const float*)d_in[11];
    const float* w_dw   = (const float*)d_in[12];
    const float* b_dw   = (const float*)d_in[13];
    const float* w_fc2  = (const float*)d_in[14];
    const float* g_fc2  = (const float*)d_in[15];
    const float* b_fc2  = (const float*)d_in[16];

    // ws layout (ws_size = 256 MiB). Unchunked phase B.
    char* ws = (char*)d_ws;
    bf16*  qkv    = (bf16*)(ws);                    //   0.0 MB, 50.3
    bf16*  lepe   = (bf16*)(ws + 50331648);         //  48.0 MiB, 16.8
    bf16*  xt     = (bf16*)(ws + 67108864);         //  64.0 MiB, 16.8 (x1 in-place)
    bf16*  x1     = (bf16*)(ws + 67108864);
    bf16*  h1     = (bf16*)(ws + 83886080);         //  80.0 MiB, 67.1
    bf16*  h1p    = (bf16*)(ws + 150994944);        // 144.0 MiB, 67.1
    bf16*  h2     = (bf16*)(ws + 218103808);        // 208.0 MiB, 16.8
    float* xwin   = (float*)(ws + 234881024);       // 224.0 MiB, 2.1
    float* qkwin  = (float*)(ws + 236978176);       // 4.2
    float* logits = (float*)(ws + 241172480);       // 2.1
    int*   tk     = (int*)(ws + 243269632);
    bf16*  wbqkv  = (bf16*)(ws + 243302400);
    bf16*  wbfc1  = (bf16*)(ws + 243695616);
    bf16*  wbfc2  = (bf16*)(ws + 244219904);
    float* bias768= (float*)(ws + 244744192);
    float* wdwT   = (float*)(ws + 244747264);       // 40 KB

    k_prep<<<2856, 256, 0, stream>>>(wq, gq, wkv, gkv, w_fc1, g_fc1, w_fc2, g_fc2,
                                     bq, bkv, w_dw, b_dw,
                                     wbqkv, wbfc1, wbfc2, bias768, wdwT);
    k_xt<<<dim3(128, 8, 8), dim3(32, 8), 0, stream>>>(x, xt);
    k_xwin<<<2048, 256, 0, stream>>>(x, xwin);
    k_qkwin<<<dim3(32, 8), 256, 0, stream>>>(xwin, wq, wkv, gq, bq, gkv, bkv, qkwin);
    k_logits<<<dim3(4, 4, 8), 256, 0, stream>>>(qkwin, logits);
    k_topk<<<512, 256, 0, stream>>>(logits, tk);
    k_mfma<128, 128><<<dim3(256, 6), 256, 0, stream>>>(
        xt, wbqkv, bias768, qkv, TT, QKVD, CDIM);
    k_lepe_t<<<1024, 256, 0, stream>>>(qkv, w_lepe, b_lepe, lepe);
    k_attn<<<2048, 256, 0, stream>>>(qkv, tk, lepe, x1);   // x1 = xt+attn+lepe fused
    k_mfma<128, 128><<<dim3(256, 8), 256, 0, stream>>>(
        x1, wbfc1, b_fc1, h1, TT, HID, CDIM);
    k_dw3_t<<<2048, 256, 0, stream>>>(h1, wdwT, h1p);
    k_mfma<64, 128><<<dim3(512, 2), 256, 0, stream>>>(
        h1p, wbfc2, b_fc2, h2, TT, CDIM, HID);
    k_final<<<dim3(128, 8, 8), dim3(32, 8), 0, stream>>>(x1, h2, (float*)d_out);
}